// Round 10
// baseline (1509.058 us; speedup 1.0000x reference)
//
#include <hip/hip_runtime.h>
#include <hip/hip_bf16.h>
#include <math.h>

#define Bn 64
#define Lq 512
#define Dm 128
#define NHh 8
#define ELn 2
#define PLn 96
#define CINn 8
#define DFFn 2048
#define NTFn 4
#define EPSf 1e-5f

typedef __attribute__((ext_vector_type(8))) short short8v;
typedef __attribute__((ext_vector_type(4))) float f32x4;

__device__ __forceinline__ short f2b(float f) {
    union { float f; unsigned u; } v; v.f = f;
    unsigned r = v.u + 0x7fff + ((v.u >> 16) & 1);
    return (short)(r >> 16);
}
// fast activations: v_rcp_f32 (~1 ulp) instead of full-precision division
__device__ __forceinline__ float fsig(float x) {
    return __builtin_amdgcn_rcpf(1.f + __expf(-x));
}
__device__ __forceinline__ float fast_tanh(float x) {
    float ax = fabsf(x);
    float e = __expf(2.f * ax);
    float t = 1.f - 2.f * __builtin_amdgcn_rcpf(e + 1.f);
    return copysignf(t, x);
}

// ------------------------------------------------------- fp32 -> bf16
__global__ void cvt_kernel(const float* __restrict__ in, short* __restrict__ out, int n) {
    int i = blockIdx.x * 256 + threadIdx.x;
    if (i < n) out[i] = f2b(in[i]);
}

// ------------------------------------------------------- bias sum (bih+bhh)
__global__ void biassum_kernel(const float* __restrict__ a, const float* __restrict__ b,
                               float* __restrict__ o, int n) {
    int i = blockIdx.x * 256 + threadIdx.x;
    if (i < n) o[i] = a[i] + b[i];
}

// ---------------------------------------------------------------- GARCH
__global__ void garch_kernel(const float* __restrict__ x_enc,
                             const float* __restrict__ g_omega,
                             const float* __restrict__ g_alpha,
                             const float* __restrict__ g_beta,
                             const float* __restrict__ g_h0,
                             float* __restrict__ garch) {
    int b = threadIdx.x;
    if (b >= Bn) return;
    float omega = log1pf(__expf(g_omega[0]));
    float alpha = 0.2f / (1.f + __expf(-g_alpha[0]));
    float beta  = 0.8f / (1.f + __expf(-g_beta[0]));
    float h = log1pf(__expf(g_h0[0]));
    const float* xe = x_enc + (size_t)b * Lq * CINn + (CINn - 2);
    for (int t = 0; t < Lq; ++t) {
        float r = xe[(size_t)t * CINn];
        h = omega + alpha * r * r + beta * h;
    }
    float ab = alpha + beta;
    for (int p = 0; p < PLn; ++p) {
        garch[b * PLn + p] = sqrtf(h);
        h = omega + ab * h;
    }
}

// ------------------------------------------------- conv + temporal + pos (bf16 out)
__global__ void enc_kernel(const float* __restrict__ x_enc,
                           const float* __restrict__ x_mark,
                           const float* __restrict__ conv_w,
                           const float* __restrict__ temp_w,
                           short* __restrict__ encb) {
    int idx = blockIdx.x * blockDim.x + threadIdx.x;   // over B*L*D
    int d = idx & (Dm - 1);
    int l = (idx >> 7) & (Lq - 1);
    int b = idx >> 16;
    int lm = (l + Lq - 1) & (Lq - 1);
    int lp = (l + 1) & (Lq - 1);
    const float* xb = x_enc + (size_t)b * Lq * CINn;
    const float* w  = conv_w + (size_t)d * CINn * 3;
    float acc = 0.f;
#pragma unroll
    for (int ci = 0; ci < CINn; ++ci) {
        acc += xb[(size_t)lm * CINn + ci] * w[ci * 3 + 0];
        acc += xb[(size_t)l  * CINn + ci] * w[ci * 3 + 1];
        acc += xb[(size_t)lp * CINn + ci] * w[ci * 3 + 2];
    }
    const float* mk = x_mark + ((size_t)b * Lq + l) * NTFn;
    const float* tw = temp_w + (size_t)d * NTFn;
#pragma unroll
    for (int f = 0; f < NTFn; ++f) acc += mk[f] * tw[f];
    float dv = __expf(-(float)(d & ~1) * (9.210340371976184f / 128.f));
    float ang = (float)l * dv;
    acc += (d & 1) ? cosf(ang) : sinf(ang);
    encb[idx] = f2b(acc);
}

// ------------------------ bf16 MFMA GEMM, tile 128x128 (4 waves of 64x64)
__global__ __launch_bounds__(256) void gemm_bf16_128(
    const short* __restrict__ A, const short* __restrict__ W,
    const float* __restrict__ b1,
    float* __restrict__ Cf, short* __restrict__ Cb,
    int M, int N, int K, int relu)
{
    int t = threadIdx.x;
    int wid = t >> 6, lane = t & 63;
    int wr = wid >> 1, wc = wid & 1;
    int m0 = blockIdx.x * 128 + wr * 64;
    int n0 = blockIdx.y * 128 + wc * 64;
    int lr = lane & 15;
    int lk = (lane >> 4) * 8;
    f32x4 acc[4][4] = {};
    for (int k0 = 0; k0 < K; k0 += 32) {
        short8v a[4], b[4];
#pragma unroll
        for (int i = 0; i < 4; ++i)
            a[i] = *reinterpret_cast<const short8v*>(&A[(size_t)(m0 + i * 16 + lr) * K + k0 + lk]);
#pragma unroll
        for (int j = 0; j < 4; ++j)
            b[j] = *reinterpret_cast<const short8v*>(&W[(size_t)(n0 + j * 16 + lr) * K + k0 + lk]);
#pragma unroll
        for (int i = 0; i < 4; ++i)
#pragma unroll
            for (int j = 0; j < 4; ++j)
                acc[i][j] = __builtin_amdgcn_mfma_f32_16x16x32_bf16(a[i], b[j], acc[i][j], 0, 0, 0);
    }
    int cr0 = (lane >> 4) * 4;
    int cc = lane & 15;
#pragma unroll
    for (int i = 0; i < 4; ++i)
#pragma unroll
        for (int j = 0; j < 4; ++j) {
            int col = n0 + j * 16 + cc;
            float bias = b1[col];
#pragma unroll
            for (int r = 0; r < 4; ++r) {
                int row = m0 + i * 16 + cr0 + r;
                float v = acc[i][j][r] + bias;
                if (relu) v = fmaxf(v, 0.f);
                if (Cf) Cf[(size_t)row * N + col] = v;
                else    Cb[(size_t)row * N + col] = f2b(v);
            }
        }
}

// ------------------------ bf16 MFMA GEMM, tile 64x64 (4 waves of 32x32)
__global__ __launch_bounds__(256) void gemm_bf16_64(
    const short* __restrict__ A, const short* __restrict__ W,
    const float* __restrict__ b1,
    float* __restrict__ Cf,
    int M, int N, int K)
{
    int t = threadIdx.x;
    int wid = t >> 6, lane = t & 63;
    int wr = wid >> 1, wc = wid & 1;
    int m0 = blockIdx.x * 64 + wr * 32;
    int n0 = blockIdx.y * 64 + wc * 32;
    int lr = lane & 15;
    int lk = (lane >> 4) * 8;
    f32x4 acc[2][2] = {};
    for (int k0 = 0; k0 < K; k0 += 32) {
        short8v a[2], b[2];
#pragma unroll
        for (int i = 0; i < 2; ++i)
            a[i] = *reinterpret_cast<const short8v*>(&A[(size_t)(m0 + i * 16 + lr) * K + k0 + lk]);
#pragma unroll
        for (int j = 0; j < 2; ++j)
            b[j] = *reinterpret_cast<const short8v*>(&W[(size_t)(n0 + j * 16 + lr) * K + k0 + lk]);
#pragma unroll
        for (int i = 0; i < 2; ++i)
#pragma unroll
            for (int j = 0; j < 2; ++j)
                acc[i][j] = __builtin_amdgcn_mfma_f32_16x16x32_bf16(a[i], b[j], acc[i][j], 0, 0, 0);
    }
    int cr0 = (lane >> 4) * 4;
    int cc = lane & 15;
#pragma unroll
    for (int i = 0; i < 2; ++i)
#pragma unroll
        for (int j = 0; j < 2; ++j) {
            int col = n0 + j * 16 + cc;
            float bias = b1[col];
#pragma unroll
            for (int r = 0; r < 4; ++r) {
                int row = m0 + i * 16 + cr0 + r;
                Cf[(size_t)row * N + col] = acc[i][j][r] + bias;
            }
        }
}

// ---------------------------------------------------------------- LSTM (MFMA matvec v3)
// v3: k-OUTER MFMA ordering (dependence distance 8 -> no result-latency stalls)
// + rcp-based activations (no v_div_* sequences on the serial c/h chain).
__global__ __launch_bounds__(256, 1) void lstm_kernel(
    const float* __restrict__ xW, const short* __restrict__ Whh_b,
    float* __restrict__ xout, short* __restrict__ xb_out)
{
    __shared__ __align__(16) short hb[2][Dm];   // bf16 h, double-buffered
    int b = blockIdx.x;
    int tid = threadIdx.x;
    int w = tid >> 6;
    int lane = tid & 63;
    int lr = lane & 15;
    int lk = (lane >> 4) * 8;
    int cr0 = (lane >> 4) * 4;
    int qs = lr >> 2;         // owned s (valid when lr<8)
    int qr = lr & 3;          // owned r

    // A-fragments: tile (g,s): rows m0 = g*128 + w*32 + s*16, K=128 in 4 chunks of 32
    short8v a[4][2][4];
#pragma unroll
    for (int g = 0; g < 4; ++g)
#pragma unroll
        for (int s = 0; s < 2; ++s)
#pragma unroll
            for (int k = 0; k < 4; ++k)
                a[g][s][k] = *reinterpret_cast<const short8v*>(
                    &Whh_b[(size_t)(g * 128 + w * 32 + s * 16 + lr) * Dm + k * 32 + lk]);

    const float* xwb = xW + (size_t)b * Lq * 512;
    float cpers = 0.f;
    if (tid < 64) reinterpret_cast<int*>(hb[0])[tid] = 0;   // h(-1) = 0

    f32x4 xwA[4][2], xwB[4][2];
#pragma unroll
    for (int g = 0; g < 4; ++g)
#pragma unroll
        for (int s = 0; s < 2; ++s) {
            xwA[g][s] = *reinterpret_cast<const f32x4*>(
                &xwb[(size_t)0 * 512 + g * 128 + w * 32 + s * 16 + cr0]);
            xwB[g][s] = *reinterpret_cast<const f32x4*>(
                &xwb[(size_t)1 * 512 + g * 128 + w * 32 + s * 16 + cr0]);
        }
    __syncthreads();

    auto step = [&](int t, f32x4 (&xwC)[4][2]) {
        int p = t & 1;
        // B-fragments: h bf16 broadcast (identical across lanes/cols)
        short8v bf[4];
#pragma unroll
        for (int k = 0; k < 4; ++k)
            bf[k] = *reinterpret_cast<const short8v*>(&hb[p][k * 32 + lk]);
        // move C-in to acc, then reuse xwC's registers for the t+2 prefetch
        f32x4 acc[4][2];
#pragma unroll
        for (int g = 0; g < 4; ++g)
#pragma unroll
            for (int s = 0; s < 2; ++s)
                acc[g][s] = xwC[g][s];
        int tp = (t + 2 < Lq) ? t + 2 : Lq - 1;
#pragma unroll
        for (int g = 0; g < 4; ++g)
#pragma unroll
            for (int s = 0; s < 2; ++s)
                xwC[g][s] = *reinterpret_cast<const f32x4*>(
                    &xwb[(size_t)tp * 512 + g * 128 + w * 32 + s * 16 + cr0]);
        // matvec: acc += Whh_tile . h  --- k OUTER: consecutive MFMAs hit
        // 8 different accumulators, so no dependent-result stalls
#pragma unroll
        for (int k = 0; k < 4; ++k)
#pragma unroll
            for (int g = 0; g < 4; ++g)
#pragma unroll
                for (int s = 0; s < 2; ++s)
                    acc[g][s] = __builtin_amdgcn_mfma_f32_16x16x32_bf16(
                        a[g][s][k], bf[k], acc[g][s], 0, 0, 0);
        // owned-copy lanes: activations in-register (static-index selects)
        if (lr < 8) {
            float iraw = 0.f, fraw = 0.f, graw = 0.f, oraw = 0.f;
#pragma unroll
            for (int s = 0; s < 2; ++s)
#pragma unroll
                for (int r = 0; r < 4; ++r)
                    if (qs == s && qr == r) {
                        iraw = acc[0][s][r]; fraw = acc[1][s][r];
                        graw = acc[2][s][r]; oraw = acc[3][s][r];
                    }
            float ig = fsig(iraw);
            float fg = fsig(fraw);
            float gg = fast_tanh(graw);
            float og = fsig(oraw);
            cpers = fg * cpers + ig * gg;
            float h = og * fast_tanh(cpers);
            int d = w * 32 + qs * 16 + cr0 + qr;
            short hv = f2b(h);
            hb[p ^ 1][d] = hv;
            size_t o = ((size_t)b * Lq + t) * Dm + d;
            xb_out[o] = hv;
            xout[o] = h;
        }
        // LDS visibility only; vmcnt stays un-drained (prefetch in flight)
        asm volatile("s_waitcnt lgkmcnt(0)" ::: "memory");
        __builtin_amdgcn_s_barrier();
    };

    for (int t = 0; t < Lq; t += 2) {
        step(t, xwA);
        step(t + 1, xwB);
    }
}

// ------------------------------------------------------------- attention
__global__ __launch_bounds__(256) void attn_kernel(
    const float* __restrict__ qkv, short* __restrict__ ctxb)
{
    __shared__ float Kb[Lq][16];
    __shared__ float Vb[Lq][16];
    int h = blockIdx.x & (NHh - 1);
    int b = blockIdx.x >> 3;
    int t = threadIdx.x;
    const float* base = qkv + (size_t)b * Lq * 384;
    int hoff = h * 16;
    for (int idx = t; idx < Lq * 16; idx += 256) {
        int row = idx >> 4, col = idx & 15;
        Kb[row][col] = base[(size_t)row * 384 + 128 + hoff + col];
        Vb[row][col] = base[(size_t)row * 384 + 256 + hoff + col];
    }
    __syncthreads();
    for (int rr = 0; rr < 2; ++rr) {
        int l = t + rr * 256;
        float q[16];
#pragma unroll
        for (int cc = 0; cc < 16; ++cc) q[cc] = base[(size_t)l * 384 + hoff + cc];
        float m = -1e30f, ssum = 0.f;
        float acc[16] = {};
        for (int jr = 0; jr < Lq; ++jr) {
            float s = 0.f;
#pragma unroll
            for (int cc = 0; cc < 16; ++cc) s += q[cc] * Kb[jr][cc];
            s *= 0.25f;
            if (s > m) {
                float corr = __expf(m - s);
                ssum *= corr;
#pragma unroll
                for (int cc = 0; cc < 16; ++cc) acc[cc] *= corr;
                m = s;
            }
            float p = __expf(s - m);
            ssum += p;
#pragma unroll
            for (int cc = 0; cc < 16; ++cc) acc[cc] += p * Vb[jr][cc];
        }
        float inv = __builtin_amdgcn_rcpf(ssum);
        short8v v0, v1;
#pragma unroll
        for (int cc = 0; cc < 8; ++cc) { v0[cc] = f2b(acc[cc] * inv); v1[cc] = f2b(acc[cc + 8] * inv); }
        short* o = ctxb + ((size_t)b * Lq + l) * Dm + hoff;
        *reinterpret_cast<short8v*>(o) = v0;
        *reinterpret_cast<short8v*>(o + 8) = v1;
    }
}

// ----------------------------------------------------- residual add + LN (+ bf16 mirror)
__global__ __launch_bounds__(256) void addln_kernel(
    float* __restrict__ x, const float* __restrict__ add,
    const float* __restrict__ g, const float* __restrict__ bta,
    short* __restrict__ xb)
{
    int wave = threadIdx.x >> 6;
    int lane = threadIdx.x & 63;
    int row = blockIdx.x * 4 + wave;
    float* xr = x + (size_t)row * Dm;
    const float* ar = add + (size_t)row * Dm;
    int d0 = lane * 2;
    float2 xv = *reinterpret_cast<const float2*>(&xr[d0]);
    float2 av = *reinterpret_cast<const float2*>(&ar[d0]);
    float v0 = xv.x + av.x, v1 = xv.y + av.y;
    float s = v0 + v1;
#pragma unroll
    for (int off = 32; off > 0; off >>= 1) s += __shfl_xor(s, off);
    float mu = s * (1.f / Dm);
    float e0 = v0 - mu, e1 = v1 - mu;
    float s2 = e0 * e0 + e1 * e1;
#pragma unroll
    for (int off = 32; off > 0; off >>= 1) s2 += __shfl_xor(s2, off);
    float rs = rsqrtf(s2 * (1.f / Dm) + EPSf);
    float o0 = e0 * rs * g[d0] + bta[d0];
    float o1 = e1 * rs * g[d0 + 1] + bta[d0 + 1];
    xr[d0] = o0;
    xr[d0 + 1] = o1;
    unsigned pk = (unsigned)(unsigned short)f2b(o0) | ((unsigned)(unsigned short)f2b(o1) << 16);
    *reinterpret_cast<unsigned*>(&xb[(size_t)row * Dm + d0]) = pk;
}

// --------------------------------------------------------------- head
__global__ void head_kernel(const float* __restrict__ x,
                            const float* __restrict__ head_w, const float* __restrict__ head_b,
                            const float* __restrict__ gw1, const float* __restrict__ gb1,
                            const float* __restrict__ gw2, const float* __restrict__ gb2,
                            const float* __restrict__ garch,
                            float* __restrict__ out)
{
    __shared__ float last[Dm];
    __shared__ float t1[Dm / 2];
    int b = blockIdx.x, t = threadIdx.x;
    if (t < Dm) last[t] = x[((size_t)b * Lq + (Lq - 1)) * Dm + t];
    __syncthreads();
    if (t < Dm / 2) {
        float s = gb1[t];
#pragma unroll 8
        for (int d = 0; d < Dm; ++d) s += last[d] * gw1[(size_t)t * Dm + d];
        t1[t] = fmaxf(s, 0.f);
    }
    __syncthreads();
    if (t < PLn) {
        float ai = head_b[t];
#pragma unroll 8
        for (int d = 0; d < Dm; ++d) ai += last[d] * head_w[(size_t)t * Dm + d];
        float gg = gb2[t];
#pragma unroll 8
        for (int j = 0; j < Dm / 2; ++j) gg += t1[j] * gw2[(size_t)t * (Dm / 2) + j];
        float gate = 1.f / (1.f + __expf(-gg));
        out[b * PLn + t] = garch[b * PLn + t] + gate * ai;
    }
}

extern "C" void kernel_launch(void* const* d_in, const int* in_sizes, int n_in,
                              void* d_out, int out_size, void* d_ws, size_t ws_size,
                              hipStream_t stream)
{
    const float* x_enc  = (const float*)d_in[0];
    const float* x_mark = (const float*)d_in[1];
    const float* conv_w = (const float*)d_in[4];
    const float* temp_w = (const float*)d_in[5];
    const float* Wih    = (const float*)d_in[6];
    const float* Whh    = (const float*)d_in[7];
    const float* bih    = (const float*)d_in[8];
    const float* bhh    = (const float*)d_in[9];
    const float* Wqkv   = (const float*)d_in[10];
    const float* bqkv   = (const float*)d_in[11];
    const float* Wo     = (const float*)d_in[12];
    const float* bo     = (const float*)d_in[13];
    const float* ln1g   = (const float*)d_in[14];
    const float* ln1b   = (const float*)d_in[15];
    const float* W1     = (const float*)d_in[16];
    const float* b1     = (const float*)d_in[17];
    const float* W2     = (const float*)d_in[18];
    const float* b2     = (const float*)d_in[19];
    const float* ln2g   = (const float*)d_in[20];
    const float* ln2b   = (const float*)d_in[21];
    const float* head_w = (const float*)d_in[22];
    const float* head_b = (const float*)d_in[23];
    const float* gw1    = (const float*)d_in[24];
    const float* gb1    = (const float*)d_in[25];
    const float* gw2    = (const float*)d_in[26];
    const float* gb2    = (const float*)d_in[27];
    const float* g_omega= (const float*)d_in[28];
    const float* g_alpha= (const float*)d_in[29];
    const float* g_beta = (const float*)d_in[30];
    const float* g_h0   = (const float*)d_in[31];

    const int M = Bn * Lq;                    // 32768
    float* ws    = (float*)d_ws;
    float* garch = ws;                        // 6144 used
    float* biassum = ws + 6144;               // 512 floats (bih+bhh)
    float* regionA = ws + 8192;               // 4,194,304 floats
    short* xb   = (short*)regionA;            //   bf16 x mirror (after lstm)
    short* ctxb = (short*)(regionA + 2097152);//   bf16 ctx
    float* xWr  = regionA + 4194304;          // 16,777,216 floats
    float* xW   = xWr;                        //   fp32 xW (dead after lstm)
    short* ff1b = (short*)xWr;                //   bf16 ff1 chunk (16384x2048)
    float* x    = xWr + 16777216;             // 4,194,304 floats (live all launch)
    float* qkvr = x + 4194304;                // 12,582,912 floats
    short* encb = (short*)qkvr;               //   bf16 enc (dead after xW gemm)
    float* qkv  = qkvr;                       //   fp32 qkv
    float* tmp  = qkvr;                       //   fp32 tmp (qkv dead when written)
    float* wbr  = qkvr + 12582912;            // bf16 weight mirrors
    short* Wqkv_b = (short*)wbr;              // 98,304
    short* Wo_b   = Wqkv_b + 98304;           // 32,768
    short* W1_b   = Wo_b + 32768;             // 524,288
    short* W2_b   = W1_b + 524288;            // 524,288
    short* Whh_bb = W2_b + 524288;            // 65,536
    short* Wih_b  = Whh_bb + 65536;           // 65,536

    cvt_kernel<<<(98304 + 255) / 256, 256, 0, stream>>>(Wqkv, Wqkv_b, 98304);
    cvt_kernel<<<(32768 + 255) / 256, 256, 0, stream>>>(Wo, Wo_b, 32768);
    cvt_kernel<<<(524288 + 255) / 256, 256, 0, stream>>>(W1, W1_b, 524288);
    cvt_kernel<<<(524288 + 255) / 256, 256, 0, stream>>>(W2, W2_b, 524288);
    cvt_kernel<<<(65536 + 255) / 256, 256, 0, stream>>>(Whh, Whh_bb, 65536);
    cvt_kernel<<<(65536 + 255) / 256, 256, 0, stream>>>(Wih, Wih_b, 65536);
    biassum_kernel<<<2, 256, 0, stream>>>(bih, bhh, biassum, 512);

    garch_kernel<<<1, 64, 0, stream>>>(x_enc, g_omega, g_alpha, g_beta, g_h0, garch);
    enc_kernel<<<(Bn * Lq * Dm) / 256, 256, 0, stream>>>(x_enc, x_mark, conv_w, temp_w, encb);
    gemm_bf16_128<<<dim3(M / 128, 512 / 128), 256, 0, stream>>>(
        encb, Wih_b, biassum, xW, nullptr, M, 512, Dm, 0);
    lstm_kernel<<<Bn, 256, 0, stream>>>(xW, Whh_bb, x, xb);

    for (int li = 0; li < ELn; ++li) {
        gemm_bf16_128<<<dim3(M / 128, 384 / 128), 256, 0, stream>>>(
            xb, Wqkv_b + (size_t)li * 384 * Dm, bqkv + li * 384, qkv, nullptr, M, 384, Dm, 0);
        attn_kernel<<<Bn * NHh, 256, 0, stream>>>(qkv, ctxb);
        gemm_bf16_64<<<dim3(M / 64, Dm / 64), 256, 0, stream>>>(
            ctxb, Wo_b + (size_t)li * Dm * Dm, bo + li * Dm, tmp, M, Dm, Dm);
        addln_kernel<<<M / 4, 256, 0, stream>>>(x, tmp, ln1g + li * Dm, ln1b + li * Dm, xb);
        for (int mc = 0; mc < 2; ++mc) {
            const int MC = M / 2;             // 16384 rows
            gemm_bf16_128<<<dim3(MC / 128, DFFn / 128), 256, 0, stream>>>(
                xb + (size_t)mc * MC * Dm, W1_b + (size_t)li * DFFn * Dm, b1 + li * DFFn,
                nullptr, ff1b, MC, DFFn, Dm, 1);
            gemm_bf16_64<<<dim3(MC / 64, Dm / 64), 256, 0, stream>>>(
                ff1b, W2_b + (size_t)li * Dm * DFFn, b2 + li * Dm,
                tmp + (size_t)mc * MC * Dm, MC, Dm, DFFn);
        }
        addln_kernel<<<M / 4, 256, 0, stream>>>(x, tmp, ln2g + li * Dm, ln2b + li * Dm, xb);
    }
    head_kernel<<<Bn, 128, 0, stream>>>(x, head_w, head_b, gw1, gb1, gw2, gb2, garch,
                                        (float*)d_out);
}

// Round 11
// 1307.048 us; speedup vs baseline: 1.1546x; 1.1546x over previous
//
#include <hip/hip_runtime.h>
#include <hip/hip_bf16.h>
#include <math.h>

#define Bn 64
#define Lq 512
#define Dm 128
#define NHh 8
#define ELn 2
#define PLn 96
#define CINn 8
#define DFFn 2048
#define NTFn 4
#define EPSf 1e-5f

typedef __attribute__((ext_vector_type(8))) short short8v;
typedef __attribute__((ext_vector_type(4))) float f32x4;

__device__ __forceinline__ short f2b(float f) {
    union { float f; unsigned u; } v; v.f = f;
    unsigned r = v.u + 0x7fff + ((v.u >> 16) & 1);
    return (short)(r >> 16);
}
__device__ __forceinline__ float b2f(short s) {
    union { unsigned u; float f; } v;
    v.u = ((unsigned)(unsigned short)s) << 16;
    return v.f;
}
__device__ __forceinline__ float fsig(float x) {
    return __builtin_amdgcn_rcpf(1.f + __expf(-x));
}
__device__ __forceinline__ float fast_tanh(float x) {
    float ax = fabsf(x);
    float e = __expf(2.f * ax);
    float t = 1.f - 2.f * __builtin_amdgcn_rcpf(e + 1.f);
    return copysignf(t, x);
}
// async global->LDS, 16B per lane; dest = uniform base + lane*16 (linear)
__device__ __forceinline__ void gload_lds16(const short* g, short* l) {
    __builtin_amdgcn_global_load_lds(
        (const __attribute__((address_space(1))) void*)g,
        (__attribute__((address_space(3))) void*)l, 16, 0, 0);
}

// ------------------------------------------------------- fp32 -> bf16
__global__ void cvt_kernel(const float* __restrict__ in, short* __restrict__ out, int n) {
    int i = blockIdx.x * 256 + threadIdx.x;
    if (i < n) out[i] = f2b(in[i]);
}

// ------------------------------------------------------- bias sum (bih+bhh)
__global__ void biassum_kernel(const float* __restrict__ a, const float* __restrict__ b,
                               float* __restrict__ o, int n) {
    int i = blockIdx.x * 256 + threadIdx.x;
    if (i < n) o[i] = a[i] + b[i];
}

// ---------------------------------------------------------------- GARCH
__global__ void garch_kernel(const float* __restrict__ x_enc,
                             const float* __restrict__ g_omega,
                             const float* __restrict__ g_alpha,
                             const float* __restrict__ g_beta,
                             const float* __restrict__ g_h0,
                             float* __restrict__ garch) {
    int b = threadIdx.x;
    if (b >= Bn) return;
    float omega = log1pf(__expf(g_omega[0]));
    float alpha = 0.2f / (1.f + __expf(-g_alpha[0]));
    float beta  = 0.8f / (1.f + __expf(-g_beta[0]));
    float h = log1pf(__expf(g_h0[0]));
    const float* xe = x_enc + (size_t)b * Lq * CINn + (CINn - 2);
    for (int t = 0; t < Lq; ++t) {
        float r = xe[(size_t)t * CINn];
        h = omega + alpha * r * r + beta * h;
    }
    float ab = alpha + beta;
    for (int p = 0; p < PLn; ++p) {
        garch[b * PLn + p] = sqrtf(h);
        h = omega + ab * h;
    }
}

// ------------------------------------------------- conv + temporal + pos (bf16 out)
__global__ void enc_kernel(const float* __restrict__ x_enc,
                           const float* __restrict__ x_mark,
                           const float* __restrict__ conv_w,
                           const float* __restrict__ temp_w,
                           short* __restrict__ encb) {
    int idx = blockIdx.x * blockDim.x + threadIdx.x;   // over B*L*D
    int d = idx & (Dm - 1);
    int l = (idx >> 7) & (Lq - 1);
    int b = idx >> 16;
    int lm = (l + Lq - 1) & (Lq - 1);
    int lp = (l + 1) & (Lq - 1);
    const float* xb = x_enc + (size_t)b * Lq * CINn;
    const float* w  = conv_w + (size_t)d * CINn * 3;
    float acc = 0.f;
#pragma unroll
    for (int ci = 0; ci < CINn; ++ci) {
        acc += xb[(size_t)lm * CINn + ci] * w[ci * 3 + 0];
        acc += xb[(size_t)l  * CINn + ci] * w[ci * 3 + 1];
        acc += xb[(size_t)lp * CINn + ci] * w[ci * 3 + 2];
    }
    const float* mk = x_mark + ((size_t)b * Lq + l) * NTFn;
    const float* tw = temp_w + (size_t)d * NTFn;
#pragma unroll
    for (int f = 0; f < NTFn; ++f) acc += mk[f] * tw[f];
    float dv = __expf(-(float)(d & ~1) * (9.210340371976184f / 128.f));
    float ang = (float)l * dv;
    acc += (d & 1) ? cosf(ang) : sinf(ang);
    encb[idx] = f2b(acc);
}

// ---------------- staged+swizzled bf16 MFMA GEMM, tile 128x128, BK=128
// C = act(A @ W^T + b1); A: MxK bf16, W: NxK bf16, both row-major.
// LDS layout: [128 rows][16 chunks of 16B], phys chunk = logical ^ (row&7)
// (2-way residual bank aliasing = free). Staged via global_load_lds w=16
// with pre-swizzled per-lane GLOBAL source, linear LDS dest (m173 pattern).
__global__ __launch_bounds__(256) void gemm_stage(
    const short* __restrict__ A, const short* __restrict__ W,
    const float* __restrict__ b1,
    float* __restrict__ Cf, short* __restrict__ Cb,
    int M, int N, int K, int relu)
{
    __shared__ short As[128 * 128];
    __shared__ short Ws[128 * 128];
    int tid = threadIdx.x;
    int w = tid >> 6, lane = tid & 63;
    int wr = w >> 1, wc = w & 1;
    int m0 = blockIdx.x * 128, n0 = blockIdx.y * 128;
    int lr = lane & 15;
    int lkq = lane >> 4;                 // 0..3
    // staging coords: chunk c = w*8+inst covers rows [c*4, c*4+4)
    int srow_in = lane >> 4;             // row within chunk
    int jp = lane & 15;                  // physical 16B-chunk index
    f32x4 acc[4][4] = {};

    for (int k0 = 0; k0 < K; k0 += 128) {
        if (k0) __syncthreads();         // protect LDS reuse
#pragma unroll
        for (int inst = 0; inst < 8; ++inst) {
            int c = w * 8 + inst;
            int r = c * 4 + srow_in;
            int j = jp ^ (r & 7);        // logical chunk for this phys slot
            gload_lds16(A + (size_t)(m0 + r) * K + k0 + j * 8, &As[c * 512]);
            gload_lds16(W + (size_t)(n0 + r) * K + k0 + j * 8, &Ws[c * 512]);
        }
        __syncthreads();                 // drains vmcnt -> LDS valid
#pragma unroll
        for (int kq = 0; kq < 4; ++kq) {
            int jlog = kq * 4 + lkq;
            short8v a[4], b[4];
#pragma unroll
            for (int i = 0; i < 4; ++i) {
                int ri = wr * 64 + i * 16 + lr;
                a[i] = *reinterpret_cast<const short8v*>(&As[ri * 128 + (jlog ^ (ri & 7)) * 8]);
            }
#pragma unroll
            for (int jj = 0; jj < 4; ++jj) {
                int rj = wc * 64 + jj * 16 + lr;
                b[jj] = *reinterpret_cast<const short8v*>(&Ws[rj * 128 + (jlog ^ (rj & 7)) * 8]);
            }
#pragma unroll
            for (int i = 0; i < 4; ++i)
#pragma unroll
                for (int jj = 0; jj < 4; ++jj)
                    acc[i][jj] = __builtin_amdgcn_mfma_f32_16x16x32_bf16(
                        a[i], b[jj], acc[i][jj], 0, 0, 0);
        }
    }
    int cr0 = (lane >> 4) * 4;
    int cc = lane & 15;
#pragma unroll
    for (int i = 0; i < 4; ++i)
#pragma unroll
        for (int jj = 0; jj < 4; ++jj) {
            int col = n0 + wc * 64 + jj * 16 + cc;
            float bias = b1[col];
#pragma unroll
            for (int r = 0; r < 4; ++r) {
                int row = m0 + wr * 64 + i * 16 + cr0 + r;
                float v = acc[i][jj][r] + bias;
                if (relu) v = fmaxf(v, 0.f);
                if (Cf) Cf[(size_t)row * N + col] = v;
                else    Cb[(size_t)row * N + col] = f2b(v);
            }
        }
}

// ---------------------------------------------------------------- LSTM (MFMA matvec v3, frozen)
__global__ __launch_bounds__(256, 1) void lstm_kernel(
    const float* __restrict__ xW, const short* __restrict__ Whh_b,
    float* __restrict__ xout, short* __restrict__ xb_out)
{
    __shared__ __align__(16) short hb[2][Dm];
    int b = blockIdx.x;
    int tid = threadIdx.x;
    int w = tid >> 6;
    int lane = tid & 63;
    int lr = lane & 15;
    int lk = (lane >> 4) * 8;
    int cr0 = (lane >> 4) * 4;
    int qs = lr >> 2;
    int qr = lr & 3;

    short8v a[4][2][4];
#pragma unroll
    for (int g = 0; g < 4; ++g)
#pragma unroll
        for (int s = 0; s < 2; ++s)
#pragma unroll
            for (int k = 0; k < 4; ++k)
                a[g][s][k] = *reinterpret_cast<const short8v*>(
                    &Whh_b[(size_t)(g * 128 + w * 32 + s * 16 + lr) * Dm + k * 32 + lk]);

    const float* xwb = xW + (size_t)b * Lq * 512;
    float cpers = 0.f;
    if (tid < 64) reinterpret_cast<int*>(hb[0])[tid] = 0;

    f32x4 xwA[4][2], xwB[4][2];
#pragma unroll
    for (int g = 0; g < 4; ++g)
#pragma unroll
        for (int s = 0; s < 2; ++s) {
            xwA[g][s] = *reinterpret_cast<const f32x4*>(
                &xwb[(size_t)0 * 512 + g * 128 + w * 32 + s * 16 + cr0]);
            xwB[g][s] = *reinterpret_cast<const f32x4*>(
                &xwb[(size_t)1 * 512 + g * 128 + w * 32 + s * 16 + cr0]);
        }
    __syncthreads();

    auto step = [&](int t, f32x4 (&xwC)[4][2]) {
        int p = t & 1;
        short8v bf[4];
#pragma unroll
        for (int k = 0; k < 4; ++k)
            bf[k] = *reinterpret_cast<const short8v*>(&hb[p][k * 32 + lk]);
        f32x4 acc[4][2];
#pragma unroll
        for (int g = 0; g < 4; ++g)
#pragma unroll
            for (int s = 0; s < 2; ++s)
                acc[g][s] = xwC[g][s];
        int tp = (t + 2 < Lq) ? t + 2 : Lq - 1;
#pragma unroll
        for (int g = 0; g < 4; ++g)
#pragma unroll
            for (int s = 0; s < 2; ++s)
                xwC[g][s] = *reinterpret_cast<const f32x4*>(
                    &xwb[(size_t)tp * 512 + g * 128 + w * 32 + s * 16 + cr0]);
#pragma unroll
        for (int k = 0; k < 4; ++k)
#pragma unroll
            for (int g = 0; g < 4; ++g)
#pragma unroll
                for (int s = 0; s < 2; ++s)
                    acc[g][s] = __builtin_amdgcn_mfma_f32_16x16x32_bf16(
                        a[g][s][k], bf[k], acc[g][s], 0, 0, 0);
        if (lr < 8) {
            float iraw = 0.f, fraw = 0.f, graw = 0.f, oraw = 0.f;
#pragma unroll
            for (int s = 0; s < 2; ++s)
#pragma unroll
                for (int r = 0; r < 4; ++r)
                    if (qs == s && qr == r) {
                        iraw = acc[0][s][r]; fraw = acc[1][s][r];
                        graw = acc[2][s][r]; oraw = acc[3][s][r];
                    }
            float ig = fsig(iraw);
            float fg = fsig(fraw);
            float gg = fast_tanh(graw);
            float og = fsig(oraw);
            cpers = fg * cpers + ig * gg;
            float h = og * fast_tanh(cpers);
            int d = w * 32 + qs * 16 + cr0 + qr;
            short hv = f2b(h);
            hb[p ^ 1][d] = hv;
            size_t o = ((size_t)b * Lq + t) * Dm + d;
            xb_out[o] = hv;
            xout[o] = h;
        }
        asm volatile("s_waitcnt lgkmcnt(0)" ::: "memory");
        __builtin_amdgcn_s_barrier();
    };

    for (int t = 0; t < Lq; t += 2) {
        step(t, xwA);
        step(t + 1, xwB);
    }
}

// ------------------------------------------------------------- attention (bf16 qkv in)
__global__ __launch_bounds__(256) void attn_kernel(
    const short* __restrict__ qkvb, short* __restrict__ ctxb)
{
    __shared__ float Kb[Lq][16];
    __shared__ float Vb[Lq][16];
    int h = blockIdx.x & (NHh - 1);
    int b = blockIdx.x >> 3;
    int t = threadIdx.x;
    const short* base = qkvb + (size_t)b * Lq * 384;
    int hoff = h * 16;
    for (int i = t; i < Lq * 2; i += 256) {
        int row = i >> 1, half = i & 1;
        short8v kv = *reinterpret_cast<const short8v*>(&base[(size_t)row * 384 + 128 + hoff + half * 8]);
        short8v vv = *reinterpret_cast<const short8v*>(&base[(size_t)row * 384 + 256 + hoff + half * 8]);
#pragma unroll
        for (int e = 0; e < 8; ++e) {
            Kb[row][half * 8 + e] = b2f(kv[e]);
            Vb[row][half * 8 + e] = b2f(vv[e]);
        }
    }
    __syncthreads();
    for (int rr = 0; rr < 2; ++rr) {
        int l = t + rr * 256;
        short8v q0 = *reinterpret_cast<const short8v*>(&base[(size_t)l * 384 + hoff]);
        short8v q1 = *reinterpret_cast<const short8v*>(&base[(size_t)l * 384 + hoff + 8]);
        float q[16];
#pragma unroll
        for (int e = 0; e < 8; ++e) { q[e] = b2f(q0[e]); q[8 + e] = b2f(q1[e]); }
        float m = -1e30f, ssum = 0.f;
        float acc[16] = {};
        for (int jr = 0; jr < Lq; ++jr) {
            float s = 0.f;
#pragma unroll
            for (int cc = 0; cc < 16; ++cc) s += q[cc] * Kb[jr][cc];
            s *= 0.25f;
            if (s > m) {
                float corr = __expf(m - s);
                ssum *= corr;
#pragma unroll
                for (int cc = 0; cc < 16; ++cc) acc[cc] *= corr;
                m = s;
            }
            float p = __expf(s - m);
            ssum += p;
#pragma unroll
            for (int cc = 0; cc < 16; ++cc) acc[cc] += p * Vb[jr][cc];
        }
        float inv = __builtin_amdgcn_rcpf(ssum);
        short8v v0, v1;
#pragma unroll
        for (int cc = 0; cc < 8; ++cc) { v0[cc] = f2b(acc[cc] * inv); v1[cc] = f2b(acc[cc + 8] * inv); }
        short* o = ctxb + ((size_t)b * Lq + l) * Dm + hoff;
        *reinterpret_cast<short8v*>(o) = v0;
        *reinterpret_cast<short8v*>(o + 8) = v1;
    }
}

// ----------------------------------------------------- residual add + LN (+ bf16 mirror)
__global__ __launch_bounds__(256) void addln_kernel(
    float* __restrict__ x, const float* __restrict__ add,
    const float* __restrict__ g, const float* __restrict__ bta,
    short* __restrict__ xb)
{
    int wave = threadIdx.x >> 6;
    int lane = threadIdx.x & 63;
    int row = blockIdx.x * 4 + wave;
    float* xr = x + (size_t)row * Dm;
    const float* ar = add + (size_t)row * Dm;
    int d0 = lane * 2;
    float2 xv = *reinterpret_cast<const float2*>(&xr[d0]);
    float2 av = *reinterpret_cast<const float2*>(&ar[d0]);
    float v0 = xv.x + av.x, v1 = xv.y + av.y;
    float s = v0 + v1;
#pragma unroll
    for (int off = 32; off > 0; off >>= 1) s += __shfl_xor(s, off);
    float mu = s * (1.f / Dm);
    float e0 = v0 - mu, e1 = v1 - mu;
    float s2 = e0 * e0 + e1 * e1;
#pragma unroll
    for (int off = 32; off > 0; off >>= 1) s2 += __shfl_xor(s2, off);
    float rs = rsqrtf(s2 * (1.f / Dm) + EPSf);
    float o0 = e0 * rs * g[d0] + bta[d0];
    float o1 = e1 * rs * g[d0 + 1] + bta[d0 + 1];
    xr[d0] = o0;
    xr[d0 + 1] = o1;
    unsigned pk = (unsigned)(unsigned short)f2b(o0) | ((unsigned)(unsigned short)f2b(o1) << 16);
    *reinterpret_cast<unsigned*>(&xb[(size_t)row * Dm + d0]) = pk;
}

// --------------------------------------------------------------- head
__global__ void head_kernel(const float* __restrict__ x,
                            const float* __restrict__ head_w, const float* __restrict__ head_b,
                            const float* __restrict__ gw1, const float* __restrict__ gb1,
                            const float* __restrict__ gw2, const float* __restrict__ gb2,
                            const float* __restrict__ garch,
                            float* __restrict__ out)
{
    __shared__ float last[Dm];
    __shared__ float t1[Dm / 2];
    int b = blockIdx.x, t = threadIdx.x;
    if (t < Dm) last[t] = x[((size_t)b * Lq + (Lq - 1)) * Dm + t];
    __syncthreads();
    if (t < Dm / 2) {
        float s = gb1[t];
#pragma unroll 8
        for (int d = 0; d < Dm; ++d) s += last[d] * gw1[(size_t)t * Dm + d];
        t1[t] = fmaxf(s, 0.f);
    }
    __syncthreads();
    if (t < PLn) {
        float ai = head_b[t];
#pragma unroll 8
        for (int d = 0; d < Dm; ++d) ai += last[d] * head_w[(size_t)t * Dm + d];
        float gg = gb2[t];
#pragma unroll 8
        for (int j = 0; j < Dm / 2; ++j) gg += t1[j] * gw2[(size_t)t * (Dm / 2) + j];
        float gate = 1.f / (1.f + __expf(-gg));
        out[b * PLn + t] = garch[b * PLn + t] + gate * ai;
    }
}

extern "C" void kernel_launch(void* const* d_in, const int* in_sizes, int n_in,
                              void* d_out, int out_size, void* d_ws, size_t ws_size,
                              hipStream_t stream)
{
    const float* x_enc  = (const float*)d_in[0];
    const float* x_mark = (const float*)d_in[1];
    const float* conv_w = (const float*)d_in[4];
    const float* temp_w = (const float*)d_in[5];
    const float* Wih    = (const float*)d_in[6];
    const float* Whh    = (const float*)d_in[7];
    const float* bih    = (const float*)d_in[8];
    const float* bhh    = (const float*)d_in[9];
    const float* Wqkv   = (const float*)d_in[10];
    const float* bqkv   = (const float*)d_in[11];
    const float* Wo     = (const float*)d_in[12];
    const float* bo     = (const float*)d_in[13];
    const float* ln1g   = (const float*)d_in[14];
    const float* ln1b   = (const float*)d_in[15];
    const float* W1     = (const float*)d_in[16];
    const float* b1     = (const float*)d_in[17];
    const float* W2     = (const float*)d_in[18];
    const float* b2     = (const float*)d_in[19];
    const float* ln2g   = (const float*)d_in[20];
    const float* ln2b   = (const float*)d_in[21];
    const float* head_w = (const float*)d_in[22];
    const float* head_b = (const float*)d_in[23];
    const float* gw1    = (const float*)d_in[24];
    const float* gb1    = (const float*)d_in[25];
    const float* gw2    = (const float*)d_in[26];
    const float* gb2    = (const float*)d_in[27];
    const float* g_omega= (const float*)d_in[28];
    const float* g_alpha= (const float*)d_in[29];
    const float* g_beta = (const float*)d_in[30];
    const float* g_h0   = (const float*)d_in[31];

    const int M = Bn * Lq;                    // 32768
    float* ws    = (float*)d_ws;
    float* garch = ws;                        // 6144 used
    float* biassum = ws + 6144;               // 512 floats (bih+bhh)
    float* regionA = ws + 8192;               // 4,194,304 floats
    short* xb   = (short*)regionA;            //   bf16 x mirror (after lstm)
    short* ctxb = (short*)(regionA + 2097152);//   bf16 ctx
    float* xWr  = regionA + 4194304;          // 16,777,216 floats
    float* xW   = xWr;                        //   fp32 xW (dead after lstm)
    short* ff1b = (short*)xWr;                //   bf16 ff1 chunk (16384x2048)
    float* x    = xWr + 16777216;             // 4,194,304 floats (live all launch)
    float* qkvr = x + 4194304;                // 12,582,912 floats
    short* encb = (short*)qkvr;               //   bf16 enc (dead after xW gemm)
    short* qkvb = (short*)qkvr;               //   bf16 qkv (dead once ctx built)
    float* tmp  = qkvr;                       //   fp32 tmp (aliases qkvb after attn)
    float* wbr  = qkvr + 12582912;            // bf16 weight mirrors
    short* Wqkv_b = (short*)wbr;              // 98,304
    short* Wo_b   = Wqkv_b + 98304;           // 32,768
    short* W1_b   = Wo_b + 32768;             // 524,288
    short* W2_b   = W1_b + 524288;            // 524,288
    short* Whh_bb = W2_b + 524288;            // 65,536
    short* Wih_b  = Whh_bb + 65536;           // 65,536

    cvt_kernel<<<(98304 + 255) / 256, 256, 0, stream>>>(Wqkv, Wqkv_b, 98304);
    cvt_kernel<<<(32768 + 255) / 256, 256, 0, stream>>>(Wo, Wo_b, 32768);
    cvt_kernel<<<(524288 + 255) / 256, 256, 0, stream>>>(W1, W1_b, 524288);
    cvt_kernel<<<(524288 + 255) / 256, 256, 0, stream>>>(W2, W2_b, 524288);
    cvt_kernel<<<(65536 + 255) / 256, 256, 0, stream>>>(Whh, Whh_bb, 65536);
    cvt_kernel<<<(65536 + 255) / 256, 256, 0, stream>>>(Wih, Wih_b, 65536);
    biassum_kernel<<<2, 256, 0, stream>>>(bih, bhh, biassum, 512);

    garch_kernel<<<1, 64, 0, stream>>>(x_enc, g_omega, g_alpha, g_beta, g_h0, garch);
    enc_kernel<<<(Bn * Lq * Dm) / 256, 256, 0, stream>>>(x_enc, x_mark, conv_w, temp_w, encb);
    gemm_stage<<<dim3(M / 128, 512 / 128), 256, 0, stream>>>(
        encb, Wih_b, biassum, xW, nullptr, M, 512, Dm, 0);
    lstm_kernel<<<Bn, 256, 0, stream>>>(xW, Whh_bb, x, xb);

    for (int li = 0; li < ELn; ++li) {
        gemm_stage<<<dim3(M / 128, 384 / 128), 256, 0, stream>>>(
            xb, Wqkv_b + (size_t)li * 384 * Dm, bqkv + li * 384, nullptr, qkvb, M, 384, Dm, 0);
        attn_kernel<<<Bn * NHh, 256, 0, stream>>>(qkvb, ctxb);
        gemm_stage<<<dim3(M / 128, Dm / 128), 256, 0, stream>>>(
            ctxb, Wo_b + (size_t)li * Dm * Dm, bo + li * Dm, tmp, nullptr, M, Dm, Dm, 0);
        addln_kernel<<<M / 4, 256, 0, stream>>>(x, tmp, ln1g + li * Dm, ln1b + li * Dm, xb);
        for (int mc = 0; mc < 2; ++mc) {
            const int MC = M / 2;             // 16384 rows
            gemm_stage<<<dim3(MC / 128, DFFn / 128), 256, 0, stream>>>(
                xb + (size_t)mc * MC * Dm, W1_b + (size_t)li * DFFn * Dm, b1 + li * DFFn,
                nullptr, ff1b, MC, DFFn, Dm, 1);
            gemm_stage<<<dim3(MC / 128, Dm / 128), 256, 0, stream>>>(
                ff1b, W2_b + (size_t)li * Dm * DFFn, b2 + li * Dm,
                tmp + (size_t)mc * MC * Dm, nullptr, MC, Dm, DFFn, 0);
        }
        addln_kernel<<<M / 4, 256, 0, stream>>>(x, tmp, ln2g + li * Dm, ln2b + li * Dm, xb);
    }
    head_kernel<<<Bn, 128, 0, stream>>>(x, head_w, head_b, gw1, gb1, gw2, gb2, garch,
                                        (float*)d_out);
}

// Round 12
// 1204.751 us; speedup vs baseline: 1.2526x; 1.0849x over previous
//
#include <hip/hip_runtime.h>
#include <hip/hip_bf16.h>
#include <math.h>

#define Bn 64
#define Lq 512
#define Dm 128
#define NHh 8
#define ELn 2
#define PLn 96
#define CINn 8
#define DFFn 2048
#define NTFn 4
#define EPSf 1e-5f

typedef __attribute__((ext_vector_type(8))) short short8v;
typedef __attribute__((ext_vector_type(4))) float f32x4;

__device__ __forceinline__ short f2b(float f) {
    union { float f; unsigned u; } v; v.f = f;
    unsigned r = v.u + 0x7fff + ((v.u >> 16) & 1);
    return (short)(r >> 16);
}
__device__ __forceinline__ float b2f(short s) {
    union { unsigned u; float f; } v;
    v.u = ((unsigned)(unsigned short)s) << 16;
    return v.f;
}
__device__ __forceinline__ float fsig(float x) {
    return __builtin_amdgcn_rcpf(1.f + __expf(-x));
}
__device__ __forceinline__ float fast_tanh(float x) {
    float ax = fabsf(x);
    float e = __expf(2.f * ax);
    float t = 1.f - 2.f * __builtin_amdgcn_rcpf(e + 1.f);
    return copysignf(t, x);
}
__device__ __forceinline__ void gload_lds16(const short* g, short* l) {
    __builtin_amdgcn_global_load_lds(
        (const __attribute__((address_space(1))) void*)g,
        (__attribute__((address_space(3))) void*)l, 16, 0, 0);
}

// ---------------- fused prep: all weight bf16 conversions + bias sum (1 launch)
__global__ void prep_kernel(const float* __restrict__ Wqkv, const float* __restrict__ Wo,
                            const float* __restrict__ W1, const float* __restrict__ W2,
                            const float* __restrict__ Whh, const float* __restrict__ Wih,
                            const float* __restrict__ bih, const float* __restrict__ bhh,
                            short* __restrict__ Wqkv_b, short* __restrict__ Wo_b,
                            short* __restrict__ W1_b, short* __restrict__ W2_b,
                            short* __restrict__ Whh_b, short* __restrict__ Wih_b,
                            float* __restrict__ biassum)
{
    int i = blockIdx.x * 256 + threadIdx.x;
    if (i < 98304)        Wqkv_b[i] = f2b(Wqkv[i]);
    else if (i < 131072)  { int j = i - 98304;   Wo_b[j]  = f2b(Wo[j]); }
    else if (i < 655360)  { int j = i - 131072;  W1_b[j]  = f2b(W1[j]); }
    else if (i < 1179648) { int j = i - 655360;  W2_b[j]  = f2b(W2[j]); }
    else if (i < 1245184) { int j = i - 1179648; Whh_b[j] = f2b(Whh[j]); }
    else if (i < 1310720) { int j = i - 1245184; Wih_b[j] = f2b(Wih[j]); }
    else if (i < 1311232) { int j = i - 1310720; biassum[j] = bih[j] + bhh[j]; }
}

// ------------------------------- conv + temporal + pos (bf16 out) + fused GARCH
__global__ void enc_kernel(const float* __restrict__ x_enc,
                           const float* __restrict__ x_mark,
                           const float* __restrict__ conv_w,
                           const float* __restrict__ temp_w,
                           short* __restrict__ encb,
                           const float* __restrict__ g_omega,
                           const float* __restrict__ g_alpha,
                           const float* __restrict__ g_beta,
                           const float* __restrict__ g_h0,
                           float* __restrict__ garch)
{
    int idx = blockIdx.x * blockDim.x + threadIdx.x;   // over B*L*D
    int d = idx & (Dm - 1);
    int l = (idx >> 7) & (Lq - 1);
    int b = idx >> 16;
    int lm = (l + Lq - 1) & (Lq - 1);
    int lp = (l + 1) & (Lq - 1);
    const float* xb = x_enc + (size_t)b * Lq * CINn;
    const float* w  = conv_w + (size_t)d * CINn * 3;
    float acc = 0.f;
#pragma unroll
    for (int ci = 0; ci < CINn; ++ci) {
        acc += xb[(size_t)lm * CINn + ci] * w[ci * 3 + 0];
        acc += xb[(size_t)l  * CINn + ci] * w[ci * 3 + 1];
        acc += xb[(size_t)lp * CINn + ci] * w[ci * 3 + 2];
    }
    const float* mk = x_mark + ((size_t)b * Lq + l) * NTFn;
    const float* tw = temp_w + (size_t)d * NTFn;
#pragma unroll
    for (int f = 0; f < NTFn; ++f) acc += mk[f] * tw[f];
    float dv = __expf(-(float)(d & ~1) * (9.210340371976184f / 128.f));
    float ang = (float)l * dv;
    acc += (d & 1) ? cosf(ang) : sinf(ang);
    encb[idx] = f2b(acc);

    // GARCH fused into block 0 (overlaps with the other 16K blocks)
    if (blockIdx.x == 0 && threadIdx.x < Bn) {
        int bb = threadIdx.x;
        float omega = log1pf(__expf(g_omega[0]));
        float alpha = 0.2f / (1.f + __expf(-g_alpha[0]));
        float beta  = 0.8f / (1.f + __expf(-g_beta[0]));
        float h = log1pf(__expf(g_h0[0]));
        const float* xe = x_enc + (size_t)bb * Lq * CINn + (CINn - 2);
        for (int t = 0; t < Lq; ++t) {
            float r = xe[(size_t)t * CINn];
            h = omega + alpha * r * r + beta * h;
        }
        float ab = alpha + beta;
        for (int p = 0; p < PLn; ++p) {
            garch[bb * PLn + p] = sqrtf(h);
            h = omega + ab * h;
        }
    }
}

// ---------------- staged+swizzled bf16 MFMA GEMM, tile 128x128, BK=128
__global__ __launch_bounds__(256) void gemm_stage(
    const short* __restrict__ A, const short* __restrict__ W,
    const float* __restrict__ b1,
    float* __restrict__ Cf, short* __restrict__ Cb,
    int M, int N, int K, int relu)
{
    __shared__ short As[128 * 128];
    __shared__ short Ws[128 * 128];
    int tid = threadIdx.x;
    int w = tid >> 6, lane = tid & 63;
    int wr = w >> 1, wc = w & 1;
    int m0 = blockIdx.x * 128, n0 = blockIdx.y * 128;
    int lr = lane & 15;
    int lkq = lane >> 4;
    int srow_in = lane >> 4;
    int jp = lane & 15;
    f32x4 acc[4][4] = {};

    for (int k0 = 0; k0 < K; k0 += 128) {
        if (k0) __syncthreads();
#pragma unroll
        for (int inst = 0; inst < 8; ++inst) {
            int c = w * 8 + inst;
            int r = c * 4 + srow_in;
            int j = jp ^ (r & 7);
            gload_lds16(A + (size_t)(m0 + r) * K + k0 + j * 8, &As[c * 512]);
            gload_lds16(W + (size_t)(n0 + r) * K + k0 + j * 8, &Ws[c * 512]);
        }
        __syncthreads();
#pragma unroll
        for (int kq = 0; kq < 4; ++kq) {
            int jlog = kq * 4 + lkq;
            short8v a[4], b[4];
#pragma unroll
            for (int i = 0; i < 4; ++i) {
                int ri = wr * 64 + i * 16 + lr;
                a[i] = *reinterpret_cast<const short8v*>(&As[ri * 128 + (jlog ^ (ri & 7)) * 8]);
            }
#pragma unroll
            for (int jj = 0; jj < 4; ++jj) {
                int rj = wc * 64 + jj * 16 + lr;
                b[jj] = *reinterpret_cast<const short8v*>(&Ws[rj * 128 + (jlog ^ (rj & 7)) * 8]);
            }
#pragma unroll
            for (int i = 0; i < 4; ++i)
#pragma unroll
                for (int jj = 0; jj < 4; ++jj)
                    acc[i][jj] = __builtin_amdgcn_mfma_f32_16x16x32_bf16(
                        a[i], b[jj], acc[i][jj], 0, 0, 0);
        }
    }
    int cr0 = (lane >> 4) * 4;
    int cc = lane & 15;
#pragma unroll
    for (int i = 0; i < 4; ++i)
#pragma unroll
        for (int jj = 0; jj < 4; ++jj) {
            int col = n0 + wc * 64 + jj * 16 + cc;
            float bias = b1[col];
#pragma unroll
            for (int r = 0; r < 4; ++r) {
                int row = m0 + wr * 64 + i * 16 + cr0 + r;
                float v = acc[i][jj][r] + bias;
                if (relu) v = fmaxf(v, 0.f);
                if (Cf) Cf[(size_t)row * N + col] = v;
                else    Cb[(size_t)row * N + col] = f2b(v);
            }
        }
}

// ---------------------------------------------------------------- LSTM (MFMA matvec v4)
// v4: zero-init MFMA (no C-in fragment); owner lanes load only their own 4
// gate biases (4 scalar loads/step, distance-4 prefetch, static buffers);
// h global stores batched 8 steps; bf16-only output.
__global__ __launch_bounds__(256, 1) void lstm_kernel(
    const float* __restrict__ xW, const short* __restrict__ Whh_b,
    short* __restrict__ xb_out)
{
    __shared__ __align__(16) short hb[2][Dm];
    int b = blockIdx.x;
    int tid = threadIdx.x;
    int w = tid >> 6;
    int lane = tid & 63;
    int lr = lane & 15;
    int lk = (lane >> 4) * 8;
    int cr0 = (lane >> 4) * 4;
    int qs = lr >> 2;
    int qr = lr & 3;
    int d = w * 32 + qs * 16 + cr0 + qr;   // owned unit (valid for lr<8)
    bool owner = (lr < 8);

    short8v a[4][2][4];
#pragma unroll
    for (int g = 0; g < 4; ++g)
#pragma unroll
        for (int s = 0; s < 2; ++s)
#pragma unroll
            for (int k = 0; k < 4; ++k)
                a[g][s][k] = *reinterpret_cast<const short8v*>(
                    &Whh_b[(size_t)(g * 128 + w * 32 + s * 16 + lr) * Dm + k * 32 + lk]);

    const float* xwb = xW + (size_t)b * Lq * 512;
    float cpers = 0.f;
    if (tid < 64) reinterpret_cast<int*>(hb[0])[tid] = 0;

    // owner-lane xw prefetch: 4 static buffers, distance 4
    float xg[4][4];
    if (owner) {
#pragma unroll
        for (int pb = 0; pb < 4; ++pb)
#pragma unroll
            for (int g = 0; g < 4; ++g)
                xg[pb][g] = xwb[(size_t)pb * 512 + g * 128 + d];
    }
    short* xo = xb_out + (size_t)b * Lq * Dm + d;
    short hsv[8];
    __syncthreads();

    for (int tb = 0; tb < Lq; tb += 8) {
#pragma unroll
        for (int s8 = 0; s8 < 8; ++s8) {
            int t = tb + s8;
            // B-fragments: h bf16 broadcast
            short8v bf[4];
#pragma unroll
            for (int k = 0; k < 4; ++k)
                bf[k] = *reinterpret_cast<const short8v*>(&hb[s8 & 1][k * 32 + lk]);
            f32x4 acc[4][2] = {};
#pragma unroll
            for (int k = 0; k < 4; ++k)
#pragma unroll
                for (int g = 0; g < 4; ++g)
#pragma unroll
                    for (int s = 0; s < 2; ++s)
                        acc[g][s] = __builtin_amdgcn_mfma_f32_16x16x32_bf16(
                            a[g][s][k], bf[k], acc[g][s], 0, 0, 0);
            if (owner) {
                float iraw = 0.f, fraw = 0.f, graw = 0.f, oraw = 0.f;
#pragma unroll
                for (int s = 0; s < 2; ++s)
#pragma unroll
                    for (int r = 0; r < 4; ++r)
                        if (qs == s && qr == r) {
                            iraw = acc[0][s][r]; fraw = acc[1][s][r];
                            graw = acc[2][s][r]; oraw = acc[3][s][r];
                        }
                iraw += xg[s8 & 3][0];
                fraw += xg[s8 & 3][1];
                graw += xg[s8 & 3][2];
                oraw += xg[s8 & 3][3];
                // refill consumed buffer with t+4 (distance-4 slack ~3 steps)
                int tp = (t + 4 < Lq) ? t + 4 : Lq - 1;
#pragma unroll
                for (int g = 0; g < 4; ++g)
                    xg[s8 & 3][g] = xwb[(size_t)tp * 512 + g * 128 + d];
                float ig = fsig(iraw);
                float fg = fsig(fraw);
                float gg = fast_tanh(graw);
                float og = fsig(oraw);
                cpers = fg * cpers + ig * gg;
                float h = og * fast_tanh(cpers);
                short hv = f2b(h);
                hsv[s8] = hv;
                hb[(s8 & 1) ^ 1][d] = hv;
            }
            asm volatile("s_waitcnt lgkmcnt(0)" ::: "memory");
            __builtin_amdgcn_s_barrier();
        }
        // batched h store burst (once per 8 steps)
        if (owner) {
#pragma unroll
            for (int s8 = 0; s8 < 8; ++s8)
                xo[(size_t)(tb + s8) * Dm] = hsv[s8];
        }
    }
}

// ------------------------------------------------------------- attention (bf16 qkv in)
__global__ __launch_bounds__(256) void attn_kernel(
    const short* __restrict__ qkvb, short* __restrict__ ctxb)
{
    __shared__ float Kb[Lq][16];
    __shared__ float Vb[Lq][16];
    int h = blockIdx.x & (NHh - 1);
    int b = blockIdx.x >> 3;
    int t = threadIdx.x;
    const short* base = qkvb + (size_t)b * Lq * 384;
    int hoff = h * 16;
    for (int i = t; i < Lq * 2; i += 256) {
        int row = i >> 1, half = i & 1;
        short8v kv = *reinterpret_cast<const short8v*>(&base[(size_t)row * 384 + 128 + hoff + half * 8]);
        short8v vv = *reinterpret_cast<const short8v*>(&base[(size_t)row * 384 + 256 + hoff + half * 8]);
#pragma unroll
        for (int e = 0; e < 8; ++e) {
            Kb[row][half * 8 + e] = b2f(kv[e]);
            Vb[row][half * 8 + e] = b2f(vv[e]);
        }
    }
    __syncthreads();
    for (int rr = 0; rr < 2; ++rr) {
        int l = t + rr * 256;
        short8v q0 = *reinterpret_cast<const short8v*>(&base[(size_t)l * 384 + hoff]);
        short8v q1 = *reinterpret_cast<const short8v*>(&base[(size_t)l * 384 + hoff + 8]);
        float q[16];
#pragma unroll
        for (int e = 0; e < 8; ++e) { q[e] = b2f(q0[e]); q[8 + e] = b2f(q1[e]); }
        float m = -1e30f, ssum = 0.f;
        float acc[16] = {};
        for (int jr = 0; jr < Lq; ++jr) {
            float s = 0.f;
#pragma unroll
            for (int cc = 0; cc < 16; ++cc) s += q[cc] * Kb[jr][cc];
            s *= 0.25f;
            if (s > m) {
                float corr = __expf(m - s);
                ssum *= corr;
#pragma unroll
                for (int cc = 0; cc < 16; ++cc) acc[cc] *= corr;
                m = s;
            }
            float p = __expf(s - m);
            ssum += p;
#pragma unroll
            for (int cc = 0; cc < 16; ++cc) acc[cc] += p * Vb[jr][cc];
        }
        float inv = __builtin_amdgcn_rcpf(ssum);
        short8v v0, v1;
#pragma unroll
        for (int cc = 0; cc < 8; ++cc) { v0[cc] = f2b(acc[cc] * inv); v1[cc] = f2b(acc[cc + 8] * inv); }
        short* o = ctxb + ((size_t)b * Lq + l) * Dm + hoff;
        *reinterpret_cast<short8v*>(o) = v0;
        *reinterpret_cast<short8v*>(o + 8) = v1;
    }
}

// -------------------- residual add + LN (+ bf16 mirror); optional bf16 base
__global__ __launch_bounds__(256) void addln_kernel(
    float* __restrict__ x, const short* __restrict__ base_b,
    const float* __restrict__ add,
    const float* __restrict__ g, const float* __restrict__ bta,
    short* __restrict__ xb)
{
    int wave = threadIdx.x >> 6;
    int lane = threadIdx.x & 63;
    int row = blockIdx.x * 4 + wave;
    float* xr = x + (size_t)row * Dm;
    const float* ar = add + (size_t)row * Dm;
    int d0 = lane * 2;
    float b0, b1v;
    if (base_b) {
        unsigned pk = *reinterpret_cast<const unsigned*>(&base_b[(size_t)row * Dm + d0]);
        b0 = b2f((short)(pk & 0xffff));
        b1v = b2f((short)(pk >> 16));
    } else {
        float2 xv = *reinterpret_cast<const float2*>(&xr[d0]);
        b0 = xv.x; b1v = xv.y;
    }
    float2 av = *reinterpret_cast<const float2*>(&ar[d0]);
    float v0 = b0 + av.x, v1 = b1v + av.y;
    float s = v0 + v1;
#pragma unroll
    for (int off = 32; off > 0; off >>= 1) s += __shfl_xor(s, off);
    float mu = s * (1.f / Dm);
    float e0 = v0 - mu, e1 = v1 - mu;
    float s2 = e0 * e0 + e1 * e1;
#pragma unroll
    for (int off = 32; off > 0; off >>= 1) s2 += __shfl_xor(s2, off);
    float rs = rsqrtf(s2 * (1.f / Dm) + EPSf);
    float o0 = e0 * rs * g[d0] + bta[d0];
    float o1 = e1 * rs * g[d0 + 1] + bta[d0 + 1];
    xr[d0] = o0;
    xr[d0 + 1] = o1;
    unsigned pk = (unsigned)(unsigned short)f2b(o0) | ((unsigned)(unsigned short)f2b(o1) << 16);
    *reinterpret_cast<unsigned*>(&xb[(size_t)row * Dm + d0]) = pk;
}

// --------------------------------------------------------------- head
__global__ void head_kernel(const float* __restrict__ x,
                            const float* __restrict__ head_w, const float* __restrict__ head_b,
                            const float* __restrict__ gw1, const float* __restrict__ gb1,
                            const float* __restrict__ gw2, const float* __restrict__ gb2,
                            const float* __restrict__ garch,
                            float* __restrict__ out)
{
    __shared__ float last[Dm];
    __shared__ float t1[Dm / 2];
    int b = blockIdx.x, t = threadIdx.x;
    if (t < Dm) last[t] = x[((size_t)b * Lq + (Lq - 1)) * Dm + t];
    __syncthreads();
    if (t < Dm / 2) {
        float s = gb1[t];
#pragma unroll 8
        for (int d = 0; d < Dm; ++d) s += last[d] * gw1[(size_t)t * Dm + d];
        t1[t] = fmaxf(s, 0.f);
    }
    __syncthreads();
    if (t < PLn) {
        float ai = head_b[t];
#pragma unroll 8
        for (int d = 0; d < Dm; ++d) ai += last[d] * head_w[(size_t)t * Dm + d];
        float gg = gb2[t];
#pragma unroll 8
        for (int j = 0; j < Dm / 2; ++j) gg += t1[j] * gw2[(size_t)t * (Dm / 2) + j];
        float gate = 1.f / (1.f + __expf(-gg));
        out[b * PLn + t] = garch[b * PLn + t] + gate * ai;
    }
}

extern "C" void kernel_launch(void* const* d_in, const int* in_sizes, int n_in,
                              void* d_out, int out_size, void* d_ws, size_t ws_size,
                              hipStream_t stream)
{
    const float* x_enc  = (const float*)d_in[0];
    const float* x_mark = (const float*)d_in[1];
    const float* conv_w = (const float*)d_in[4];
    const float* temp_w = (const float*)d_in[5];
    const float* Wih    = (const float*)d_in[6];
    const float* Whh    = (const float*)d_in[7];
    const float* bih    = (const float*)d_in[8];
    const float* bhh    = (const float*)d_in[9];
    const float* Wqkv   = (const float*)d_in[10];
    const float* bqkv   = (const float*)d_in[11];
    const float* Wo     = (const float*)d_in[12];
    const float* bo     = (const float*)d_in[13];
    const float* ln1g   = (const float*)d_in[14];
    const float* ln1b   = (const float*)d_in[15];
    const float* W1     = (const float*)d_in[16];
    const float* b1     = (const float*)d_in[17];
    const float* W2     = (const float*)d_in[18];
    const float* b2     = (const float*)d_in[19];
    const float* ln2g   = (const float*)d_in[20];
    const float* ln2b   = (const float*)d_in[21];
    const float* head_w = (const float*)d_in[22];
    const float* head_b = (const float*)d_in[23];
    const float* gw1    = (const float*)d_in[24];
    const float* gb1    = (const float*)d_in[25];
    const float* gw2    = (const float*)d_in[26];
    const float* gb2    = (const float*)d_in[27];
    const float* g_omega= (const float*)d_in[28];
    const float* g_alpha= (const float*)d_in[29];
    const float* g_beta = (const float*)d_in[30];
    const float* g_h0   = (const float*)d_in[31];

    const int M = Bn * Lq;                    // 32768
    float* ws    = (float*)d_ws;
    float* garch = ws;                        // 6144 used
    float* biassum = ws + 6144;               // 512 floats (bih+bhh)
    float* regionA = ws + 8192;               // 4,194,304 floats
    short* xb   = (short*)regionA;            //   bf16 x mirror (after lstm)
    short* ctxb = (short*)(regionA + 2097152);//   bf16 ctx
    float* xWr  = regionA + 4194304;          // 16,777,216 floats
    float* xW   = xWr;                        //   fp32 xW (dead after lstm)
    short* ff1b = (short*)xWr;                //   bf16 ff1 chunk (16384x2048)
    float* x    = xWr + 16777216;             // 4,194,304 floats (live all launch)
    float* qkvr = x + 4194304;                // 12,582,912 floats
    short* encb = (short*)qkvr;               //   bf16 enc (dead after xW gemm)
    short* qkvb = (short*)qkvr;               //   bf16 qkv (dead once ctx built)
    float* tmp  = qkvr;                       //   fp32 tmp (aliases qkvb after attn)
    float* wbr  = qkvr + 12582912;            // bf16 weight mirrors
    short* Wqkv_b = (short*)wbr;              // 98,304
    short* Wo_b   = Wqkv_b + 98304;           // 32,768
    short* W1_b   = Wo_b + 32768;             // 524,288
    short* W2_b   = W1_b + 524288;            // 524,288
    short* Whh_bb = W2_b + 524288;            // 65,536
    short* Wih_b  = Whh_bb + 65536;           // 65,536

    prep_kernel<<<5122, 256, 0, stream>>>(Wqkv, Wo, W1, W2, Whh, Wih, bih, bhh,
                                          Wqkv_b, Wo_b, W1_b, W2_b, Whh_bb, Wih_b, biassum);
    enc_kernel<<<(Bn * Lq * Dm) / 256, 256, 0, stream>>>(
        x_enc, x_mark, conv_w, temp_w, encb, g_omega, g_alpha, g_beta, g_h0, garch);
    gemm_stage<<<dim3(M / 128, 512 / 128), 256, 0, stream>>>(
        encb, Wih_b, biassum, xW, nullptr, M, 512, Dm, 0);
    lstm_kernel<<<Bn, 256, 0, stream>>>(xW, Whh_bb, xb);

    for (int li = 0; li < ELn; ++li) {
        gemm_stage<<<dim3(M / 128, 384 / 128), 256, 0, stream>>>(
            xb, Wqkv_b + (size_t)li * 384 * Dm, bqkv + li * 384, nullptr, qkvb, M, 384, Dm, 0);
        attn_kernel<<<Bn * NHh, 256, 0, stream>>>(qkvb, ctxb);
        gemm_stage<<<dim3(M / 128, Dm / 128), 256, 0, stream>>>(
            ctxb, Wo_b + (size_t)li * Dm * Dm, bo + li * Dm, tmp, nullptr, M, Dm, Dm, 0);
        addln_kernel<<<M / 4, 256, 0, stream>>>(
            x, (li == 0) ? xb : nullptr, tmp, ln1g + li * Dm, ln1b + li * Dm, xb);
        for (int mc = 0; mc < 2; ++mc) {
            const int MC = M / 2;             // 16384 rows
            gemm_stage<<<dim3(MC / 128, DFFn / 128), 256, 0, stream>>>(
                xb + (size_t)mc * MC * Dm, W1_b + (size_t)li * DFFn * Dm, b1 + li * DFFn,
                nullptr, ff1b, MC, DFFn, Dm, 1);
            gemm_stage<<<dim3(MC / 128, Dm / 128), 256, 0, stream>>>(
                ff1b, W2_b + (size_t)li * Dm * DFFn, b2 + li * Dm,
                tmp + (size_t)mc * MC * Dm, nullptr, MC, Dm, DFFn, 0);
        }
        addln_kernel<<<M / 4, 256, 0, stream>>>(
            x, nullptr, tmp, ln2g + li * Dm, ln2b + li * Dm, xb);
    }
    head_kernel<<<Bn, 128, 0, stream>>>(x, head_w, head_b, gw1, gb1, gw2, gb2, garch,
                                        (float*)d_out);
}

// Round 13
// 1187.099 us; speedup vs baseline: 1.2712x; 1.0149x over previous
//
#include <hip/hip_runtime.h>
#include <hip/hip_bf16.h>
#include <math.h>

#define Bn 64
#define Lq 512
#define Dm 128
#define NHh 8
#define ELn 2
#define PLn 96
#define CINn 8
#define DFFn 2048
#define NTFn 4
#define EPSf 1e-5f

typedef __attribute__((ext_vector_type(8))) short short8v;
typedef __attribute__((ext_vector_type(4))) float f32x4;

__device__ __forceinline__ short f2b(float f) {
    union { float f; unsigned u; } v; v.f = f;
    unsigned r = v.u + 0x7fff + ((v.u >> 16) & 1);
    return (short)(r >> 16);
}
__device__ __forceinline__ float b2f(short s) {
    union { unsigned u; float f; } v;
    v.u = ((unsigned)(unsigned short)s) << 16;
    return v.f;
}
__device__ __forceinline__ float fsig(float x) {
    return __builtin_amdgcn_rcpf(1.f + __expf(-x));
}
__device__ __forceinline__ float fast_tanh(float x) {
    float ax = fabsf(x);
    float e = __expf(2.f * ax);
    float t = 1.f - 2.f * __builtin_amdgcn_rcpf(e + 1.f);
    return copysignf(t, x);
}
__device__ __forceinline__ void gload_lds16(const short* g, short* l) {
    __builtin_amdgcn_global_load_lds(
        (const __attribute__((address_space(1))) void*)g,
        (__attribute__((address_space(3))) void*)l, 16, 0, 0);
}
__device__ __forceinline__ void gload_lds16f(const float* g, float* l) {
    __builtin_amdgcn_global_load_lds(
        (const __attribute__((address_space(1))) void*)g,
        (__attribute__((address_space(3))) void*)l, 16, 0, 0);
}

// ---------------- fused prep: all weight bf16 conversions + bias sum (1 launch)
__global__ void prep_kernel(const float* __restrict__ Wqkv, const float* __restrict__ Wo,
                            const float* __restrict__ W1, const float* __restrict__ W2,
                            const float* __restrict__ Whh, const float* __restrict__ Wih,
                            const float* __restrict__ bih, const float* __restrict__ bhh,
                            short* __restrict__ Wqkv_b, short* __restrict__ Wo_b,
                            short* __restrict__ W1_b, short* __restrict__ W2_b,
                            short* __restrict__ Whh_b, short* __restrict__ Wih_b,
                            float* __restrict__ biassum)
{
    int i = blockIdx.x * 256 + threadIdx.x;
    if (i < 98304)        Wqkv_b[i] = f2b(Wqkv[i]);
    else if (i < 131072)  { int j = i - 98304;   Wo_b[j]  = f2b(Wo[j]); }
    else if (i < 655360)  { int j = i - 131072;  W1_b[j]  = f2b(W1[j]); }
    else if (i < 1179648) { int j = i - 655360;  W2_b[j]  = f2b(W2[j]); }
    else if (i < 1245184) { int j = i - 1179648; Whh_b[j] = f2b(Whh[j]); }
    else if (i < 1310720) { int j = i - 1245184; Wih_b[j] = f2b(Wih[j]); }
    else if (i < 1311232) { int j = i - 1310720; biassum[j] = bih[j] + bhh[j]; }
}

// ------------------------------- conv + temporal + pos (bf16 out) + fused GARCH
__global__ void enc_kernel(const float* __restrict__ x_enc,
                           const float* __restrict__ x_mark,
                           const float* __restrict__ conv_w,
                           const float* __restrict__ temp_w,
                           short* __restrict__ encb,
                           const float* __restrict__ g_omega,
                           const float* __restrict__ g_alpha,
                           const float* __restrict__ g_beta,
                           const float* __restrict__ g_h0,
                           float* __restrict__ garch)
{
    int idx = blockIdx.x * blockDim.x + threadIdx.x;   // over B*L*D
    int d = idx & (Dm - 1);
    int l = (idx >> 7) & (Lq - 1);
    int b = idx >> 16;
    int lm = (l + Lq - 1) & (Lq - 1);
    int lp = (l + 1) & (Lq - 1);
    const float* xb = x_enc + (size_t)b * Lq * CINn;
    const float* w  = conv_w + (size_t)d * CINn * 3;
    float acc = 0.f;
#pragma unroll
    for (int ci = 0; ci < CINn; ++ci) {
        acc += xb[(size_t)lm * CINn + ci] * w[ci * 3 + 0];
        acc += xb[(size_t)l  * CINn + ci] * w[ci * 3 + 1];
        acc += xb[(size_t)lp * CINn + ci] * w[ci * 3 + 2];
    }
    const float* mk = x_mark + ((size_t)b * Lq + l) * NTFn;
    const float* tw = temp_w + (size_t)d * NTFn;
#pragma unroll
    for (int f = 0; f < NTFn; ++f) acc += mk[f] * tw[f];
    float dv = __expf(-(float)(d & ~1) * (9.210340371976184f / 128.f));
    float ang = (float)l * dv;
    acc += (d & 1) ? cosf(ang) : sinf(ang);
    encb[idx] = f2b(acc);

    if (blockIdx.x == 0 && threadIdx.x < Bn) {
        int bb = threadIdx.x;
        float omega = log1pf(__expf(g_omega[0]));
        float alpha = 0.2f / (1.f + __expf(-g_alpha[0]));
        float beta  = 0.8f / (1.f + __expf(-g_beta[0]));
        float h = log1pf(__expf(g_h0[0]));
        const float* xe = x_enc + (size_t)bb * Lq * CINn + (CINn - 2);
        for (int t = 0; t < Lq; ++t) {
            float r = xe[(size_t)t * CINn];
            h = omega + alpha * r * r + beta * h;
        }
        float ab = alpha + beta;
        for (int p = 0; p < PLn; ++p) {
            garch[bb * PLn + p] = sqrtf(h);
            h = omega + ab * h;
        }
    }
}

// ---------------- staged+swizzled bf16 MFMA GEMM, tile 128x128, BK=128
__global__ __launch_bounds__(256) void gemm_stage(
    const short* __restrict__ A, const short* __restrict__ W,
    const float* __restrict__ b1,
    float* __restrict__ Cf, short* __restrict__ Cb,
    int M, int N, int K, int relu)
{
    __shared__ short As[128 * 128];
    __shared__ short Ws[128 * 128];
    int tid = threadIdx.x;
    int w = tid >> 6, lane = tid & 63;
    int wr = w >> 1, wc = w & 1;
    int m0 = blockIdx.x * 128, n0 = blockIdx.y * 128;
    int lr = lane & 15;
    int lkq = lane >> 4;
    int srow_in = lane >> 4;
    int jp = lane & 15;
    f32x4 acc[4][4] = {};

    for (int k0 = 0; k0 < K; k0 += 128) {
        if (k0) __syncthreads();
#pragma unroll
        for (int inst = 0; inst < 8; ++inst) {
            int c = w * 8 + inst;
            int r = c * 4 + srow_in;
            int j = jp ^ (r & 7);
            gload_lds16(A + (size_t)(m0 + r) * K + k0 + j * 8, &As[c * 512]);
            gload_lds16(W + (size_t)(n0 + r) * K + k0 + j * 8, &Ws[c * 512]);
        }
        __syncthreads();
#pragma unroll
        for (int kq = 0; kq < 4; ++kq) {
            int jlog = kq * 4 + lkq;
            short8v a[4], b[4];
#pragma unroll
            for (int i = 0; i < 4; ++i) {
                int ri = wr * 64 + i * 16 + lr;
                a[i] = *reinterpret_cast<const short8v*>(&As[ri * 128 + (jlog ^ (ri & 7)) * 8]);
            }
#pragma unroll
            for (int jj = 0; jj < 4; ++jj) {
                int rj = wc * 64 + jj * 16 + lr;
                b[jj] = *reinterpret_cast<const short8v*>(&Ws[rj * 128 + (jlog ^ (rj & 7)) * 8]);
            }
#pragma unroll
            for (int i = 0; i < 4; ++i)
#pragma unroll
                for (int jj = 0; jj < 4; ++jj)
                    acc[i][jj] = __builtin_amdgcn_mfma_f32_16x16x32_bf16(
                        a[i], b[jj], acc[i][jj], 0, 0, 0);
        }
    }
    int cr0 = (lane >> 4) * 4;
    int cc = lane & 15;
#pragma unroll
    for (int i = 0; i < 4; ++i)
#pragma unroll
        for (int jj = 0; jj < 4; ++jj) {
            int col = n0 + wc * 64 + jj * 16 + cc;
            float bias = b1[col];
#pragma unroll
            for (int r = 0; r < 4; ++r) {
                int row = m0 + wr * 64 + i * 16 + cr0 + r;
                float v = acc[i][jj][r] + bias;
                if (relu) v = fmaxf(v, 0.f);
                if (Cf) Cf[(size_t)row * N + col] = v;
                else    Cb[(size_t)row * N + col] = f2b(v);
            }
        }
}

// ---------------------------------------------------------------- LSTM (MFMA matvec v5)
// v5: ZERO global ops inside the step loop. xW staged through LDS in 8-step
// 16KB chunks via global_load_lds (pure vmcnt), double-buffered, prefetch
// distance 1 chunk (~8 steps of slack), counted vmcnt(4) wait only at chunk
// boundaries. Step loop = ds_read + MFMA + VALU + ds_write + barrier only.
__global__ __launch_bounds__(256, 1) void lstm_kernel(
    const float* __restrict__ xW, const short* __restrict__ Whh_b,
    short* __restrict__ xb_out)
{
    __shared__ __align__(16) short hb[2][Dm];          // bf16 h, double-buffered
    __shared__ __align__(16) float xs[2][8 * 512];     // xW chunks, 2 x 16KB
    int b = blockIdx.x;
    int tid = threadIdx.x;
    int w = tid >> 6;
    int lane = tid & 63;
    int lr = lane & 15;
    int lk = (lane >> 4) * 8;
    int cr0 = (lane >> 4) * 4;
    int qs = lr >> 2;
    int qr = lr & 3;
    int d = w * 32 + qs * 16 + cr0 + qr;   // owned unit (valid for lr<8)
    bool owner = (lr < 8);

    short8v a[4][2][4];
#pragma unroll
    for (int g = 0; g < 4; ++g)
#pragma unroll
        for (int s = 0; s < 2; ++s)
#pragma unroll
            for (int k = 0; k < 4; ++k)
                a[g][s][k] = *reinterpret_cast<const short8v*>(
                    &Whh_b[(size_t)(g * 128 + w * 32 + s * 16 + lr) * Dm + k * 32 + lk]);

    const float* xwb = xW + (size_t)b * Lq * 512;
    // stage chunk c (8 steps x 512 floats) into xs[buf]; 4 insts/wave, linear
    auto stage = [&](int c, int buf) {
        const float* src = xwb + (size_t)c * 4096 + w * 1024 + lane * 4;
        float* dst = &xs[buf][w * 1024];
#pragma unroll
        for (int i = 0; i < 4; ++i)
            gload_lds16f(src + i * 256, dst + i * 256);
    };

    float cpers = 0.f;
    if (tid < 64) reinterpret_cast<int*>(hb[0])[tid] = 0;
    stage(0, 0);
    stage(1, 1);

    short* xo = xb_out + (size_t)b * Lq * Dm + d;
    short hsv[8];
    asm volatile("s_waitcnt lgkmcnt(0)" ::: "memory");

    for (int c = 0; c < 64; ++c) {
        int buf = c & 1;
        // drain this chunk's 4 loads (oldest); next chunk's 4 stay in flight
        asm volatile("s_waitcnt vmcnt(4)" ::: "memory");
        __builtin_amdgcn_sched_barrier(0);
        __builtin_amdgcn_s_barrier();
#pragma unroll
        for (int s8 = 0; s8 < 8; ++s8) {
            short8v bf[4];
#pragma unroll
            for (int k = 0; k < 4; ++k)
                bf[k] = *reinterpret_cast<const short8v*>(&hb[s8 & 1][k * 32 + lk]);
            f32x4 acc[4][2] = {};
#pragma unroll
            for (int k = 0; k < 4; ++k)
#pragma unroll
                for (int g = 0; g < 4; ++g)
#pragma unroll
                    for (int s = 0; s < 2; ++s)
                        acc[g][s] = __builtin_amdgcn_mfma_f32_16x16x32_bf16(
                            a[g][s][k], bf[k], acc[g][s], 0, 0, 0);
            if (owner) {
                float iraw = 0.f, fraw = 0.f, graw = 0.f, oraw = 0.f;
#pragma unroll
                for (int s = 0; s < 2; ++s)
#pragma unroll
                    for (int r = 0; r < 4; ++r)
                        if (qs == s && qr == r) {
                            iraw = acc[0][s][r]; fraw = acc[1][s][r];
                            graw = acc[2][s][r]; oraw = acc[3][s][r];
                        }
                iraw += xs[buf][s8 * 512 + 0 * 128 + d];
                fraw += xs[buf][s8 * 512 + 1 * 128 + d];
                graw += xs[buf][s8 * 512 + 2 * 128 + d];
                oraw += xs[buf][s8 * 512 + 3 * 128 + d];
                float ig = fsig(iraw);
                float fg = fsig(fraw);
                float gg = fast_tanh(graw);
                float og = fsig(oraw);
                cpers = fg * cpers + ig * gg;
                float h = og * fast_tanh(cpers);
                short hv = f2b(h);
                hsv[s8] = hv;
                hb[(s8 & 1) ^ 1][d] = hv;
            }
            asm volatile("s_waitcnt lgkmcnt(0)" ::: "memory");
            __builtin_amdgcn_s_barrier();
        }
        // prefetch chunk c+2 into the buffer just freed (clamped dead reload
        // at the tail keeps the vmcnt(4) invariant exact)
        int cn = (c + 2 < 64) ? c + 2 : 63;
        stage(cn, buf);
        // batched h store burst (global stores retire during next chunk)
        if (owner) {
#pragma unroll
            for (int s8 = 0; s8 < 8; ++s8)
                xo[(size_t)(c * 8 + s8) * Dm] = hsv[s8];
        }
    }
}

// ------------------------------------------------------------- attention (bf16 qkv in)
__global__ __launch_bounds__(256) void attn_kernel(
    const short* __restrict__ qkvb, short* __restrict__ ctxb)
{
    __shared__ float Kb[Lq][16];
    __shared__ float Vb[Lq][16];
    int h = blockIdx.x & (NHh - 1);
    int b = blockIdx.x >> 3;
    int t = threadIdx.x;
    const short* base = qkvb + (size_t)b * Lq * 384;
    int hoff = h * 16;
    for (int i = t; i < Lq * 2; i += 256) {
        int row = i >> 1, half = i & 1;
        short8v kv = *reinterpret_cast<const short8v*>(&base[(size_t)row * 384 + 128 + hoff + half * 8]);
        short8v vv = *reinterpret_cast<const short8v*>(&base[(size_t)row * 384 + 256 + hoff + half * 8]);
#pragma unroll
        for (int e = 0; e < 8; ++e) {
            Kb[row][half * 8 + e] = b2f(kv[e]);
            Vb[row][half * 8 + e] = b2f(vv[e]);
        }
    }
    __syncthreads();
    for (int rr = 0; rr < 2; ++rr) {
        int l = t + rr * 256;
        short8v q0 = *reinterpret_cast<const short8v*>(&base[(size_t)l * 384 + hoff]);
        short8v q1 = *reinterpret_cast<const short8v*>(&base[(size_t)l * 384 + hoff + 8]);
        float q[16];
#pragma unroll
        for (int e = 0; e < 8; ++e) { q[e] = b2f(q0[e]); q[8 + e] = b2f(q1[e]); }
        float m = -1e30f, ssum = 0.f;
        float acc[16] = {};
        for (int jr = 0; jr < Lq; ++jr) {
            float s = 0.f;
#pragma unroll
            for (int cc = 0; cc < 16; ++cc) s += q[cc] * Kb[jr][cc];
            s *= 0.25f;
            if (s > m) {
                float corr = __expf(m - s);
                ssum *= corr;
#pragma unroll
                for (int cc = 0; cc < 16; ++cc) acc[cc] *= corr;
                m = s;
            }
            float p = __expf(s - m);
            ssum += p;
#pragma unroll
            for (int cc = 0; cc < 16; ++cc) acc[cc] += p * Vb[jr][cc];
        }
        float inv = __builtin_amdgcn_rcpf(ssum);
        short8v v0, v1;
#pragma unroll
        for (int cc = 0; cc < 8; ++cc) { v0[cc] = f2b(acc[cc] * inv); v1[cc] = f2b(acc[cc + 8] * inv); }
        short* o = ctxb + ((size_t)b * Lq + l) * Dm + hoff;
        *reinterpret_cast<short8v*>(o) = v0;
        *reinterpret_cast<short8v*>(o + 8) = v1;
    }
}

// -------------------- residual add + LN (+ bf16 mirror); optional bf16 base
__global__ __launch_bounds__(256) void addln_kernel(
    float* __restrict__ x, const short* __restrict__ base_b,
    const float* __restrict__ add,
    const float* __restrict__ g, const float* __restrict__ bta,
    short* __restrict__ xb)
{
    int wave = threadIdx.x >> 6;
    int lane = threadIdx.x & 63;
    int row = blockIdx.x * 4 + wave;
    float* xr = x + (size_t)row * Dm;
    const float* ar = add + (size_t)row * Dm;
    int d0 = lane * 2;
    float b0, b1v;
    if (base_b) {
        unsigned pk = *reinterpret_cast<const unsigned*>(&base_b[(size_t)row * Dm + d0]);
        b0 = b2f((short)(pk & 0xffff));
        b1v = b2f((short)(pk >> 16));
    } else {
        float2 xv = *reinterpret_cast<const float2*>(&xr[d0]);
        b0 = xv.x; b1v = xv.y;
    }
    float2 av = *reinterpret_cast<const float2*>(&ar[d0]);
    float v0 = b0 + av.x, v1 = b1v + av.y;
    float s = v0 + v1;
#pragma unroll
    for (int off = 32; off > 0; off >>= 1) s += __shfl_xor(s, off);
    float mu = s * (1.f / Dm);
    float e0 = v0 - mu, e1 = v1 - mu;
    float s2 = e0 * e0 + e1 * e1;
#pragma unroll
    for (int off = 32; off > 0; off >>= 1) s2 += __shfl_xor(s2, off);
    float rs = rsqrtf(s2 * (1.f / Dm) + EPSf);
    float o0 = e0 * rs * g[d0] + bta[d0];
    float o1 = e1 * rs * g[d0 + 1] + bta[d0 + 1];
    xr[d0] = o0;
    xr[d0 + 1] = o1;
    unsigned pk = (unsigned)(unsigned short)f2b(o0) | ((unsigned)(unsigned short)f2b(o1) << 16);
    *reinterpret_cast<unsigned*>(&xb[(size_t)row * Dm + d0]) = pk;
}

// --------------------------------------------------------------- head
__global__ void head_kernel(const float* __restrict__ x,
                            const float* __restrict__ head_w, const float* __restrict__ head_b,
                            const float* __restrict__ gw1, const float* __restrict__ gb1,
                            const float* __restrict__ gw2, const float* __restrict__ gb2,
                            const float* __restrict__ garch,
                            float* __restrict__ out)
{
    __shared__ float last[Dm];
    __shared__ float t1[Dm / 2];
    int b = blockIdx.x, t = threadIdx.x;
    if (t < Dm) last[t] = x[((size_t)b * Lq + (Lq - 1)) * Dm + t];
    __syncthreads();
    if (t < Dm / 2) {
        float s = gb1[t];
#pragma unroll 8
        for (int d = 0; d < Dm; ++d) s += last[d] * gw1[(size_t)t * Dm + d];
        t1[t] = fmaxf(s, 0.f);
    }
    __syncthreads();
    if (t < PLn) {
        float ai = head_b[t];
#pragma unroll 8
        for (int d = 0; d < Dm; ++d) ai += last[d] * head_w[(size_t)t * Dm + d];
        float gg = gb2[t];
#pragma unroll 8
        for (int j = 0; j < Dm / 2; ++j) gg += t1[j] * gw2[(size_t)t * (Dm / 2) + j];
        float gate = 1.f / (1.f + __expf(-gg));
        out[b * PLn + t] = garch[b * PLn + t] + gate * ai;
    }
}

extern "C" void kernel_launch(void* const* d_in, const int* in_sizes, int n_in,
                              void* d_out, int out_size, void* d_ws, size_t ws_size,
                              hipStream_t stream)
{
    const float* x_enc  = (const float*)d_in[0];
    const float* x_mark = (const float*)d_in[1];
    const float* conv_w = (const float*)d_in[4];
    const float* temp_w = (const float*)d_in[5];
    const float* Wih    = (const float*)d_in[6];
    const float* Whh    = (const float*)d_in[7];
    const float* bih    = (const float*)d_in[8];
    const float* bhh    = (const float*)d_in[9];
    const float* Wqkv   = (const float*)d_in[10];
    const float* bqkv   = (const float*)d_in[11];
    const float* Wo     = (const float*)d_in[12];
    const float* bo     = (const float*)d_in[13];
    const float* ln1g   = (const float*)d_in[14];
    const float* ln1b   = (const float*)d_in[15];
    const float* W1     = (const float*)d_in[16];
    const float* b1     = (const float*)d_in[17];
    const float* W2     = (const float*)d_in[18];
    const float* b2     = (const float*)d_in[19];
    const float* ln2g   = (const float*)d_in[20];
    const float* ln2b   = (const float*)d_in[21];
    const float* head_w = (const float*)d_in[22];
    const float* head_b = (const float*)d_in[23];
    const float* gw1    = (const float*)d_in[24];
    const float* gb1    = (const float*)d_in[25];
    const float* gw2    = (const float*)d_in[26];
    const float* gb2    = (const float*)d_in[27];
    const float* g_omega= (const float*)d_in[28];
    const float* g_alpha= (const float*)d_in[29];
    const float* g_beta = (const float*)d_in[30];
    const float* g_h0   = (const float*)d_in[31];

    const int M = Bn * Lq;                    // 32768
    float* ws    = (float*)d_ws;
    float* garch = ws;                        // 6144 used
    float* biassum = ws + 6144;               // 512 floats (bih+bhh)
    float* regionA = ws + 8192;               // 4,194,304 floats
    short* xb   = (short*)regionA;            //   bf16 x mirror (after lstm)
    short* ctxb = (short*)(regionA + 2097152);//   bf16 ctx
    float* xWr  = regionA + 4194304;          // 16,777,216 floats
    float* xW   = xWr;                        //   fp32 xW (dead after lstm)
    short* ff1b = (short*)xWr;                //   bf16 ff1 chunk (16384x2048)
    float* x    = xWr + 16777216;             // 4,194,304 floats (live all launch)
    float* qkvr = x + 4194304;                // 12,582,912 floats
    short* encb = (short*)qkvr;               //   bf16 enc (dead after xW gemm)
    short* qkvb = (short*)qkvr;               //   bf16 qkv (dead once ctx built)
    float* tmp  = qkvr;                       //   fp32 tmp (aliases qkvb after attn)
    float* wbr  = qkvr + 12582912;            // bf16 weight mirrors
    short* Wqkv_b = (short*)wbr;              // 98,304
    short* Wo_b   = Wqkv_b + 98304;           // 32,768
    short* W1_b   = Wo_b + 32768;             // 524,288
    short* W2_b   = W1_b + 524288;            // 524,288
    short* Whh_bb = W2_b + 524288;            // 65,536
    short* Wih_b  = Whh_bb + 65536;           // 65,536

    prep_kernel<<<5122, 256, 0, stream>>>(Wqkv, Wo, W1, W2, Whh, Wih, bih, bhh,
                                          Wqkv_b, Wo_b, W1_b, W2_b, Whh_bb, Wih_b, biassum);
    enc_kernel<<<(Bn * Lq * Dm) / 256, 256, 0, stream>>>(
        x_enc, x_mark, conv_w, temp_w, encb, g_omega, g_alpha, g_beta, g_h0, garch);
    gemm_stage<<<dim3(M / 128, 512 / 128), 256, 0, stream>>>(
        encb, Wih_b, biassum, xW, nullptr, M, 512, Dm, 0);
    lstm_kernel<<<Bn, 256, 0, stream>>>(xW, Whh_bb, xb);

    for (int li = 0; li < ELn; ++li) {
        gemm_stage<<<dim3(M / 128, 384 / 128), 256, 0, stream>>>(
            xb, Wqkv_b + (size_t)li * 384 * Dm, bqkv + li * 384, nullptr, qkvb, M, 384, Dm, 0);
        attn_kernel<<<Bn * NHh, 256, 0, stream>>>(qkvb, ctxb);
        gemm_stage<<<dim3(M / 128, Dm / 128), 256, 0, stream>>>(
            ctxb, Wo_b + (size_t)li * Dm * Dm, bo + li * Dm, tmp, nullptr, M, Dm, Dm, 0);
        addln_kernel<<<M / 4, 256, 0, stream>>>(
            x, (li == 0) ? xb : nullptr, tmp, ln1g + li * Dm, ln1b + li * Dm, xb);
        for (int mc = 0; mc < 2; ++mc) {
            const int MC = M / 2;             // 16384 rows
            gemm_stage<<<dim3(MC / 128, DFFn / 128), 256, 0, stream>>>(
                xb + (size_t)mc * MC * Dm, W1_b + (size_t)li * DFFn * Dm, b1 + li * DFFn,
                nullptr, ff1b, MC, DFFn, Dm, 1);
            gemm_stage<<<dim3(MC / 128, Dm / 128), 256, 0, stream>>>(
                ff1b, W2_b + (size_t)li * Dm * DFFn, b2 + li * Dm,
                tmp + (size_t)mc * MC * Dm, nullptr, MC, Dm, DFFn, 0);
        }
        addln_kernel<<<M / 4, 256, 0, stream>>>(
            x, nullptr, tmp, ln2g + li * Dm, ln2b + li * Dm, xb);
    }
    head_kernel<<<Bn, 128, 0, stream>>>(x, head_w, head_b, gw1, gb1, gw2, gb2, garch,
                                        (float*)d_out);
}

// Round 14
// 1077.296 us; speedup vs baseline: 1.4008x; 1.1019x over previous
//
#include <hip/hip_runtime.h>
#include <hip/hip_bf16.h>
#include <math.h>

#define Bn 64
#define Lq 512
#define Dm 128
#define NHh 8
#define ELn 2
#define PLn 96
#define CINn 8
#define DFFn 2048
#define NTFn 4
#define EPSf 1e-5f

typedef __attribute__((ext_vector_type(8))) short short8v;
typedef __attribute__((ext_vector_type(4))) float f32x4;

__device__ __forceinline__ short f2b(float f) {
    union { float f; unsigned u; } v; v.f = f;
    unsigned r = v.u + 0x7fff + ((v.u >> 16) & 1);
    return (short)(r >> 16);
}
__device__ __forceinline__ float b2f(short s) {
    union { unsigned u; float f; } v;
    v.u = ((unsigned)(unsigned short)s) << 16;
    return v.f;
}
__device__ __forceinline__ float fsig(float x) {
    return __builtin_amdgcn_rcpf(1.f + __expf(-x));
}
__device__ __forceinline__ float fast_tanh(float x) {
    float ax = fabsf(x);
    float e = __expf(2.f * ax);
    float t = 1.f - 2.f * __builtin_amdgcn_rcpf(e + 1.f);
    return copysignf(t, x);
}
__device__ __forceinline__ void gload_lds16(const short* g, short* l) {
    __builtin_amdgcn_global_load_lds(
        (const __attribute__((address_space(1))) void*)g,
        (__attribute__((address_space(3))) void*)l, 16, 0, 0);
}
__device__ __forceinline__ void gload_lds16f(const float* g, float* l) {
    __builtin_amdgcn_global_load_lds(
        (const __attribute__((address_space(1))) void*)g,
        (__attribute__((address_space(3))) void*)l, 16, 0, 0);
}

// ---------------- fused prep: all weight bf16 conversions + bias sum (1 launch)
__global__ void prep_kernel(const float* __restrict__ Wqkv, const float* __restrict__ Wo,
                            const float* __restrict__ W1, const float* __restrict__ W2,
                            const float* __restrict__ Whh, const float* __restrict__ Wih,
                            const float* __restrict__ bih, const float* __restrict__ bhh,
                            short* __restrict__ Wqkv_b, short* __restrict__ Wo_b,
                            short* __restrict__ W1_b, short* __restrict__ W2_b,
                            short* __restrict__ Whh_b, short* __restrict__ Wih_b,
                            float* __restrict__ biassum)
{
    int i = blockIdx.x * 256 + threadIdx.x;
    if (i < 98304)        Wqkv_b[i] = f2b(Wqkv[i]);
    else if (i < 131072)  { int j = i - 98304;   Wo_b[j]  = f2b(Wo[j]); }
    else if (i < 655360)  { int j = i - 131072;  W1_b[j]  = f2b(W1[j]); }
    else if (i < 1179648) { int j = i - 655360;  W2_b[j]  = f2b(W2[j]); }
    else if (i < 1245184) { int j = i - 1179648; Whh_b[j] = f2b(Whh[j]); }
    else if (i < 1310720) { int j = i - 1245184; Wih_b[j] = f2b(Wih[j]); }
    else if (i < 1311232) { int j = i - 1310720; biassum[j] = bih[j] + bhh[j]; }
}

// ------------------------------- conv + temporal + pos (bf16 out) + fused GARCH
__global__ void enc_kernel(const float* __restrict__ x_enc,
                           const float* __restrict__ x_mark,
                           const float* __restrict__ conv_w,
                           const float* __restrict__ temp_w,
                           short* __restrict__ encb,
                           const float* __restrict__ g_omega,
                           const float* __restrict__ g_alpha,
                           const float* __restrict__ g_beta,
                           const float* __restrict__ g_h0,
                           float* __restrict__ garch)
{
    int idx = blockIdx.x * blockDim.x + threadIdx.x;   // over B*L*D
    int d = idx & (Dm - 1);
    int l = (idx >> 7) & (Lq - 1);
    int b = idx >> 16;
    int lm = (l + Lq - 1) & (Lq - 1);
    int lp = (l + 1) & (Lq - 1);
    const float* xb = x_enc + (size_t)b * Lq * CINn;
    const float* w  = conv_w + (size_t)d * CINn * 3;
    float acc = 0.f;
#pragma unroll
    for (int ci = 0; ci < CINn; ++ci) {
        acc += xb[(size_t)lm * CINn + ci] * w[ci * 3 + 0];
        acc += xb[(size_t)l  * CINn + ci] * w[ci * 3 + 1];
        acc += xb[(size_t)lp * CINn + ci] * w[ci * 3 + 2];
    }
    const float* mk = x_mark + ((size_t)b * Lq + l) * NTFn;
    const float* tw = temp_w + (size_t)d * NTFn;
#pragma unroll
    for (int f = 0; f < NTFn; ++f) acc += mk[f] * tw[f];
    float dv = __expf(-(float)(d & ~1) * (9.210340371976184f / 128.f));
    float ang = (float)l * dv;
    acc += (d & 1) ? cosf(ang) : sinf(ang);
    encb[idx] = f2b(acc);

    if (blockIdx.x == 0 && threadIdx.x < Bn) {
        int bb = threadIdx.x;
        float omega = log1pf(__expf(g_omega[0]));
        float alpha = 0.2f / (1.f + __expf(-g_alpha[0]));
        float beta  = 0.8f / (1.f + __expf(-g_beta[0]));
        float h = log1pf(__expf(g_h0[0]));
        const float* xe = x_enc + (size_t)bb * Lq * CINn + (CINn - 2);
        for (int t = 0; t < Lq; ++t) {
            float r = xe[(size_t)t * CINn];
            h = omega + alpha * r * r + beta * h;
        }
        float ab = alpha + beta;
        for (int p = 0; p < PLn; ++p) {
            garch[bb * PLn + p] = sqrtf(h);
            h = omega + ab * h;
        }
    }
}

// ---------------- staged+swizzled bf16 MFMA GEMM, tile 128x128, BK=128
__global__ __launch_bounds__(256) void gemm_stage(
    const short* __restrict__ A, const short* __restrict__ W,
    const float* __restrict__ b1,
    float* __restrict__ Cf, short* __restrict__ Cb,
    int M, int N, int K, int relu)
{
    __shared__ short As[128 * 128];
    __shared__ short Ws[128 * 128];
    int tid = threadIdx.x;
    int w = tid >> 6, lane = tid & 63;
    int wr = w >> 1, wc = w & 1;
    int m0 = blockIdx.x * 128, n0 = blockIdx.y * 128;
    int lr = lane & 15;
    int lkq = lane >> 4;
    int srow_in = lane >> 4;
    int jp = lane & 15;
    f32x4 acc[4][4] = {};

    for (int k0 = 0; k0 < K; k0 += 128) {
        if (k0) __syncthreads();
#pragma unroll
        for (int inst = 0; inst < 8; ++inst) {
            int c = w * 8 + inst;
            int r = c * 4 + srow_in;
            int j = jp ^ (r & 7);
            gload_lds16(A + (size_t)(m0 + r) * K + k0 + j * 8, &As[c * 512]);
            gload_lds16(W + (size_t)(n0 + r) * K + k0 + j * 8, &Ws[c * 512]);
        }
        __syncthreads();
#pragma unroll
        for (int kq = 0; kq < 4; ++kq) {
            int jlog = kq * 4 + lkq;
            short8v a[4], b[4];
#pragma unroll
            for (int i = 0; i < 4; ++i) {
                int ri = wr * 64 + i * 16 + lr;
                a[i] = *reinterpret_cast<const short8v*>(&As[ri * 128 + (jlog ^ (ri & 7)) * 8]);
            }
#pragma unroll
            for (int jj = 0; jj < 4; ++jj) {
                int rj = wc * 64 + jj * 16 + lr;
                b[jj] = *reinterpret_cast<const short8v*>(&Ws[rj * 128 + (jlog ^ (rj & 7)) * 8]);
            }
#pragma unroll
            for (int i = 0; i < 4; ++i)
#pragma unroll
                for (int jj = 0; jj < 4; ++jj)
                    acc[i][jj] = __builtin_amdgcn_mfma_f32_16x16x32_bf16(
                        a[i], b[jj], acc[i][jj], 0, 0, 0);
        }
    }
    int cr0 = (lane >> 4) * 4;
    int cc = lane & 15;
#pragma unroll
    for (int i = 0; i < 4; ++i)
#pragma unroll
        for (int jj = 0; jj < 4; ++jj) {
            int col = n0 + wc * 64 + jj * 16 + cc;
            float bias = b1[col];
#pragma unroll
            for (int r = 0; r < 4; ++r) {
                int row = m0 + wr * 64 + i * 16 + cr0 + r;
                float v = acc[i][jj][r] + bias;
                if (relu) v = fmaxf(v, 0.f);
                if (Cf) Cf[(size_t)row * N + col] = v;
                else    Cb[(size_t)row * N + col] = f2b(v);
            }
        }
}

// ---------------- fused FFN: out = relu(X@W1^T+b1)@W2^T + b2, ff1 never in HBM
// per 128-row block: loop 16 chunks of 128 ff-dims; P (128x128 bf16) lives in LDS.
__global__ __launch_bounds__(256, 1) void ffn_fused(
    const short* __restrict__ X, const short* __restrict__ W1w,
    const float* __restrict__ bias1,
    const short* __restrict__ W2w, const float* __restrict__ bias2,
    float* __restrict__ out)
{
    __shared__ short Xs[128 * 128];   // x tile (swizzled)
    __shared__ short Wa[128 * 128];   // W1 chunk
    __shared__ short Wb[128 * 128];   // W2 chunk
    __shared__ short Ps[128 * 128];   // P = relu(x@W1f^T+b1f), bf16 (swizzled)
    int tid = threadIdx.x;
    int w = tid >> 6, lane = tid & 63;
    int wr = w >> 1, wc = w & 1;
    int m0 = blockIdx.x * 128;
    int lr = lane & 15;
    int lkq = lane >> 4;
    int srow_in = lane >> 4;
    int jp = lane & 15;
    int cr0 = (lane >> 4) * 4;
    int cc = lane & 15;

    // stage X tile once (K=128), swizzled like gemm_stage
#pragma unroll
    for (int inst = 0; inst < 8; ++inst) {
        int c = w * 8 + inst;
        int r = c * 4 + srow_in;
        int j = jp ^ (r & 7);
        gload_lds16(X + (size_t)(m0 + r) * 128 + j * 8, &Xs[c * 512]);
    }

    f32x4 acc[4][4] = {};
    for (int f = 0; f < 16; ++f) {
        // stage W1 chunk: rows f*128..+128, K=128 (contiguous 32KB)
#pragma unroll
        for (int inst = 0; inst < 8; ++inst) {
            int c = w * 8 + inst;
            int r = c * 4 + srow_in;
            int j = jp ^ (r & 7);
            gload_lds16(W1w + (size_t)(f * 128 + r) * 128 + j * 8, &Wa[c * 512]);
        }
        __syncthreads();   // drains Xs(f==0)+Wa loads; fences Ps/Wb reuse from prev chunk
        // bias1 for this lane's 4 output cols (consumed at Ps write — latency covered)
        float bv[4];
#pragma unroll
        for (int jj = 0; jj < 4; ++jj) bv[jj] = bias1[f * 128 + wc * 64 + jj * 16 + cc];
        // gemm1: P = X @ W1f^T
        f32x4 acc1[4][4] = {};
#pragma unroll
        for (int kq = 0; kq < 4; ++kq) {
            int jlog = kq * 4 + lkq;
            short8v a[4], b[4];
#pragma unroll
            for (int i = 0; i < 4; ++i) {
                int ri = wr * 64 + i * 16 + lr;
                a[i] = *reinterpret_cast<const short8v*>(&Xs[ri * 128 + (jlog ^ (ri & 7)) * 8]);
            }
#pragma unroll
            for (int jj = 0; jj < 4; ++jj) {
                int rj = wc * 64 + jj * 16 + lr;
                b[jj] = *reinterpret_cast<const short8v*>(&Wa[rj * 128 + (jlog ^ (rj & 7)) * 8]);
            }
#pragma unroll
            for (int i = 0; i < 4; ++i)
#pragma unroll
                for (int jj = 0; jj < 4; ++jj)
                    acc1[i][jj] = __builtin_amdgcn_mfma_f32_16x16x32_bf16(
                        a[i], b[jj], acc1[i][jj], 0, 0, 0);
        }
        // stage W2 chunk while gemm1 results settle: rows n=0..127, k=f*128..+128
#pragma unroll
        for (int inst = 0; inst < 8; ++inst) {
            int c = w * 8 + inst;
            int r = c * 4 + srow_in;
            int j = jp ^ (r & 7);
            gload_lds16(W2w + (size_t)r * 2048 + f * 128 + j * 8, &Wb[c * 512]);
        }
        // relu+bias+cvt -> Ps (swizzled: phys = row*128 + ((col>>3 ^ row&7)*8 + col&7))
#pragma unroll
        for (int i = 0; i < 4; ++i)
#pragma unroll
            for (int jj = 0; jj < 4; ++jj) {
                int col = wc * 64 + jj * 16 + cc;
                int jc = col >> 3, ec = col & 7;
#pragma unroll
                for (int r = 0; r < 4; ++r) {
                    int row = wr * 64 + i * 16 + cr0 + r;
                    float v = fmaxf(acc1[i][jj][r] + bv[jj], 0.f);
                    Ps[row * 128 + ((jc ^ (row & 7)) * 8 + ec)] = f2b(v);
                }
            }
        __syncthreads();   // drains Wb loads + Ps ds_writes
        // gemm2: acc += P @ W2f^T
#pragma unroll
        for (int kq = 0; kq < 4; ++kq) {
            int jlog = kq * 4 + lkq;
            short8v a[4], b[4];
#pragma unroll
            for (int i = 0; i < 4; ++i) {
                int ri = wr * 64 + i * 16 + lr;
                a[i] = *reinterpret_cast<const short8v*>(&Ps[ri * 128 + (jlog ^ (ri & 7)) * 8]);
            }
#pragma unroll
            for (int jj = 0; jj < 4; ++jj) {
                int rj = wc * 64 + jj * 16 + lr;
                b[jj] = *reinterpret_cast<const short8v*>(&Wb[rj * 128 + (jlog ^ (rj & 7)) * 8]);
            }
#pragma unroll
            for (int i = 0; i < 4; ++i)
#pragma unroll
                for (int jj = 0; jj < 4; ++jj)
                    acc[i][jj] = __builtin_amdgcn_mfma_f32_16x16x32_bf16(
                        a[i], b[jj], acc[i][jj], 0, 0, 0);
        }
    }
    // epilogue: out = acc + b2 (fp32, for addln)
#pragma unroll
    for (int i = 0; i < 4; ++i)
#pragma unroll
        for (int jj = 0; jj < 4; ++jj) {
            int col = wc * 64 + jj * 16 + cc;
            float bias = bias2[col];
#pragma unroll
            for (int r = 0; r < 4; ++r) {
                int row = m0 + wr * 64 + i * 16 + cr0 + r;
                out[(size_t)row * Dm + col] = acc[i][jj][r] + bias;
            }
        }
}

// ---------------------------------------------------------------- LSTM (MFMA matvec v5, frozen)
__global__ __launch_bounds__(256, 1) void lstm_kernel(
    const float* __restrict__ xW, const short* __restrict__ Whh_b,
    short* __restrict__ xb_out)
{
    __shared__ __align__(16) short hb[2][Dm];
    __shared__ __align__(16) float xs[2][8 * 512];
    int b = blockIdx.x;
    int tid = threadIdx.x;
    int w = tid >> 6;
    int lane = tid & 63;
    int lr = lane & 15;
    int lk = (lane >> 4) * 8;
    int cr0 = (lane >> 4) * 4;
    int qs = lr >> 2;
    int qr = lr & 3;
    int d = w * 32 + qs * 16 + cr0 + qr;
    bool owner = (lr < 8);

    short8v a[4][2][4];
#pragma unroll
    for (int g = 0; g < 4; ++g)
#pragma unroll
        for (int s = 0; s < 2; ++s)
#pragma unroll
            for (int k = 0; k < 4; ++k)
                a[g][s][k] = *reinterpret_cast<const short8v*>(
                    &Whh_b[(size_t)(g * 128 + w * 32 + s * 16 + lr) * Dm + k * 32 + lk]);

    const float* xwb = xW + (size_t)b * Lq * 512;
    auto stage = [&](int c, int buf) {
        const float* src = xwb + (size_t)c * 4096 + w * 1024 + lane * 4;
        float* dst = &xs[buf][w * 1024];
#pragma unroll
        for (int i = 0; i < 4; ++i)
            gload_lds16f(src + i * 256, dst + i * 256);
    };

    float cpers = 0.f;
    if (tid < 64) reinterpret_cast<int*>(hb[0])[tid] = 0;
    stage(0, 0);
    stage(1, 1);

    short* xo = xb_out + (size_t)b * Lq * Dm + d;
    short hsv[8];
    asm volatile("s_waitcnt lgkmcnt(0)" ::: "memory");

    for (int c = 0; c < 64; ++c) {
        int buf = c & 1;
        asm volatile("s_waitcnt vmcnt(4)" ::: "memory");
        __builtin_amdgcn_sched_barrier(0);
        __builtin_amdgcn_s_barrier();
#pragma unroll
        for (int s8 = 0; s8 < 8; ++s8) {
            short8v bf[4];
#pragma unroll
            for (int k = 0; k < 4; ++k)
                bf[k] = *reinterpret_cast<const short8v*>(&hb[s8 & 1][k * 32 + lk]);
            f32x4 acc[4][2] = {};
#pragma unroll
            for (int k = 0; k < 4; ++k)
#pragma unroll
                for (int g = 0; g < 4; ++g)
#pragma unroll
                    for (int s = 0; s < 2; ++s)
                        acc[g][s] = __builtin_amdgcn_mfma_f32_16x16x32_bf16(
                            a[g][s][k], bf[k], acc[g][s], 0, 0, 0);
            if (owner) {
                float iraw = 0.f, fraw = 0.f, graw = 0.f, oraw = 0.f;
#pragma unroll
                for (int s = 0; s < 2; ++s)
#pragma unroll
                    for (int r = 0; r < 4; ++r)
                        if (qs == s && qr == r) {
                            iraw = acc[0][s][r]; fraw = acc[1][s][r];
                            graw = acc[2][s][r]; oraw = acc[3][s][r];
                        }
                iraw += xs[buf][s8 * 512 + 0 * 128 + d];
                fraw += xs[buf][s8 * 512 + 1 * 128 + d];
                graw += xs[buf][s8 * 512 + 2 * 128 + d];
                oraw += xs[buf][s8 * 512 + 3 * 128 + d];
                float ig = fsig(iraw);
                float fg = fsig(fraw);
                float gg = fast_tanh(graw);
                float og = fsig(oraw);
                cpers = fg * cpers + ig * gg;
                float h = og * fast_tanh(cpers);
                short hv = f2b(h);
                hsv[s8] = hv;
                hb[(s8 & 1) ^ 1][d] = hv;
            }
            asm volatile("s_waitcnt lgkmcnt(0)" ::: "memory");
            __builtin_amdgcn_s_barrier();
        }
        int cn = (c + 2 < 64) ? c + 2 : 63;
        stage(cn, buf);
        if (owner) {
#pragma unroll
            for (int s8 = 0; s8 < 8; ++s8)
                xo[(size_t)(c * 8 + s8) * Dm] = hsv[s8];
        }
    }
}

// ------------------------------------------------------------- attention (bf16 qkv in)
__global__ __launch_bounds__(256) void attn_kernel(
    const short* __restrict__ qkvb, short* __restrict__ ctxb)
{
    __shared__ float Kb[Lq][16];
    __shared__ float Vb[Lq][16];
    int h = blockIdx.x & (NHh - 1);
    int b = blockIdx.x >> 3;
    int t = threadIdx.x;
    const short* base = qkvb + (size_t)b * Lq * 384;
    int hoff = h * 16;
    for (int i = t; i < Lq * 2; i += 256) {
        int row = i >> 1, half = i & 1;
        short8v kv = *reinterpret_cast<const short8v*>(&base[(size_t)row * 384 + 128 + hoff + half * 8]);
        short8v vv = *reinterpret_cast<const short8v*>(&base[(size_t)row * 384 + 256 + hoff + half * 8]);
#pragma unroll
        for (int e = 0; e < 8; ++e) {
            Kb[row][half * 8 + e] = b2f(kv[e]);
            Vb[row][half * 8 + e] = b2f(vv[e]);
        }
    }
    __syncthreads();
    for (int rr = 0; rr < 2; ++rr) {
        int l = t + rr * 256;
        short8v q0 = *reinterpret_cast<const short8v*>(&base[(size_t)l * 384 + hoff]);
        short8v q1 = *reinterpret_cast<const short8v*>(&base[(size_t)l * 384 + hoff + 8]);
        float q[16];
#pragma unroll
        for (int e = 0; e < 8; ++e) { q[e] = b2f(q0[e]); q[8 + e] = b2f(q1[e]); }
        float m = -1e30f, ssum = 0.f;
        float acc[16] = {};
        for (int jr = 0; jr < Lq; ++jr) {
            float s = 0.f;
#pragma unroll
            for (int cc = 0; cc < 16; ++cc) s += q[cc] * Kb[jr][cc];
            s *= 0.25f;
            if (s > m) {
                float corr = __expf(m - s);
                ssum *= corr;
#pragma unroll
                for (int cc = 0; cc < 16; ++cc) acc[cc] *= corr;
                m = s;
            }
            float p = __expf(s - m);
            ssum += p;
#pragma unroll
            for (int cc = 0; cc < 16; ++cc) acc[cc] += p * Vb[jr][cc];
        }
        float inv = __builtin_amdgcn_rcpf(ssum);
        short8v v0, v1;
#pragma unroll
        for (int cc = 0; cc < 8; ++cc) { v0[cc] = f2b(acc[cc] * inv); v1[cc] = f2b(acc[cc + 8] * inv); }
        short* o = ctxb + ((size_t)b * Lq + l) * Dm + hoff;
        *reinterpret_cast<short8v*>(o) = v0;
        *reinterpret_cast<short8v*>(o + 8) = v1;
    }
}

// -------------------- residual add + LN (+ bf16 mirror); optional bf16 base
__global__ __launch_bounds__(256) void addln_kernel(
    float* __restrict__ x, const short* __restrict__ base_b,
    const float* __restrict__ add,
    const float* __restrict__ g, const float* __restrict__ bta,
    short* __restrict__ xb)
{
    int wave = threadIdx.x >> 6;
    int lane = threadIdx.x & 63;
    int row = blockIdx.x * 4 + wave;
    float* xr = x + (size_t)row * Dm;
    const float* ar = add + (size_t)row * Dm;
    int d0 = lane * 2;
    float b0, b1v;
    if (base_b) {
        unsigned pk = *reinterpret_cast<const unsigned*>(&base_b[(size_t)row * Dm + d0]);
        b0 = b2f((short)(pk & 0xffff));
        b1v = b2f((short)(pk >> 16));
    } else {
        float2 xv = *reinterpret_cast<const float2*>(&xr[d0]);
        b0 = xv.x; b1v = xv.y;
    }
    float2 av = *reinterpret_cast<const float2*>(&ar[d0]);
    float v0 = b0 + av.x, v1 = b1v + av.y;
    float s = v0 + v1;
#pragma unroll
    for (int off = 32; off > 0; off >>= 1) s += __shfl_xor(s, off);
    float mu = s * (1.f / Dm);
    float e0 = v0 - mu, e1 = v1 - mu;
    float s2 = e0 * e0 + e1 * e1;
#pragma unroll
    for (int off = 32; off > 0; off >>= 1) s2 += __shfl_xor(s2, off);
    float rs = rsqrtf(s2 * (1.f / Dm) + EPSf);
    float o0 = e0 * rs * g[d0] + bta[d0];
    float o1 = e1 * rs * g[d0 + 1] + bta[d0 + 1];
    xr[d0] = o0;
    xr[d0 + 1] = o1;
    unsigned pk = (unsigned)(unsigned short)f2b(o0) | ((unsigned)(unsigned short)f2b(o1) << 16);
    *reinterpret_cast<unsigned*>(&xb[(size_t)row * Dm + d0]) = pk;
}

// --------------------------------------------------------------- head
__global__ void head_kernel(const float* __restrict__ x,
                            const float* __restrict__ head_w, const float* __restrict__ head_b,
                            const float* __restrict__ gw1, const float* __restrict__ gb1,
                            const float* __restrict__ gw2, const float* __restrict__ gb2,
                            const float* __restrict__ garch,
                            float* __restrict__ out)
{
    __shared__ float last[Dm];
    __shared__ float t1[Dm / 2];
    int b = blockIdx.x, t = threadIdx.x;
    if (t < Dm) last[t] = x[((size_t)b * Lq + (Lq - 1)) * Dm + t];
    __syncthreads();
    if (t < Dm / 2) {
        float s = gb1[t];
#pragma unroll 8
        for (int d = 0; d < Dm; ++d) s += last[d] * gw1[(size_t)t * Dm + d];
        t1[t] = fmaxf(s, 0.f);
    }
    __syncthreads();
    if (t < PLn) {
        float ai = head_b[t];
#pragma unroll 8
        for (int d = 0; d < Dm; ++d) ai += last[d] * head_w[(size_t)t * Dm + d];
        float gg = gb2[t];
#pragma unroll 8
        for (int j = 0; j < Dm / 2; ++j) gg += t1[j] * gw2[(size_t)t * (Dm / 2) + j];
        float gate = 1.f / (1.f + __expf(-gg));
        out[b * PLn + t] = garch[b * PLn + t] + gate * ai;
    }
}

extern "C" void kernel_launch(void* const* d_in, const int* in_sizes, int n_in,
                              void* d_out, int out_size, void* d_ws, size_t ws_size,
                              hipStream_t stream)
{
    const float* x_enc  = (const float*)d_in[0];
    const float* x_mark = (const float*)d_in[1];
    const float* conv_w = (const float*)d_in[4];
    const float* temp_w = (const float*)d_in[5];
    const float* Wih    = (const float*)d_in[6];
    const float* Whh    = (const float*)d_in[7];
    const float* bih    = (const float*)d_in[8];
    const float* bhh    = (const float*)d_in[9];
    const float* Wqkv   = (const float*)d_in[10];
    const float* bqkv   = (const float*)d_in[11];
    const float* Wo     = (const float*)d_in[12];
    const float* bo     = (const float*)d_in[13];
    const float* ln1g   = (const float*)d_in[14];
    const float* ln1b   = (const float*)d_in[15];
    const float* W1     = (const float*)d_in[16];
    const float* b1     = (const float*)d_in[17];
    const float* W2     = (const float*)d_in[18];
    const float* b2     = (const float*)d_in[19];
    const float* ln2g   = (const float*)d_in[20];
    const float* ln2b   = (const float*)d_in[21];
    const float* head_w = (const float*)d_in[22];
    const float* head_b = (const float*)d_in[23];
    const float* gw1    = (const float*)d_in[24];
    const float* gb1    = (const float*)d_in[25];
    const float* gw2    = (const float*)d_in[26];
    const float* gb2    = (const float*)d_in[27];
    const float* g_omega= (const float*)d_in[28];
    const float* g_alpha= (const float*)d_in[29];
    const float* g_beta = (const float*)d_in[30];
    const float* g_h0   = (const float*)d_in[31];

    const int M = Bn * Lq;                    // 32768
    float* ws    = (float*)d_ws;
    float* garch = ws;                        // 6144 used
    float* biassum = ws + 6144;               // 512 floats (bih+bhh)
    float* regionA = ws + 8192;               // 4,194,304 floats
    short* xb   = (short*)regionA;            //   bf16 x mirror (after lstm)
    short* ctxb = (short*)(regionA + 2097152);//   bf16 ctx
    float* xWr  = regionA + 4194304;          // 16,777,216 floats
    float* xW   = xWr;                        //   fp32 xW (dead after lstm)
    float* x    = xWr + 16777216;             // 4,194,304 floats (live all launch)
    float* qkvr = x + 4194304;                // 12,582,912 floats
    short* encb = (short*)qkvr;               //   bf16 enc (dead after xW gemm)
    short* qkvb = (short*)qkvr;               //   bf16 qkv (dead once ctx built)
    float* tmp  = qkvr;                       //   fp32 tmp (aliases qkvb after attn)
    float* wbr  = qkvr + 12582912;            // bf16 weight mirrors
    short* Wqkv_b = (short*)wbr;              // 98,304
    short* Wo_b   = Wqkv_b + 98304;           // 32,768
    short* W1_b   = Wo_b + 32768;             // 524,288
    short* W2_b   = W1_b + 524288;            // 524,288
    short* Whh_bb = W2_b + 524288;            // 65,536
    short* Wih_b  = Whh_bb + 65536;           // 65,536

    prep_kernel<<<5122, 256, 0, stream>>>(Wqkv, Wo, W1, W2, Whh, Wih, bih, bhh,
                                          Wqkv_b, Wo_b, W1_b, W2_b, Whh_bb, Wih_b, biassum);
    enc_kernel<<<(Bn * Lq * Dm) / 256, 256, 0, stream>>>(
        x_enc, x_mark, conv_w, temp_w, encb, g_omega, g_alpha, g_beta, g_h0, garch);
    gemm_stage<<<dim3(M / 128, 512 / 128), 256, 0, stream>>>(
        encb, Wih_b, biassum, xW, nullptr, M, 512, Dm, 0);
    lstm_kernel<<<Bn, 256, 0, stream>>>(xW, Whh_bb, xb);

    for (int li = 0; li < ELn; ++li) {
        gemm_stage<<<dim3(M / 128, 384 / 128), 256, 0, stream>>>(
            xb, Wqkv_b + (size_t)li * 384 * Dm, bqkv + li * 384, nullptr, qkvb, M, 384, Dm, 0);
        attn_kernel<<<Bn * NHh, 256, 0, stream>>>(qkvb, ctxb);
        gemm_stage<<<dim3(M / 128, Dm / 128), 256, 0, stream>>>(
            ctxb, Wo_b + (size_t)li * Dm * Dm, bo + li * Dm, tmp, nullptr, M, Dm, Dm, 0);
        addln_kernel<<<M / 4, 256, 0, stream>>>(
            x, (li == 0) ? xb : nullptr, tmp, ln1g + li * Dm, ln1b + li * Dm, xb);
        ffn_fused<<<M / 128, 256, 0, stream>>>(
            xb, W1_b + (size_t)li * DFFn * Dm, b1 + li * DFFn,
            W2_b + (size_t)li * Dm * DFFn, b2 + li * Dm, tmp);
        addln_kernel<<<M / 4, 256, 0, stream>>>(
            x, nullptr, tmp, ln2g + li * Dm, ln2b + li * Dm, xb);
    }
    head_kernel<<<Bn, 128, 0, stream>>>(x, head_w, head_b, gw1, gb1, gw2, gb2, garch,
                                        (float*)d_out);
}

// Round 15
// 1074.961 us; speedup vs baseline: 1.4038x; 1.0022x over previous
//
#include <hip/hip_runtime.h>
#include <hip/hip_bf16.h>
#include <math.h>

#define Bn 64
#define Lq 512
#define Dm 128
#define NHh 8
#define ELn 2
#define PLn 96
#define CINn 8
#define DFFn 2048
#define NTFn 4
#define EPSf 1e-5f

typedef __attribute__((ext_vector_type(8))) short short8v;
typedef __attribute__((ext_vector_type(4))) float f32x4;

__device__ __forceinline__ short f2b(float f) {
    union { float f; unsigned u; } v; v.f = f;
    unsigned r = v.u + 0x7fff + ((v.u >> 16) & 1);
    return (short)(r >> 16);
}
__device__ __forceinline__ float b2f(short s) {
    union { unsigned u; float f; } v;
    v.u = ((unsigned)(unsigned short)s) << 16;
    return v.f;
}
__device__ __forceinline__ float fsig(float x) {
    return __builtin_amdgcn_rcpf(1.f + __expf(-x));
}
__device__ __forceinline__ float fast_tanh(float x) {
    float ax = fabsf(x);
    float e = __expf(2.f * ax);
    float t = 1.f - 2.f * __builtin_amdgcn_rcpf(e + 1.f);
    return copysignf(t, x);
}
__device__ __forceinline__ void gload_lds16(const short* g, short* l) {
    __builtin_amdgcn_global_load_lds(
        (const __attribute__((address_space(1))) void*)g,
        (__attribute__((address_space(3))) void*)l, 16, 0, 0);
}
__device__ __forceinline__ void gload_lds16f(const float* g, float* l) {
    __builtin_amdgcn_global_load_lds(
        (const __attribute__((address_space(1))) void*)g,
        (__attribute__((address_space(3))) void*)l, 16, 0, 0);
}

// ---------------- fused prep: all weight bf16 conversions + bias sum (1 launch)
__global__ void prep_kernel(const float* __restrict__ Wqkv, const float* __restrict__ Wo,
                            const float* __restrict__ W1, const float* __restrict__ W2,
                            const float* __restrict__ Whh, const float* __restrict__ Wih,
                            const float* __restrict__ bih, const float* __restrict__ bhh,
                            short* __restrict__ Wqkv_b, short* __restrict__ Wo_b,
                            short* __restrict__ W1_b, short* __restrict__ W2_b,
                            short* __restrict__ Whh_b, short* __restrict__ Wih_b,
                            float* __restrict__ biassum)
{
    int i = blockIdx.x * 256 + threadIdx.x;
    if (i < 98304)        Wqkv_b[i] = f2b(Wqkv[i]);
    else if (i < 131072)  { int j = i - 98304;   Wo_b[j]  = f2b(Wo[j]); }
    else if (i < 655360)  { int j = i - 131072;  W1_b[j]  = f2b(W1[j]); }
    else if (i < 1179648) { int j = i - 655360;  W2_b[j]  = f2b(W2[j]); }
    else if (i < 1245184) { int j = i - 1179648; Whh_b[j] = f2b(Whh[j]); }
    else if (i < 1310720) { int j = i - 1245184; Wih_b[j] = f2b(Wih[j]); }
    else if (i < 1311232) { int j = i - 1310720; biassum[j] = bih[j] + bhh[j]; }
}

// ------------------------------- conv + temporal + pos (bf16 out) + fused GARCH
__global__ void enc_kernel(const float* __restrict__ x_enc,
                           const float* __restrict__ x_mark,
                           const float* __restrict__ conv_w,
                           const float* __restrict__ temp_w,
                           short* __restrict__ encb,
                           const float* __restrict__ g_omega,
                           const float* __restrict__ g_alpha,
                           const float* __restrict__ g_beta,
                           const float* __restrict__ g_h0,
                           float* __restrict__ garch)
{
    int idx = blockIdx.x * blockDim.x + threadIdx.x;   // over B*L*D
    int d = idx & (Dm - 1);
    int l = (idx >> 7) & (Lq - 1);
    int b = idx >> 16;
    int lm = (l + Lq - 1) & (Lq - 1);
    int lp = (l + 1) & (Lq - 1);
    const float* xb = x_enc + (size_t)b * Lq * CINn;
    const float* w  = conv_w + (size_t)d * CINn * 3;
    float acc = 0.f;
#pragma unroll
    for (int ci = 0; ci < CINn; ++ci) {
        acc += xb[(size_t)lm * CINn + ci] * w[ci * 3 + 0];
        acc += xb[(size_t)l  * CINn + ci] * w[ci * 3 + 1];
        acc += xb[(size_t)lp * CINn + ci] * w[ci * 3 + 2];
    }
    const float* mk = x_mark + ((size_t)b * Lq + l) * NTFn;
    const float* tw = temp_w + (size_t)d * NTFn;
#pragma unroll
    for (int f = 0; f < NTFn; ++f) acc += mk[f] * tw[f];
    float dv = __expf(-(float)(d & ~1) * (9.210340371976184f / 128.f));
    float ang = (float)l * dv;
    acc += (d & 1) ? cosf(ang) : sinf(ang);
    encb[idx] = f2b(acc);

    if (blockIdx.x == 0 && threadIdx.x < Bn) {
        int bb = threadIdx.x;
        float omega = log1pf(__expf(g_omega[0]));
        float alpha = 0.2f / (1.f + __expf(-g_alpha[0]));
        float beta  = 0.8f / (1.f + __expf(-g_beta[0]));
        float h = log1pf(__expf(g_h0[0]));
        const float* xe = x_enc + (size_t)bb * Lq * CINn + (CINn - 2);
        for (int t = 0; t < Lq; ++t) {
            float r = xe[(size_t)t * CINn];
            h = omega + alpha * r * r + beta * h;
        }
        float ab = alpha + beta;
        for (int p = 0; p < PLn; ++p) {
            garch[bb * PLn + p] = sqrtf(h);
            h = omega + ab * h;
        }
    }
}

// ---------------- staged+swizzled bf16 MFMA GEMM, tile 128x128, BK=128
__global__ __launch_bounds__(256) void gemm_stage(
    const short* __restrict__ A, const short* __restrict__ W,
    const float* __restrict__ b1,
    float* __restrict__ Cf, short* __restrict__ Cb,
    int M, int N, int K, int relu)
{
    __shared__ short As[128 * 128];
    __shared__ short Ws[128 * 128];
    int tid = threadIdx.x;
    int w = tid >> 6, lane = tid & 63;
    int wr = w >> 1, wc = w & 1;
    int m0 = blockIdx.x * 128, n0 = blockIdx.y * 128;
    int lr = lane & 15;
    int lkq = lane >> 4;
    int srow_in = lane >> 4;
    int jp = lane & 15;
    f32x4 acc[4][4] = {};

    for (int k0 = 0; k0 < K; k0 += 128) {
        if (k0) __syncthreads();
#pragma unroll
        for (int inst = 0; inst < 8; ++inst) {
            int c = w * 8 + inst;
            int r = c * 4 + srow_in;
            int j = jp ^ (r & 7);
            gload_lds16(A + (size_t)(m0 + r) * K + k0 + j * 8, &As[c * 512]);
            gload_lds16(W + (size_t)(n0 + r) * K + k0 + j * 8, &Ws[c * 512]);
        }
        __syncthreads();
#pragma unroll
        for (int kq = 0; kq < 4; ++kq) {
            int jlog = kq * 4 + lkq;
            short8v a[4], b[4];
#pragma unroll
            for (int i = 0; i < 4; ++i) {
                int ri = wr * 64 + i * 16 + lr;
                a[i] = *reinterpret_cast<const short8v*>(&As[ri * 128 + (jlog ^ (ri & 7)) * 8]);
            }
#pragma unroll
            for (int jj = 0; jj < 4; ++jj) {
                int rj = wc * 64 + jj * 16 + lr;
                b[jj] = *reinterpret_cast<const short8v*>(&Ws[rj * 128 + (jlog ^ (rj & 7)) * 8]);
            }
#pragma unroll
            for (int i = 0; i < 4; ++i)
#pragma unroll
                for (int jj = 0; jj < 4; ++jj)
                    acc[i][jj] = __builtin_amdgcn_mfma_f32_16x16x32_bf16(
                        a[i], b[jj], acc[i][jj], 0, 0, 0);
        }
    }
    int cr0 = (lane >> 4) * 4;
    int cc = lane & 15;
#pragma unroll
    for (int i = 0; i < 4; ++i)
#pragma unroll
        for (int jj = 0; jj < 4; ++jj) {
            int col = n0 + wc * 64 + jj * 16 + cc;
            float bias = b1[col];
#pragma unroll
            for (int r = 0; r < 4; ++r) {
                int row = m0 + wr * 64 + i * 16 + cr0 + r;
                float v = acc[i][jj][r] + bias;
                if (relu) v = fmaxf(v, 0.f);
                if (Cf) Cf[(size_t)row * N + col] = v;
                else    Cb[(size_t)row * N + col] = f2b(v);
            }
        }
}

// ---------------- fused FFN: out = relu(X@W1^T+b1)@W2^T + b2, ff1 never in HBM
// per 128-row block: loop 16 chunks of 128 ff-dims; P (128x128 bf16) lives in LDS.
__global__ __launch_bounds__(256, 1) void ffn_fused(
    const short* __restrict__ X, const short* __restrict__ W1w,
    const float* __restrict__ bias1,
    const short* __restrict__ W2w, const float* __restrict__ bias2,
    float* __restrict__ out)
{
    __shared__ short Xs[128 * 128];   // x tile (swizzled)
    __shared__ short Wa[128 * 128];   // W1 chunk
    __shared__ short Wb[128 * 128];   // W2 chunk
    __shared__ short Ps[128 * 128];   // P = relu(x@W1f^T+b1f), bf16 (swizzled)
    int tid = threadIdx.x;
    int w = tid >> 6, lane = tid & 63;
    int wr = w >> 1, wc = w & 1;
    int m0 = blockIdx.x * 128;
    int lr = lane & 15;
    int lkq = lane >> 4;
    int srow_in = lane >> 4;
    int jp = lane & 15;
    int cr0 = (lane >> 4) * 4;
    int cc = lane & 15;

    // stage X tile once (K=128), swizzled like gemm_stage
#pragma unroll
    for (int inst = 0; inst < 8; ++inst) {
        int c = w * 8 + inst;
        int r = c * 4 + srow_in;
        int j = jp ^ (r & 7);
        gload_lds16(X + (size_t)(m0 + r) * 128 + j * 8, &Xs[c * 512]);
    }

    f32x4 acc[4][4] = {};
    for (int f = 0; f < 16; ++f) {
        // stage W1 chunk: rows f*128..+128, K=128 (contiguous 32KB)
#pragma unroll
        for (int inst = 0; inst < 8; ++inst) {
            int c = w * 8 + inst;
            int r = c * 4 + srow_in;
            int j = jp ^ (r & 7);
            gload_lds16(W1w + (size_t)(f * 128 + r) * 128 + j * 8, &Wa[c * 512]);
        }
        __syncthreads();   // drains Xs(f==0)+Wa loads; fences Ps/Wb reuse from prev chunk
        // bias1 for this lane's 4 output cols (consumed at Ps write — latency covered)
        float bv[4];
#pragma unroll
        for (int jj = 0; jj < 4; ++jj) bv[jj] = bias1[f * 128 + wc * 64 + jj * 16 + cc];
        // gemm1: P = X @ W1f^T
        f32x4 acc1[4][4] = {};
#pragma unroll
        for (int kq = 0; kq < 4; ++kq) {
            int jlog = kq * 4 + lkq;
            short8v a[4], b[4];
#pragma unroll
            for (int i = 0; i < 4; ++i) {
                int ri = wr * 64 + i * 16 + lr;
                a[i] = *reinterpret_cast<const short8v*>(&Xs[ri * 128 + (jlog ^ (ri & 7)) * 8]);
            }
#pragma unroll
            for (int jj = 0; jj < 4; ++jj) {
                int rj = wc * 64 + jj * 16 + lr;
                b[jj] = *reinterpret_cast<const short8v*>(&Wa[rj * 128 + (jlog ^ (rj & 7)) * 8]);
            }
#pragma unroll
            for (int i = 0; i < 4; ++i)
#pragma unroll
                for (int jj = 0; jj < 4; ++jj)
                    acc1[i][jj] = __builtin_amdgcn_mfma_f32_16x16x32_bf16(
                        a[i], b[jj], acc1[i][jj], 0, 0, 0);
        }
        // stage W2 chunk while gemm1 results settle: rows n=0..127, k=f*128..+128
#pragma unroll
        for (int inst = 0; inst < 8; ++inst) {
            int c = w * 8 + inst;
            int r = c * 4 + srow_in;
            int j = jp ^ (r & 7);
            gload_lds16(W2w + (size_t)r * 2048 + f * 128 + j * 8, &Wb[c * 512]);
        }
        // relu+bias+cvt -> Ps (swizzled: phys = row*128 + ((col>>3 ^ row&7)*8 + col&7))
#pragma unroll
        for (int i = 0; i < 4; ++i)
#pragma unroll
            for (int jj = 0; jj < 4; ++jj) {
                int col = wc * 64 + jj * 16 + cc;
                int jc = col >> 3, ec = col & 7;
#pragma unroll
                for (int r = 0; r < 4; ++r) {
                    int row = wr * 64 + i * 16 + cr0 + r;
                    float v = fmaxf(acc1[i][jj][r] + bv[jj], 0.f);
                    Ps[row * 128 + ((jc ^ (row & 7)) * 8 + ec)] = f2b(v);
                }
            }
        __syncthreads();   // drains Wb loads + Ps ds_writes
        // gemm2: acc += P @ W2f^T
#pragma unroll
        for (int kq = 0; kq < 4; ++kq) {
            int jlog = kq * 4 + lkq;
            short8v a[4], b[4];
#pragma unroll
            for (int i = 0; i < 4; ++i) {
                int ri = wr * 64 + i * 16 + lr;
                a[i] = *reinterpret_cast<const short8v*>(&Ps[ri * 128 + (jlog ^ (ri & 7)) * 8]);
            }
#pragma unroll
            for (int jj = 0; jj < 4; ++jj) {
                int rj = wc * 64 + jj * 16 + lr;
                b[jj] = *reinterpret_cast<const short8v*>(&Wb[rj * 128 + (jlog ^ (rj & 7)) * 8]);
            }
#pragma unroll
            for (int i = 0; i < 4; ++i)
#pragma unroll
                for (int jj = 0; jj < 4; ++jj)
                    acc[i][jj] = __builtin_amdgcn_mfma_f32_16x16x32_bf16(
                        a[i], b[jj], acc[i][jj], 0, 0, 0);
        }
    }
    // epilogue: out = acc + b2 (fp32, for addln)
#pragma unroll
    for (int i = 0; i < 4; ++i)
#pragma unroll
        for (int jj = 0; jj < 4; ++jj) {
            int col = wc * 64 + jj * 16 + cc;
            float bias = bias2[col];
#pragma unroll
            for (int r = 0; r < 4; ++r) {
                int row = m0 + wr * 64 + i * 16 + cr0 + r;
                out[(size_t)row * Dm + col] = acc[i][jj][r] + bias;
            }
        }
}

// ---------------------------------------------------------------- LSTM (MFMA matvec v5, frozen)
__global__ __launch_bounds__(256, 1) void lstm_kernel(
    const float* __restrict__ xW, const short* __restrict__ Whh_b,
    short* __restrict__ xb_out)
{
    __shared__ __align__(16) short hb[2][Dm];
    __shared__ __align__(16) float xs[2][8 * 512];
    int b = blockIdx.x;
    int tid = threadIdx.x;
    int w = tid >> 6;
    int lane = tid & 63;
    int lr = lane & 15;
    int lk = (lane >> 4) * 8;
    int cr0 = (lane >> 4) * 4;
    int qs = lr >> 2;
    int qr = lr & 3;
    int d = w * 32 + qs * 16 + cr0 + qr;
    bool owner = (lr < 8);

    short8v a[4][2][4];
#pragma unroll
    for (int g = 0; g < 4; ++g)
#pragma unroll
        for (int s = 0; s < 2; ++s)
#pragma unroll
            for (int k = 0; k < 4; ++k)
                a[g][s][k] = *reinterpret_cast<const short8v*>(
                    &Whh_b[(size_t)(g * 128 + w * 32 + s * 16 + lr) * Dm + k * 32 + lk]);

    const float* xwb = xW + (size_t)b * Lq * 512;
    auto stage = [&](int c, int buf) {
        const float* src = xwb + (size_t)c * 4096 + w * 1024 + lane * 4;
        float* dst = &xs[buf][w * 1024];
#pragma unroll
        for (int i = 0; i < 4; ++i)
            gload_lds16f(src + i * 256, dst + i * 256);
    };

    float cpers = 0.f;
    if (tid < 64) reinterpret_cast<int*>(hb[0])[tid] = 0;
    stage(0, 0);
    stage(1, 1);

    short* xo = xb_out + (size_t)b * Lq * Dm + d;
    short hsv[8];
    asm volatile("s_waitcnt lgkmcnt(0)" ::: "memory");

    for (int c = 0; c < 64; ++c) {
        int buf = c & 1;
        asm volatile("s_waitcnt vmcnt(4)" ::: "memory");
        __builtin_amdgcn_sched_barrier(0);
        __builtin_amdgcn_s_barrier();
#pragma unroll
        for (int s8 = 0; s8 < 8; ++s8) {
            short8v bf[4];
#pragma unroll
            for (int k = 0; k < 4; ++k)
                bf[k] = *reinterpret_cast<const short8v*>(&hb[s8 & 1][k * 32 + lk]);
            f32x4 acc[4][2] = {};
#pragma unroll
            for (int k = 0; k < 4; ++k)
#pragma unroll
                for (int g = 0; g < 4; ++g)
#pragma unroll
                    for (int s = 0; s < 2; ++s)
                        acc[g][s] = __builtin_amdgcn_mfma_f32_16x16x32_bf16(
                            a[g][s][k], bf[k], acc[g][s], 0, 0, 0);
            if (owner) {
                float iraw = 0.f, fraw = 0.f, graw = 0.f, oraw = 0.f;
#pragma unroll
                for (int s = 0; s < 2; ++s)
#pragma unroll
                    for (int r = 0; r < 4; ++r)
                        if (qs == s && qr == r) {
                            iraw = acc[0][s][r]; fraw = acc[1][s][r];
                            graw = acc[2][s][r]; oraw = acc[3][s][r];
                        }
                iraw += xs[buf][s8 * 512 + 0 * 128 + d];
                fraw += xs[buf][s8 * 512 + 1 * 128 + d];
                graw += xs[buf][s8 * 512 + 2 * 128 + d];
                oraw += xs[buf][s8 * 512 + 3 * 128 + d];
                float ig = fsig(iraw);
                float fg = fsig(fraw);
                float gg = fast_tanh(graw);
                float og = fsig(oraw);
                cpers = fg * cpers + ig * gg;
                float h = og * fast_tanh(cpers);
                short hv = f2b(h);
                hsv[s8] = hv;
                hb[(s8 & 1) ^ 1][d] = hv;
            }
            asm volatile("s_waitcnt lgkmcnt(0)" ::: "memory");
            __builtin_amdgcn_s_barrier();
        }
        int cn = (c + 2 < 64) ? c + 2 : 63;
        stage(cn, buf);
        if (owner) {
#pragma unroll
            for (int s8 = 0; s8 < 8; ++s8)
                xo[(size_t)(c * 8 + s8) * Dm] = hsv[s8];
        }
    }
}

// ------------------------------------------------------------- attention (bf16 qkv in)
__global__ __launch_bounds__(256) void attn_kernel(
    const short* __restrict__ qkvb, short* __restrict__ ctxb)
{
    __shared__ float Kb[Lq][16];
    __shared__ float Vb[Lq][16];
    int h = blockIdx.x & (NHh - 1);
    int b = blockIdx.x >> 3;
    int t = threadIdx.x;
    const short* base = qkvb + (size_t)b * Lq * 384;
    int hoff = h * 16;
    for (int i = t; i < Lq * 2; i += 256) {
        int row = i >> 1, half = i & 1;
        short8v kv = *reinterpret_cast<const short8v*>(&base[(size_t)row * 384 + 128 + hoff + half * 8]);
        short8v vv = *reinterpret_cast<const short8v*>(&base[(size_t)row * 384 + 256 + hoff + half * 8]);
#pragma unroll
        for (int e = 0; e < 8; ++e) {
            Kb[row][half * 8 + e] = b2f(kv[e]);
            Vb[row][half * 8 + e] = b2f(vv[e]);
        }
    }
    __syncthreads();
    for (int rr = 0; rr < 2; ++rr) {
        int l = t + rr * 256;
        short8v q0 = *reinterpret_cast<const short8v*>(&base[(size_t)l * 384 + hoff]);
        short8v q1 = *reinterpret_cast<const short8v*>(&base[(size_t)l * 384 + hoff + 8]);
        float q[16];
#pragma unroll
        for (int e = 0; e < 8; ++e) { q[e] = b2f(q0[e]); q[8 + e] = b2f(q1[e]); }
        float m = -1e30f, ssum = 0.f;
        float acc[16] = {};
        for (int jr = 0; jr < Lq; ++jr) {
            float s = 0.f;
#pragma unroll
            for (int cc = 0; cc < 16; ++cc) s += q[cc] * Kb[jr][cc];
            s *= 0.25f;
            if (s > m) {
                float corr = __expf(m - s);
                ssum *= corr;
#pragma unroll
                for (int cc = 0; cc < 16; ++cc) acc[cc] *= corr;
                m = s;
            }
            float p = __expf(s - m);
            ssum += p;
#pragma unroll
            for (int cc = 0; cc < 16; ++cc) acc[cc] += p * Vb[jr][cc];
        }
        float inv = __builtin_amdgcn_rcpf(ssum);
        short8v v0, v1;
#pragma unroll
        for (int cc = 0; cc < 8; ++cc) { v0[cc] = f2b(acc[cc] * inv); v1[cc] = f2b(acc[cc + 8] * inv); }
        short* o = ctxb + ((size_t)b * Lq + l) * Dm + hoff;
        *reinterpret_cast<short8v*>(o) = v0;
        *reinterpret_cast<short8v*>(o + 8) = v1;
    }
}

// -------------------- residual add + LN (+ bf16 mirror); optional bf16 base
__global__ __launch_bounds__(256) void addln_kernel(
    float* __restrict__ x, const short* __restrict__ base_b,
    const float* __restrict__ add,
    const float* __restrict__ g, const float* __restrict__ bta,
    short* __restrict__ xb)
{
    int wave = threadIdx.x >> 6;
    int lane = threadIdx.x & 63;
    int row = blockIdx.x * 4 + wave;
    float* xr = x + (size_t)row * Dm;
    const float* ar = add + (size_t)row * Dm;
    int d0 = lane * 2;
    float b0, b1v;
    if (base_b) {
        unsigned pk = *reinterpret_cast<const unsigned*>(&base_b[(size_t)row * Dm + d0]);
        b0 = b2f((short)(pk & 0xffff));
        b1v = b2f((short)(pk >> 16));
    } else {
        float2 xv = *reinterpret_cast<const float2*>(&xr[d0]);
        b0 = xv.x; b1v = xv.y;
    }
    float2 av = *reinterpret_cast<const float2*>(&ar[d0]);
    float v0 = b0 + av.x, v1 = b1v + av.y;
    float s = v0 + v1;
#pragma unroll
    for (int off = 32; off > 0; off >>= 1) s += __shfl_xor(s, off);
    float mu = s * (1.f / Dm);
    float e0 = v0 - mu, e1 = v1 - mu;
    float s2 = e0 * e0 + e1 * e1;
#pragma unroll
    for (int off = 32; off > 0; off >>= 1) s2 += __shfl_xor(s2, off);
    float rs = rsqrtf(s2 * (1.f / Dm) + EPSf);
    float o0 = e0 * rs * g[d0] + bta[d0];
    float o1 = e1 * rs * g[d0 + 1] + bta[d0 + 1];
    xr[d0] = o0;
    xr[d0 + 1] = o1;
    unsigned pk = (unsigned)(unsigned short)f2b(o0) | ((unsigned)(unsigned short)f2b(o1) << 16);
    *reinterpret_cast<unsigned*>(&xb[(size_t)row * Dm + d0]) = pk;
}

// --------------------------------------------------------------- head
__global__ void head_kernel(const float* __restrict__ x,
                            const float* __restrict__ head_w, const float* __restrict__ head_b,
                            const float* __restrict__ gw1, const float* __restrict__ gb1,
                            const float* __restrict__ gw2, const float* __restrict__ gb2,
                            const float* __restrict__ garch,
                            float* __restrict__ out)
{
    __shared__ float last[Dm];
    __shared__ float t1[Dm / 2];
    int b = blockIdx.x, t = threadIdx.x;
    if (t < Dm) last[t] = x[((size_t)b * Lq + (Lq - 1)) * Dm + t];
    __syncthreads();
    if (t < Dm / 2) {
        float s = gb1[t];
#pragma unroll 8
        for (int d = 0; d < Dm; ++d) s += last[d] * gw1[(size_t)t * Dm + d];
        t1[t] = fmaxf(s, 0.f);
    }
    __syncthreads();
    if (t < PLn) {
        float ai = head_b[t];
#pragma unroll 8
        for (int d = 0; d < Dm; ++d) ai += last[d] * head_w[(size_t)t * Dm + d];
        float gg = gb2[t];
#pragma unroll 8
        for (int j = 0; j < Dm / 2; ++j) gg += t1[j] * gw2[(size_t)t * (Dm / 2) + j];
        float gate = 1.f / (1.f + __expf(-gg));
        out[b * PLn + t] = garch[b * PLn + t] + gate * ai;
    }
}

extern "C" void kernel_launch(void* const* d_in, const int* in_sizes, int n_in,
                              void* d_out, int out_size, void* d_ws, size_t ws_size,
                              hipStream_t stream)
{
    const float* x_enc  = (const float*)d_in[0];
    const float* x_mark = (const float*)d_in[1];
    const float* conv_w = (const float*)d_in[4];
    const float* temp_w = (const float*)d_in[5];
    const float* Wih    = (const float*)d_in[6];
    const float* Whh    = (const float*)d_in[7];
    const float* bih    = (const float*)d_in[8];
    const float* bhh    = (const float*)d_in[9];
    const float* Wqkv   = (const float*)d_in[10];
    const float* bqkv   = (const float*)d_in[11];
    const float* Wo     = (const float*)d_in[12];
    const float* bo     = (const float*)d_in[13];
    const float* ln1g   = (const float*)d_in[14];
    const float* ln1b   = (const float*)d_in[15];
    const float* W1     = (const float*)d_in[16];
    const float* b1     = (const float*)d_in[17];
    const float* W2     = (const float*)d_in[18];
    const float* b2     = (const float*)d_in[19];
    const float* ln2g   = (const float*)d_in[20];
    const float* ln2b   = (const float*)d_in[21];
    const float* head_w = (const float*)d_in[22];
    const float* head_b = (const float*)d_in[23];
    const float* gw1    = (const float*)d_in[24];
    const float* gb1    = (const float*)d_in[25];
    const float* gw2    = (const float*)d_in[26];
    const float* gb2    = (const float*)d_in[27];
    const float* g_omega= (const float*)d_in[28];
    const float* g_alpha= (const float*)d_in[29];
    const float* g_beta = (const float*)d_in[30];
    const float* g_h0   = (const float*)d_in[31];

    const int M = Bn * Lq;                    // 32768
    float* ws    = (float*)d_ws;
    float* garch = ws;                        // 6144 used
    float* biassum = ws + 6144;               // 512 floats (bih+bhh)
    float* regionA = ws + 8192;               // 4,194,304 floats
    short* xb   = (short*)regionA;            //   bf16 x mirror (after lstm)
    short* ctxb = (short*)(regionA + 2097152);//   bf16 ctx
    float* xWr  = regionA + 4194304;          // 16,777,216 floats
    float* xW   = xWr;                        //   fp32 xW (dead after lstm)
    float* x    = xWr + 16777216;             // 4,194,304 floats (live all launch)
    float* qkvr = x + 4194304;                // 12,582,912 floats
    short* encb = (short*)qkvr;               //   bf16 enc (dead after xW gemm)
    short* qkvb = (short*)qkvr;               //   bf16 qkv (dead once ctx built)
    float* tmp  = qkvr;                       //   fp32 tmp (aliases qkvb after attn)
    float* wbr  = qkvr + 12582912;            // bf16 weight mirrors
    short* Wqkv_b = (short*)wbr;              // 98,304
    short* Wo_b   = Wqkv_b + 98304;           // 32,768
    short* W1_b   = Wo_b + 32768;             // 524,288
    short* W2_b   = W1_b + 524288;            // 524,288
    short* Whh_bb = W2_b + 524288;            // 65,536
    short* Wih_b  = Whh_bb + 65536;           // 65,536

    prep_kernel<<<5122, 256, 0, stream>>>(Wqkv, Wo, W1, W2, Whh, Wih, bih, bhh,
                                          Wqkv_b, Wo_b, W1_b, W2_b, Whh_bb, Wih_b, biassum);
    enc_kernel<<<(Bn * Lq * Dm) / 256, 256, 0, stream>>>(
        x_enc, x_mark, conv_w, temp_w, encb, g_omega, g_alpha, g_beta, g_h0, garch);
    gemm_stage<<<dim3(M / 128, 512 / 128), 256, 0, stream>>>(
        encb, Wih_b, biassum, xW, nullptr, M, 512, Dm, 0);
    lstm_kernel<<<Bn, 256, 0, stream>>>(xW, Whh_bb, xb);

    for (int li = 0; li < ELn; ++li) {
        gemm_stage<<<dim3(M / 128, 384 / 128), 256, 0, stream>>>(
            xb, Wqkv_b + (size_t)li * 384 * Dm, bqkv + li * 384, nullptr, qkvb, M, 384, Dm, 0);
        attn_kernel<<<Bn * NHh, 256, 0, stream>>>(qkvb, ctxb);
        gemm_stage<<<dim3(M / 128, Dm / 128), 256, 0, stream>>>(
            ctxb, Wo_b + (size_t)li * Dm * Dm, bo + li * Dm, tmp, nullptr, M, Dm, Dm, 0);
        addln_kernel<<<M / 4, 256, 0, stream>>>(
            x, (li == 0) ? xb : nullptr, tmp, ln1g + li * Dm, ln1b + li * Dm, xb);
        ffn_fused<<<M / 128, 256, 0, stream>>>(
            xb, W1_b + (size_t)li * DFFn * Dm, b1 + li * DFFn,
            W2_b + (size_t)li * Dm * DFFn, b2 + li * Dm, tmp);
        addln_kernel<<<M / 4, 256, 0, stream>>>(
            x, nullptr, tmp, ln2g + li * Dm, ln2b + li * Dm, xb);
    }
    head_kernel<<<Bn, 128, 0, stream>>>(x, head_w, head_b, gw1, gb1, gw2, gb2, garch,
                                        (float*)d_out);
}

// Round 16
// 816.508 us; speedup vs baseline: 1.8482x; 1.3165x over previous
//
#include <hip/hip_runtime.h>
#include <hip/hip_bf16.h>
#include <math.h>

#define Bn 64
#define Lq 512
#define Dm 128
#define NHh 8
#define ELn 2
#define PLn 96
#define CINn 8
#define DFFn 2048
#define NTFn 4
#define EPSf 1e-5f

typedef __attribute__((ext_vector_type(8))) short short8v;
typedef __attribute__((ext_vector_type(4))) float f32x4;

__device__ __forceinline__ short f2b(float f) {
    union { float f; unsigned u; } v; v.f = f;
    unsigned r = v.u + 0x7fff + ((v.u >> 16) & 1);
    return (short)(r >> 16);
}
__device__ __forceinline__ float b2f(short s) {
    union { unsigned u; float f; } v;
    v.u = ((unsigned)(unsigned short)s) << 16;
    return v.f;
}
__device__ __forceinline__ float fsig(float x) {
    return __builtin_amdgcn_rcpf(1.f + __expf(-x));
}
__device__ __forceinline__ float fast_tanh(float x) {
    float ax = fabsf(x);
    float e = __expf(2.f * ax);
    float t = 1.f - 2.f * __builtin_amdgcn_rcpf(e + 1.f);
    return copysignf(t, x);
}
__device__ __forceinline__ void gload_lds16(const short* g, short* l) {
    __builtin_amdgcn_global_load_lds(
        (const __attribute__((address_space(1))) void*)g,
        (__attribute__((address_space(3))) void*)l, 16, 0, 0);
}
__device__ __forceinline__ void gload_lds16f(const float* g, float* l) {
    __builtin_amdgcn_global_load_lds(
        (const __attribute__((address_space(1))) void*)g,
        (__attribute__((address_space(3))) void*)l, 16, 0, 0);
}
__device__ __forceinline__ short8v zero8() {
    short8v z;
#pragma unroll
    for (int e = 0; e < 8; ++e) z[e] = 0;
    return z;
}

// ---------------- fused prep: all weight bf16 conversions + bias sum (1 launch)
__global__ void prep_kernel(const float* __restrict__ Wqkv, const float* __restrict__ Wo,
                            const float* __restrict__ W1, const float* __restrict__ W2,
                            const float* __restrict__ Whh, const float* __restrict__ Wih,
                            const float* __restrict__ bih, const float* __restrict__ bhh,
                            short* __restrict__ Wqkv_b, short* __restrict__ Wo_b,
                            short* __restrict__ W1_b, short* __restrict__ W2_b,
                            short* __restrict__ Whh_b, short* __restrict__ Wih_b,
                            float* __restrict__ biassum)
{
    int i = blockIdx.x * 256 + threadIdx.x;
    if (i < 98304)        Wqkv_b[i] = f2b(Wqkv[i]);
    else if (i < 131072)  { int j = i - 98304;   Wo_b[j]  = f2b(Wo[j]); }
    else if (i < 655360)  { int j = i - 131072;  W1_b[j]  = f2b(W1[j]); }
    else if (i < 1179648) { int j = i - 655360;  W2_b[j]  = f2b(W2[j]); }
    else if (i < 1245184) { int j = i - 1179648; Whh_b[j] = f2b(Whh[j]); }
    else if (i < 1310720) { int j = i - 1245184; Wih_b[j] = f2b(Wih[j]); }
    else if (i < 1311232) { int j = i - 1310720; biassum[j] = bih[j] + bhh[j]; }
}

// ------------------------------- conv + temporal + pos (bf16 out) + fused GARCH
__global__ void enc_kernel(const float* __restrict__ x_enc,
                           const float* __restrict__ x_mark,
                           const float* __restrict__ conv_w,
                           const float* __restrict__ temp_w,
                           short* __restrict__ encb,
                           const float* __restrict__ g_omega,
                           const float* __restrict__ g_alpha,
                           const float* __restrict__ g_beta,
                           const float* __restrict__ g_h0,
                           float* __restrict__ garch)
{
    int idx = blockIdx.x * blockDim.x + threadIdx.x;   // over B*L*D
    int d = idx & (Dm - 1);
    int l = (idx >> 7) & (Lq - 1);
    int b = idx >> 16;
    int lm = (l + Lq - 1) & (Lq - 1);
    int lp = (l + 1) & (Lq - 1);
    const float* xb = x_enc + (size_t)b * Lq * CINn;
    const float* w  = conv_w + (size_t)d * CINn * 3;
    float acc = 0.f;
#pragma unroll
    for (int ci = 0; ci < CINn; ++ci) {
        acc += xb[(size_t)lm * CINn + ci] * w[ci * 3 + 0];
        acc += xb[(size_t)l  * CINn + ci] * w[ci * 3 + 1];
        acc += xb[(size_t)lp * CINn + ci] * w[ci * 3 + 2];
    }
    const float* mk = x_mark + ((size_t)b * Lq + l) * NTFn;
    const float* tw = temp_w + (size_t)d * NTFn;
#pragma unroll
    for (int f = 0; f < NTFn; ++f) acc += mk[f] * tw[f];
    float dv = __expf(-(float)(d & ~1) * (9.210340371976184f / 128.f));
    float ang = (float)l * dv;
    acc += (d & 1) ? cosf(ang) : sinf(ang);
    encb[idx] = f2b(acc);

    if (blockIdx.x == 0 && threadIdx.x < Bn) {
        int bb = threadIdx.x;
        float omega = log1pf(__expf(g_omega[0]));
        float alpha = 0.2f / (1.f + __expf(-g_alpha[0]));
        float beta  = 0.8f / (1.f + __expf(-g_beta[0]));
        float h = log1pf(__expf(g_h0[0]));
        const float* xe = x_enc + (size_t)bb * Lq * CINn + (CINn - 2);
        for (int t = 0; t < Lq; ++t) {
            float r = xe[(size_t)t * CINn];
            h = omega + alpha * r * r + beta * h;
        }
        float ab = alpha + beta;
        for (int p = 0; p < PLn; ++p) {
            garch[bb * PLn + p] = sqrtf(h);
            h = omega + ab * h;
        }
    }
}

// ---------------- staged+swizzled bf16 MFMA GEMM, tile 128x128, BK=128
__global__ __launch_bounds__(256) void gemm_stage(
    const short* __restrict__ A, const short* __restrict__ W,
    const float* __restrict__ b1,
    float* __restrict__ Cf, short* __restrict__ Cb,
    int M, int N, int K, int relu)
{
    __shared__ short As[128 * 128];
    __shared__ short Ws[128 * 128];
    int tid = threadIdx.x;
    int w = tid >> 6, lane = tid & 63;
    int wr = w >> 1, wc = w & 1;
    int m0 = blockIdx.x * 128, n0 = blockIdx.y * 128;
    int lr = lane & 15;
    int lkq = lane >> 4;
    int srow_in = lane >> 4;
    int jp = lane & 15;
    f32x4 acc[4][4] = {};

    for (int k0 = 0; k0 < K; k0 += 128) {
        if (k0) __syncthreads();
#pragma unroll
        for (int inst = 0; inst < 8; ++inst) {
            int c = w * 8 + inst;
            int r = c * 4 + srow_in;
            int j = jp ^ (r & 7);
            gload_lds16(A + (size_t)(m0 + r) * K + k0 + j * 8, &As[c * 512]);
            gload_lds16(W + (size_t)(n0 + r) * K + k0 + j * 8, &Ws[c * 512]);
        }
        __syncthreads();
#pragma unroll
        for (int kq = 0; kq < 4; ++kq) {
            int jlog = kq * 4 + lkq;
            short8v a[4], b[4];
#pragma unroll
            for (int i = 0; i < 4; ++i) {
                int ri = wr * 64 + i * 16 + lr;
                a[i] = *reinterpret_cast<const short8v*>(&As[ri * 128 + (jlog ^ (ri & 7)) * 8]);
            }
#pragma unroll
            for (int jj = 0; jj < 4; ++jj) {
                int rj = wc * 64 + jj * 16 + lr;
                b[jj] = *reinterpret_cast<const short8v*>(&Ws[rj * 128 + (jlog ^ (rj & 7)) * 8]);
            }
#pragma unroll
            for (int i = 0; i < 4; ++i)
#pragma unroll
                for (int jj = 0; jj < 4; ++jj)
                    acc[i][jj] = __builtin_amdgcn_mfma_f32_16x16x32_bf16(
                        a[i], b[jj], acc[i][jj], 0, 0, 0);
        }
    }
    int cr0 = (lane >> 4) * 4;
    int cc = lane & 15;
#pragma unroll
    for (int i = 0; i < 4; ++i)
#pragma unroll
        for (int jj = 0; jj < 4; ++jj) {
            int col = n0 + wc * 64 + jj * 16 + cc;
            float bias = b1[col];
#pragma unroll
            for (int r = 0; r < 4; ++r) {
                int row = m0 + wr * 64 + i * 16 + cr0 + r;
                float v = acc[i][jj][r] + bias;
                if (relu) v = fmaxf(v, 0.f);
                if (Cf) Cf[(size_t)row * N + col] = v;
                else    Cb[(size_t)row * N + col] = f2b(v);
            }
        }
}

// ---------------- fused FFN: out = relu(X@W1^T+b1)@W2^T + b2, ff1 never in HBM
__global__ __launch_bounds__(256, 1) void ffn_fused(
    const short* __restrict__ X, const short* __restrict__ W1w,
    const float* __restrict__ bias1,
    const short* __restrict__ W2w, const float* __restrict__ bias2,
    float* __restrict__ out)
{
    __shared__ short Xs[128 * 128];
    __shared__ short Wa[128 * 128];
    __shared__ short Wb[128 * 128];
    __shared__ short Ps[128 * 128];
    int tid = threadIdx.x;
    int w = tid >> 6, lane = tid & 63;
    int wr = w >> 1, wc = w & 1;
    int m0 = blockIdx.x * 128;
    int lr = lane & 15;
    int lkq = lane >> 4;
    int srow_in = lane >> 4;
    int jp = lane & 15;
    int cr0 = (lane >> 4) * 4;
    int cc = lane & 15;

#pragma unroll
    for (int inst = 0; inst < 8; ++inst) {
        int c = w * 8 + inst;
        int r = c * 4 + srow_in;
        int j = jp ^ (r & 7);
        gload_lds16(X + (size_t)(m0 + r) * 128 + j * 8, &Xs[c * 512]);
    }

    f32x4 acc[4][4] = {};
    for (int f = 0; f < 16; ++f) {
#pragma unroll
        for (int inst = 0; inst < 8; ++inst) {
            int c = w * 8 + inst;
            int r = c * 4 + srow_in;
            int j = jp ^ (r & 7);
            gload_lds16(W1w + (size_t)(f * 128 + r) * 128 + j * 8, &Wa[c * 512]);
        }
        __syncthreads();
        float bv[4];
#pragma unroll
        for (int jj = 0; jj < 4; ++jj) bv[jj] = bias1[f * 128 + wc * 64 + jj * 16 + cc];
        f32x4 acc1[4][4] = {};
#pragma unroll
        for (int kq = 0; kq < 4; ++kq) {
            int jlog = kq * 4 + lkq;
            short8v a[4], b[4];
#pragma unroll
            for (int i = 0; i < 4; ++i) {
                int ri = wr * 64 + i * 16 + lr;
                a[i] = *reinterpret_cast<const short8v*>(&Xs[ri * 128 + (jlog ^ (ri & 7)) * 8]);
            }
#pragma unroll
            for (int jj = 0; jj < 4; ++jj) {
                int rj = wc * 64 + jj * 16 + lr;
                b[jj] = *reinterpret_cast<const short8v*>(&Wa[rj * 128 + (jlog ^ (rj & 7)) * 8]);
            }
#pragma unroll
            for (int i = 0; i < 4; ++i)
#pragma unroll
                for (int jj = 0; jj < 4; ++jj)
                    acc1[i][jj] = __builtin_amdgcn_mfma_f32_16x16x32_bf16(
                        a[i], b[jj], acc1[i][jj], 0, 0, 0);
        }
#pragma unroll
        for (int inst = 0; inst < 8; ++inst) {
            int c = w * 8 + inst;
            int r = c * 4 + srow_in;
            int j = jp ^ (r & 7);
            gload_lds16(W2w + (size_t)r * 2048 + f * 128 + j * 8, &Wb[c * 512]);
        }
#pragma unroll
        for (int i = 0; i < 4; ++i)
#pragma unroll
            for (int jj = 0; jj < 4; ++jj) {
                int col = wc * 64 + jj * 16 + cc;
                int jc = col >> 3, ec = col & 7;
#pragma unroll
                for (int r = 0; r < 4; ++r) {
                    int row = wr * 64 + i * 16 + cr0 + r;
                    float v = fmaxf(acc1[i][jj][r] + bv[jj], 0.f);
                    Ps[row * 128 + ((jc ^ (row & 7)) * 8 + ec)] = f2b(v);
                }
            }
        __syncthreads();
#pragma unroll
        for (int kq = 0; kq < 4; ++kq) {
            int jlog = kq * 4 + lkq;
            short8v a[4], b[4];
#pragma unroll
            for (int i = 0; i < 4; ++i) {
                int ri = wr * 64 + i * 16 + lr;
                a[i] = *reinterpret_cast<const short8v*>(&Ps[ri * 128 + (jlog ^ (ri & 7)) * 8]);
            }
#pragma unroll
            for (int jj = 0; jj < 4; ++jj) {
                int rj = wc * 64 + jj * 16 + lr;
                b[jj] = *reinterpret_cast<const short8v*>(&Wb[rj * 128 + (jlog ^ (rj & 7)) * 8]);
            }
#pragma unroll
            for (int i = 0; i < 4; ++i)
#pragma unroll
                for (int jj = 0; jj < 4; ++jj)
                    acc[i][jj] = __builtin_amdgcn_mfma_f32_16x16x32_bf16(
                        a[i], b[jj], acc[i][jj], 0, 0, 0);
        }
    }
#pragma unroll
    for (int i = 0; i < 4; ++i)
#pragma unroll
        for (int jj = 0; jj < 4; ++jj) {
            int col = wc * 64 + jj * 16 + cc;
            float bias = bias2[col];
#pragma unroll
            for (int r = 0; r < 4; ++r) {
                int row = m0 + wr * 64 + i * 16 + cr0 + r;
                out[(size_t)row * Dm + col] = acc[i][jj][r] + bias;
            }
        }
}

// ---------------------------------------------------------------- LSTM (MFMA matvec v5, frozen)
__global__ __launch_bounds__(256, 1) void lstm_kernel(
    const float* __restrict__ xW, const short* __restrict__ Whh_b,
    short* __restrict__ xb_out)
{
    __shared__ __align__(16) short hb[2][Dm];
    __shared__ __align__(16) float xs[2][8 * 512];
    int b = blockIdx.x;
    int tid = threadIdx.x;
    int w = tid >> 6;
    int lane = tid & 63;
    int lr = lane & 15;
    int lk = (lane >> 4) * 8;
    int cr0 = (lane >> 4) * 4;
    int qs = lr >> 2;
    int qr = lr & 3;
    int d = w * 32 + qs * 16 + cr0 + qr;
    bool owner = (lr < 8);

    short8v a[4][2][4];
#pragma unroll
    for (int g = 0; g < 4; ++g)
#pragma unroll
        for (int s = 0; s < 2; ++s)
#pragma unroll
            for (int k = 0; k < 4; ++k)
                a[g][s][k] = *reinterpret_cast<const short8v*>(
                    &Whh_b[(size_t)(g * 128 + w * 32 + s * 16 + lr) * Dm + k * 32 + lk]);

    const float* xwb = xW + (size_t)b * Lq * 512;
    auto stage = [&](int c, int buf) {
        const float* src = xwb + (size_t)c * 4096 + w * 1024 + lane * 4;
        float* dst = &xs[buf][w * 1024];
#pragma unroll
        for (int i = 0; i < 4; ++i)
            gload_lds16f(src + i * 256, dst + i * 256);
    };

    float cpers = 0.f;
    if (tid < 64) reinterpret_cast<int*>(hb[0])[tid] = 0;
    stage(0, 0);
    stage(1, 1);

    short* xo = xb_out + (size_t)b * Lq * Dm + d;
    short hsv[8];
    asm volatile("s_waitcnt lgkmcnt(0)" ::: "memory");

    for (int c = 0; c < 64; ++c) {
        int buf = c & 1;
        asm volatile("s_waitcnt vmcnt(4)" ::: "memory");
        __builtin_amdgcn_sched_barrier(0);
        __builtin_amdgcn_s_barrier();
#pragma unroll
        for (int s8 = 0; s8 < 8; ++s8) {
            short8v bf[4];
#pragma unroll
            for (int k = 0; k < 4; ++k)
                bf[k] = *reinterpret_cast<const short8v*>(&hb[s8 & 1][k * 32 + lk]);
            f32x4 acc[4][2] = {};
#pragma unroll
            for (int k = 0; k < 4; ++k)
#pragma unroll
                for (int g = 0; g < 4; ++g)
#pragma unroll
                    for (int s = 0; s < 2; ++s)
                        acc[g][s] = __builtin_amdgcn_mfma_f32_16x16x32_bf16(
                            a[g][s][k], bf[k], acc[g][s], 0, 0, 0);
            if (owner) {
                float iraw = 0.f, fraw = 0.f, graw = 0.f, oraw = 0.f;
#pragma unroll
                for (int s = 0; s < 2; ++s)
#pragma unroll
                    for (int r = 0; r < 4; ++r)
                        if (qs == s && qr == r) {
                            iraw = acc[0][s][r]; fraw = acc[1][s][r];
                            graw = acc[2][s][r]; oraw = acc[3][s][r];
                        }
                iraw += xs[buf][s8 * 512 + 0 * 128 + d];
                fraw += xs[buf][s8 * 512 + 1 * 128 + d];
                graw += xs[buf][s8 * 512 + 2 * 128 + d];
                oraw += xs[buf][s8 * 512 + 3 * 128 + d];
                float ig = fsig(iraw);
                float fg = fsig(fraw);
                float gg = fast_tanh(graw);
                float og = fsig(oraw);
                cpers = fg * cpers + ig * gg;
                float h = og * fast_tanh(cpers);
                short hv = f2b(h);
                hsv[s8] = hv;
                hb[(s8 & 1) ^ 1][d] = hv;
            }
            asm volatile("s_waitcnt lgkmcnt(0)" ::: "memory");
            __builtin_amdgcn_s_barrier();
        }
        int cn = (c + 2 < 64) ? c + 2 : 63;
        stage(cn, buf);
        if (owner) {
#pragma unroll
            for (int s8 = 0; s8 < 8; ++s8)
                xo[(size_t)(c * 8 + s8) * Dm] = hsv[s8];
        }
    }
}

// ------------------------------------------------- MFMA flash attention
// block = (b,h), 4 waves x 128 q-rows. Swapped QK^T (mfma(K,Q)) puts S[q][key]
// lane-local (q=lane&15, 4 keys/lane). d=16 zero-padded to K=32 on inputs.
// P -> bf16 via per-wave LDS transpose (within-wave, no barriers) into the
// exact A-frag layout for PV over 32 keys. V frags in registers (loaded once).
// Defer-max (THR=8) makes O-rescale rare.
__global__ __launch_bounds__(256, 1) void attn_kernel(
    const short* __restrict__ qkvb, short* __restrict__ ctxb)
{
    __shared__ __align__(16) short Klds[512 * 16];   // [key][dim] bf16, 16KB
    __shared__ __align__(16) short Plds[4][16 * 40]; // per-wave P scratch [q][40]
    __shared__ __align__(16) float Flds[4][16];      // per-wave fac/inv scratch
    int h = blockIdx.x & (NHh - 1);
    int b = blockIdx.x >> 3;
    int tid = threadIdx.x;
    int w = tid >> 6, lane = tid & 63;
    int cc = lane & 15, kg = lane >> 4;
    const short* base = qkvb + (size_t)b * Lq * 384;
    int hoff = h * 16;

    // stage K into LDS: 512 rows x 32B
    for (int i = tid; i < 1024; i += 256) {
        int r = i >> 1, half = i & 1;
        *reinterpret_cast<short8v*>(&Klds[r * 16 + half * 8]) =
            *reinterpret_cast<const short8v*>(&base[(size_t)r * 384 + 128 + hoff + half * 8]);
    }

    // V register fragments: group g covers keys g*32..+31; lane holds
    // V[key=g*32+kg*8+e][dim=cc] (B-operand layout for 16x16x32)
    short8v vf[16];
#pragma unroll
    for (int g = 0; g < 16; ++g) {
        short8v v;
#pragma unroll
        for (int e = 0; e < 8; ++e)
            v[e] = base[(size_t)(g * 32 + kg * 8 + e) * 384 + 256 + hoff + cc];
        vf[g] = v;
    }
    __syncthreads();   // K staged

    int wq0 = w * 128;   // wave's q-row base
    for (int qt = 0; qt < 8; ++qt) {
        // Q B-frag: lane holds Q[q=wq0+qt*16+cc][dim kg*8+e], kg>=2 zero
        short8v qf = zero8();
        if (kg < 2)
            qf = *reinterpret_cast<const short8v*>(
                &base[(size_t)(wq0 + qt * 16 + cc) * 384 + hoff + kg * 8]);
        f32x4 O = {};
        float m = -1e30f, lsum = 0.f;
#pragma unroll
        for (int g = 0; g < 16; ++g) {
#pragma unroll
            for (int half = 0; half < 2; ++half) {
                int kt = g * 2 + half;
                short8v kf = zero8();
                if (kg < 2)
                    kf = *reinterpret_cast<const short8v*>(&Klds[(kt * 16 + cc) * 16 + kg * 8]);
                f32x4 s4 = __builtin_amdgcn_mfma_f32_16x16x32_bf16(kf, qf, f32x4{}, 0, 0, 0);
                float s0 = s4[0] * 0.25f, s1 = s4[1] * 0.25f;
                float s2 = s4[2] * 0.25f, s3 = s4[3] * 0.25f;
                float rmax = fmaxf(fmaxf(s0, s1), fmaxf(s2, s3));
                rmax = fmaxf(rmax, __shfl_xor(rmax, 16));
                rmax = fmaxf(rmax, __shfl_xor(rmax, 32));
                if (__any(rmax > m + 8.f)) {
                    float newm = fmaxf(m, rmax);
                    float fac = __expf(m - newm);
                    m = newm;
                    lsum *= fac;
                    if (kg == 0) Flds[w][cc] = fac;
                    f32x4 fv = *reinterpret_cast<f32x4*>(&Flds[w][kg * 4]);
                    O[0] *= fv[0]; O[1] *= fv[1]; O[2] *= fv[2]; O[3] *= fv[3];
                }
                float p0 = __expf(s0 - m), p1 = __expf(s1 - m);
                float p2 = __expf(s2 - m), p3 = __expf(s3 - m);
                lsum += (p0 + p1) + (p2 + p3);
                uint2 pk;
                pk.x = (unsigned)(unsigned short)f2b(p0) |
                       ((unsigned)(unsigned short)f2b(p1) << 16);
                pk.y = (unsigned)(unsigned short)f2b(p2) |
                       ((unsigned)(unsigned short)f2b(p3) << 16);
                *reinterpret_cast<uint2*>(&Plds[w][cc * 40 + half * 16 + kg * 4]) = pk;
            }
            // PV over the 32 keys of this group (within-wave LDS exchange)
            short8v pf = *reinterpret_cast<const short8v*>(&Plds[w][cc * 40 + kg * 8]);
            O = __builtin_amdgcn_mfma_f32_16x16x32_bf16(pf, vf[g], O, 0, 0, 0);
        }
        // finalize: l reduce + broadcast inverse to O-lane layout
        lsum += __shfl_xor(lsum, 16);
        lsum += __shfl_xor(lsum, 32);
        float inv = __builtin_amdgcn_rcpf(lsum);
        if (kg == 0) Flds[w][cc] = inv;
        f32x4 iv = *reinterpret_cast<f32x4*>(&Flds[w][kg * 4]);
        int qrow = wq0 + qt * 16 + kg * 4;
        short* o = ctxb + ((size_t)b * Lq + qrow) * Dm + hoff + cc;
#pragma unroll
        for (int r = 0; r < 4; ++r)
            o[(size_t)r * Dm] = f2b(O[r] * iv[r]);
    }
}

// -------------------- residual add + LN (+ bf16 mirror); optional bf16 base
__global__ __launch_bounds__(256) void addln_kernel(
    float* __restrict__ x, const short* __restrict__ base_b,
    const float* __restrict__ add,
    const float* __restrict__ g, const float* __restrict__ bta,
    short* __restrict__ xb)
{
    int wave = threadIdx.x >> 6;
    int lane = threadIdx.x & 63;
    int row = blockIdx.x * 4 + wave;
    float* xr = x + (size_t)row * Dm;
    const float* ar = add + (size_t)row * Dm;
    int d0 = lane * 2;
    float b0, b1v;
    if (base_b) {
        unsigned pk = *reinterpret_cast<const unsigned*>(&base_b[(size_t)row * Dm + d0]);
        b0 = b2f((short)(pk & 0xffff));
        b1v = b2f((short)(pk >> 16));
    } else {
        float2 xv = *reinterpret_cast<const float2*>(&xr[d0]);
        b0 = xv.x; b1v = xv.y;
    }
    float2 av = *reinterpret_cast<const float2*>(&ar[d0]);
    float v0 = b0 + av.x, v1 = b1v + av.y;
    float s = v0 + v1;
#pragma unroll
    for (int off = 32; off > 0; off >>= 1) s += __shfl_xor(s, off);
    float mu = s * (1.f / Dm);
    float e0 = v0 - mu, e1 = v1 - mu;
    float s2 = e0 * e0 + e1 * e1;
#pragma unroll
    for (int off = 32; off > 0; off >>= 1) s2 += __shfl_xor(s2, off);
    float rs = rsqrtf(s2 * (1.f / Dm) + EPSf);
    float o0 = e0 * rs * g[d0] + bta[d0];
    float o1 = e1 * rs * g[d0 + 1] + bta[d0 + 1];
    xr[d0] = o0;
    xr[d0 + 1] = o1;
    unsigned pk = (unsigned)(unsigned short)f2b(o0) | ((unsigned)(unsigned short)f2b(o1) << 16);
    *reinterpret_cast<unsigned*>(&xb[(size_t)row * Dm + d0]) = pk;
}

// --------------------------------------------------------------- head
__global__ void head_kernel(const float* __restrict__ x,
                            const float* __restrict__ head_w, const float* __restrict__ head_b,
                            const float* __restrict__ gw1, const float* __restrict__ gb1,
                            const float* __restrict__ gw2, const float* __restrict__ gb2,
                            const float* __restrict__ garch,
                            float* __restrict__ out)
{
    __shared__ float last[Dm];
    __shared__ float t1[Dm / 2];
    int b = blockIdx.x, t = threadIdx.x;
    if (t < Dm) last[t] = x[((size_t)b * Lq + (Lq - 1)) * Dm + t];
    __syncthreads();
    if (t < Dm / 2) {
        float s = gb1[t];
#pragma unroll 8
        for (int d = 0; d < Dm; ++d) s += last[d] * gw1[(size_t)t * Dm + d];
        t1[t] = fmaxf(s, 0.f);
    }
    __syncthreads();
    if (t < PLn) {
        float ai = head_b[t];
#pragma unroll 8
        for (int d = 0; d < Dm; ++d) ai += last[d] * head_w[(size_t)t * Dm + d];
        float gg = gb2[t];
#pragma unroll 8
        for (int j = 0; j < Dm / 2; ++j) gg += t1[j] * gw2[(size_t)t * (Dm / 2) + j];
        float gate = 1.f / (1.f + __expf(-gg));
        out[b * PLn + t] = garch[b * PLn + t] + gate * ai;
    }
}

extern "C" void kernel_launch(void* const* d_in, const int* in_sizes, int n_in,
                              void* d_out, int out_size, void* d_ws, size_t ws_size,
                              hipStream_t stream)
{
    const float* x_enc  = (const float*)d_in[0];
    const float* x_mark = (const float*)d_in[1];
    const float* conv_w = (const float*)d_in[4];
    const float* temp_w = (const float*)d_in[5];
    const float* Wih    = (const float*)d_in[6];
    const float* Whh    = (const float*)d_in[7];
    const float* bih    = (const float*)d_in[8];
    const float* bhh    = (const float*)d_in[9];
    const float* Wqkv   = (const float*)d_in[10];
    const float* bqkv   = (const float*)d_in[11];
    const float* Wo     = (const float*)d_in[12];
    const float* bo     = (const float*)d_in[13];
    const float* ln1g   = (const float*)d_in[14];
    const float* ln1b   = (const float*)d_in[15];
    const float* W1     = (const float*)d_in[16];
    const float* b1     = (const float*)d_in[17];
    const float* W2     = (const float*)d_in[18];
    const float* b2     = (const float*)d_in[19];
    const float* ln2g   = (const float*)d_in[20];
    const float* ln2b   = (const float*)d_in[21];
    const float* head_w = (const float*)d_in[22];
    const float* head_b = (const float*)d_in[23];
    const float* gw1    = (const float*)d_in[24];
    const float* gb1    = (const float*)d_in[25];
    const float* gw2    = (const float*)d_in[26];
    const float* gb2    = (const float*)d_in[27];
    const float* g_omega= (const float*)d_in[28];
    const float* g_alpha= (const float*)d_in[29];
    const float* g_beta = (const float*)d_in[30];
    const float* g_h0   = (const float*)d_in[31];

    const int M = Bn * Lq;                    // 32768
    float* ws    = (float*)d_ws;
    float* garch = ws;                        // 6144 used
    float* biassum = ws + 6144;               // 512 floats (bih+bhh)
    float* regionA = ws + 8192;               // 4,194,304 floats
    short* xb   = (short*)regionA;            //   bf16 x mirror (after lstm)
    short* ctxb = (short*)(regionA + 2097152);//   bf16 ctx
    float* xWr  = regionA + 4194304;          // 16,777,216 floats
    float* xW   = xWr;                        //   fp32 xW (dead after lstm)
    float* x    = xWr + 16777216;             // 4,194,304 floats (live all launch)
    float* qkvr = x + 4194304;                // 12,582,912 floats
    short* encb = (short*)qkvr;               //   bf16 enc (dead after xW gemm)
    short* qkvb = (short*)qkvr;               //   bf16 qkv (dead once ctx built)
    float* tmp  = qkvr;                       //   fp32 tmp (aliases qkvb after attn)
    float* wbr  = qkvr + 12582912;            // bf16 weight mirrors
    short* Wqkv_b = (short*)wbr;              // 98,304
    short* Wo_b   = Wqkv_b + 98304;           // 32,768
    short* W1_b   = Wo_b + 32768;             // 524,288
    short* W2_b   = W1_b + 524288;            // 524,288
    short* Whh_bb = W2_b + 524288;            // 65,536
    short* Wih_b  = Whh_bb + 65536;           // 65,536

    prep_kernel<<<5122, 256, 0, stream>>>(Wqkv, Wo, W1, W2, Whh, Wih, bih, bhh,
                                          Wqkv_b, Wo_b, W1_b, W2_b, Whh_bb, Wih_b, biassum);
    enc_kernel<<<(Bn * Lq * Dm) / 256, 256, 0, stream>>>(
        x_enc, x_mark, conv_w, temp_w, encb, g_omega, g_alpha, g_beta, g_h0, garch);
    gemm_stage<<<dim3(M / 128, 512 / 128), 256, 0, stream>>>(
        encb, Wih_b, biassum, xW, nullptr, M, 512, Dm, 0);
    lstm_kernel<<<Bn, 256, 0, stream>>>(xW, Whh_bb, xb);

    for (int li = 0; li < ELn; ++li) {
        gemm_stage<<<dim3(M / 128, 384 / 128), 256, 0, stream>>>(
            xb, Wqkv_b + (size_t)li * 384 * Dm, bqkv + li * 384, nullptr, qkvb, M, 384, Dm, 0);
        attn_kernel<<<Bn * NHh, 256, 0, stream>>>(qkvb, ctxb);
        gemm_stage<<<dim3(M / 128, Dm / 128), 256, 0, stream>>>(
            ctxb, Wo_b + (size_t)li * Dm * Dm, bo + li * Dm, tmp, nullptr, M, Dm, Dm, 0);
        addln_kernel<<<M / 4, 256, 0, stream>>>(
            x, (li == 0) ? xb : nullptr, tmp, ln1g + li * Dm, ln1b + li * Dm, xb);
        ffn_fused<<<M / 128, 256, 0, stream>>>(
            xb, W1_b + (size_t)li * DFFn * Dm, b1 + li * DFFn,
            W2_b + (size_t)li * Dm * DFFn, b2 + li * Dm, tmp);
        addln_kernel<<<M / 4, 256, 0, stream>>>(
            x, nullptr, tmp, ln2g + li * Dm, ln2b + li * Dm, xb);
    }
    head_kernel<<<Bn, 128, 0, stream>>>(x, head_w, head_b, gw1, gb1, gw2, gb2, garch,
                                        (float*)d_out);
}

// Round 17
// 789.725 us; speedup vs baseline: 1.9109x; 1.0339x over previous
//
#include <hip/hip_runtime.h>
#include <hip/hip_bf16.h>
#include <math.h>

#define Bn 64
#define Lq 512
#define Dm 128
#define NHh 8
#define ELn 2
#define PLn 96
#define CINn 8
#define DFFn 2048
#define NTFn 4
#define EPSf 1e-5f

typedef __attribute__((ext_vector_type(8))) short short8v;
typedef __attribute__((ext_vector_type(4))) float f32x4;

__device__ __forceinline__ short f2b(float f) {
    union { float f; unsigned u; } v; v.f = f;
    unsigned r = v.u + 0x7fff + ((v.u >> 16) & 1);
    return (short)(r >> 16);
}
__device__ __forceinline__ float b2f(short s) {
    union { unsigned u; float f; } v;
    v.u = ((unsigned)(unsigned short)s) << 16;
    return v.f;
}
__device__ __forceinline__ float fsig(float x) {
    return __builtin_amdgcn_rcpf(1.f + __expf(-x));
}
__device__ __forceinline__ float fast_tanh(float x) {
    float ax = fabsf(x);
    float e = __expf(2.f * ax);
    float t = 1.f - 2.f * __builtin_amdgcn_rcpf(e + 1.f);
    return copysignf(t, x);
}
__device__ __forceinline__ void gload_lds16(const short* g, short* l) {
    __builtin_amdgcn_global_load_lds(
        (const __attribute__((address_space(1))) void*)g,
        (__attribute__((address_space(3))) void*)l, 16, 0, 0);
}
__device__ __forceinline__ void gload_lds16f(const float* g, float* l) {
    __builtin_amdgcn_global_load_lds(
        (const __attribute__((address_space(1))) void*)g,
        (__attribute__((address_space(3))) void*)l, 16, 0, 0);
}
__device__ __forceinline__ short8v zero8() {
    short8v z;
#pragma unroll
    for (int e = 0; e < 8; ++e) z[e] = 0;
    return z;
}

// ---- fused residual+LN epilogue on a 128x128 C-tile held in acc (4 waves)
// rows lane-local per 16-lane group: reduce via 4 shfl_xor; cross-wave halves
// combined through a 1KB LDS redbuf. Writes x (fp32) + xb (bf16).
__device__ __forceinline__ void ln_epi(
    f32x4 (&acc)[4][4], int wr, int wc, int lane, int m0,
    const float* __restrict__ bias, float* __restrict__ x,
    const short* __restrict__ base_b,
    const float* __restrict__ g, const float* __restrict__ bta,
    short* __restrict__ xb, float* redbuf)
{
    int cc = lane & 15, q = lane >> 4, cr0 = q * 4;
    float bvv[4], gv[4], bb[4];
#pragma unroll
    for (int jj = 0; jj < 4; ++jj) {
        int col = wc * 64 + jj * 16 + cc;
        bvv[jj] = bias[col]; gv[jj] = g[col]; bb[jj] = bta[col];
    }
    // v = acc + bias + residual
#pragma unroll
    for (int i = 0; i < 4; ++i)
#pragma unroll
        for (int jj = 0; jj < 4; ++jj) {
            int col = wc * 64 + jj * 16 + cc;
#pragma unroll
            for (int r = 0; r < 4; ++r) {
                int rowg = m0 + wr * 64 + i * 16 + cr0 + r;
                float resid = base_b ? b2f(base_b[(size_t)rowg * Dm + col])
                                     : x[(size_t)rowg * Dm + col];
                acc[i][jj][r] += bvv[jj] + resid;
            }
        }
    int rlb = wr * 64 + cr0;
    // mean
    float mu[4][4];
#pragma unroll
    for (int i = 0; i < 4; ++i)
#pragma unroll
        for (int r = 0; r < 4; ++r) {
            float s = (acc[i][0][r] + acc[i][1][r]) + (acc[i][2][r] + acc[i][3][r]);
            s += __shfl_xor(s, 1); s += __shfl_xor(s, 2);
            s += __shfl_xor(s, 4); s += __shfl_xor(s, 8);
            mu[i][r] = s;                       // this wave-half's row sum
        }
    if (cc == 0) {
#pragma unroll
        for (int i = 0; i < 4; ++i)
#pragma unroll
            for (int r = 0; r < 4; ++r)
                redbuf[wc * 128 + rlb + i * 16 + r] = mu[i][r];
    }
    __syncthreads();
#pragma unroll
    for (int i = 0; i < 4; ++i)
#pragma unroll
        for (int r = 0; r < 4; ++r)
            mu[i][r] = (mu[i][r] + redbuf[(wc ^ 1) * 128 + rlb + i * 16 + r]) * (1.f / 128.f);
    // variance
    float rs[4][4];
#pragma unroll
    for (int i = 0; i < 4; ++i)
#pragma unroll
        for (int r = 0; r < 4; ++r) {
            float s2 = 0.f;
#pragma unroll
            for (int jj = 0; jj < 4; ++jj) {
                acc[i][jj][r] -= mu[i][r];
                s2 += acc[i][jj][r] * acc[i][jj][r];
            }
            s2 += __shfl_xor(s2, 1); s2 += __shfl_xor(s2, 2);
            s2 += __shfl_xor(s2, 4); s2 += __shfl_xor(s2, 8);
            rs[i][r] = s2;
        }
    __syncthreads();                             // redbuf reuse fence
    if (cc == 0) {
#pragma unroll
        for (int i = 0; i < 4; ++i)
#pragma unroll
            for (int r = 0; r < 4; ++r)
                redbuf[wc * 128 + rlb + i * 16 + r] = rs[i][r];
    }
    __syncthreads();
#pragma unroll
    for (int i = 0; i < 4; ++i)
#pragma unroll
        for (int r = 0; r < 4; ++r)
            rs[i][r] = rsqrtf((rs[i][r] + redbuf[(wc ^ 1) * 128 + rlb + i * 16 + r]) *
                              (1.f / 128.f) + EPSf);
    // write x + xb
#pragma unroll
    for (int i = 0; i < 4; ++i)
#pragma unroll
        for (int jj = 0; jj < 4; ++jj) {
            int col = wc * 64 + jj * 16 + cc;
#pragma unroll
            for (int r = 0; r < 4; ++r) {
                int rowg = m0 + wr * 64 + i * 16 + cr0 + r;
                float o = acc[i][jj][r] * rs[i][r] * gv[jj] + bb[jj];
                x[(size_t)rowg * Dm + col] = o;
                xb[(size_t)rowg * Dm + col] = f2b(o);
            }
        }
}

// ---------------- fused prep: weight bf16 conversions + bias sum + pos table
__global__ void prep_kernel(const float* __restrict__ Wqkv, const float* __restrict__ Wo,
                            const float* __restrict__ W1, const float* __restrict__ W2,
                            const float* __restrict__ Whh, const float* __restrict__ Wih,
                            const float* __restrict__ bih, const float* __restrict__ bhh,
                            short* __restrict__ Wqkv_b, short* __restrict__ Wo_b,
                            short* __restrict__ W1_b, short* __restrict__ W2_b,
                            short* __restrict__ Whh_b, short* __restrict__ Wih_b,
                            float* __restrict__ biassum, float* __restrict__ ptab)
{
    int i = blockIdx.x * 256 + threadIdx.x;
    if (i < 98304)        Wqkv_b[i] = f2b(Wqkv[i]);
    else if (i < 131072)  { int j = i - 98304;   Wo_b[j]  = f2b(Wo[j]); }
    else if (i < 655360)  { int j = i - 131072;  W1_b[j]  = f2b(W1[j]); }
    else if (i < 1179648) { int j = i - 655360;  W2_b[j]  = f2b(W2[j]); }
    else if (i < 1245184) { int j = i - 1179648; Whh_b[j] = f2b(Whh[j]); }
    else if (i < 1310720) { int j = i - 1245184; Wih_b[j] = f2b(Wih[j]); }
    else if (i < 1311232) { int j = i - 1310720; biassum[j] = bih[j] + bhh[j]; }
    else if (i < 1376768) {
        int j = i - 1311232;
        int l = j >> 7, d = j & 127;
        float dv = __expf(-(float)(d & ~1) * (9.210340371976184f / 128.f));
        float ang = (float)l * dv;
        ptab[j] = (d & 1) ? cosf(ang) : sinf(ang);
    }
}

// ------------------------------- conv + temporal + pos-table (bf16 out) + GARCH
__global__ void enc_kernel(const float* __restrict__ x_enc,
                           const float* __restrict__ x_mark,
                           const float* __restrict__ conv_w,
                           const float* __restrict__ temp_w,
                           short* __restrict__ encb,
                           const float* __restrict__ ptab,
                           const float* __restrict__ g_omega,
                           const float* __restrict__ g_alpha,
                           const float* __restrict__ g_beta,
                           const float* __restrict__ g_h0,
                           float* __restrict__ garch)
{
    int idx = blockIdx.x * blockDim.x + threadIdx.x;   // over B*L*D
    int d = idx & (Dm - 1);
    int l = (idx >> 7) & (Lq - 1);
    int b = idx >> 16;
    int lm = (l + Lq - 1) & (Lq - 1);
    int lp = (l + 1) & (Lq - 1);
    const float* xb = x_enc + (size_t)b * Lq * CINn;
    const float* w  = conv_w + (size_t)d * CINn * 3;
    float acc = 0.f;
#pragma unroll
    for (int ci = 0; ci < CINn; ++ci) {
        acc += xb[(size_t)lm * CINn + ci] * w[ci * 3 + 0];
        acc += xb[(size_t)l  * CINn + ci] * w[ci * 3 + 1];
        acc += xb[(size_t)lp * CINn + ci] * w[ci * 3 + 2];
    }
    const float* mk = x_mark + ((size_t)b * Lq + l) * NTFn;
    const float* tw = temp_w + (size_t)d * NTFn;
#pragma unroll
    for (int f = 0; f < NTFn; ++f) acc += mk[f] * tw[f];
    acc += ptab[idx & 65535];
    encb[idx] = f2b(acc);

    if (blockIdx.x == 0 && threadIdx.x < Bn) {
        int bb = threadIdx.x;
        float omega = log1pf(__expf(g_omega[0]));
        float alpha = 0.2f / (1.f + __expf(-g_alpha[0]));
        float beta  = 0.8f / (1.f + __expf(-g_beta[0]));
        float h = log1pf(__expf(g_h0[0]));
        const float* xe = x_enc + (size_t)bb * Lq * CINn + (CINn - 2);
        for (int t = 0; t < Lq; ++t) {
            float r = xe[(size_t)t * CINn];
            h = omega + alpha * r * r + beta * h;
        }
        float ab = alpha + beta;
        for (int p = 0; p < PLn; ++p) {
            garch[bb * PLn + p] = sqrtf(h);
            h = omega + ab * h;
        }
    }
}

// ---------------- staged+swizzled bf16 MFMA GEMM, tile 128x128, BK=128
__global__ __launch_bounds__(256) void gemm_stage(
    const short* __restrict__ A, const short* __restrict__ W,
    const float* __restrict__ b1,
    float* __restrict__ Cf, short* __restrict__ Cb,
    int M, int N, int K, int relu)
{
    __shared__ short As[128 * 128];
    __shared__ short Ws[128 * 128];
    int tid = threadIdx.x;
    int w = tid >> 6, lane = tid & 63;
    int wr = w >> 1, wc = w & 1;
    int m0 = blockIdx.x * 128, n0 = blockIdx.y * 128;
    int lr = lane & 15;
    int lkq = lane >> 4;
    int srow_in = lane >> 4;
    int jp = lane & 15;
    f32x4 acc[4][4] = {};

    for (int k0 = 0; k0 < K; k0 += 128) {
        if (k0) __syncthreads();
#pragma unroll
        for (int inst = 0; inst < 8; ++inst) {
            int c = w * 8 + inst;
            int r = c * 4 + srow_in;
            int j = jp ^ (r & 7);
            gload_lds16(A + (size_t)(m0 + r) * K + k0 + j * 8, &As[c * 512]);
            gload_lds16(W + (size_t)(n0 + r) * K + k0 + j * 8, &Ws[c * 512]);
        }
        __syncthreads();
#pragma unroll
        for (int kq = 0; kq < 4; ++kq) {
            int jlog = kq * 4 + lkq;
            short8v a[4], b[4];
#pragma unroll
            for (int i = 0; i < 4; ++i) {
                int ri = wr * 64 + i * 16 + lr;
                a[i] = *reinterpret_cast<const short8v*>(&As[ri * 128 + (jlog ^ (ri & 7)) * 8]);
            }
#pragma unroll
            for (int jj = 0; jj < 4; ++jj) {
                int rj = wc * 64 + jj * 16 + lr;
                b[jj] = *reinterpret_cast<const short8v*>(&Ws[rj * 128 + (jlog ^ (rj & 7)) * 8]);
            }
#pragma unroll
            for (int i = 0; i < 4; ++i)
#pragma unroll
                for (int jj = 0; jj < 4; ++jj)
                    acc[i][jj] = __builtin_amdgcn_mfma_f32_16x16x32_bf16(
                        a[i], b[jj], acc[i][jj], 0, 0, 0);
        }
    }
    int cr0 = (lane >> 4) * 4;
    int cc = lane & 15;
#pragma unroll
    for (int i = 0; i < 4; ++i)
#pragma unroll
        for (int jj = 0; jj < 4; ++jj) {
            int col = n0 + wc * 64 + jj * 16 + cc;
            float bias = b1[col];
#pragma unroll
            for (int r = 0; r < 4; ++r) {
                int row = m0 + wr * 64 + i * 16 + cr0 + r;
                float v = acc[i][jj][r] + bias;
                if (relu) v = fmaxf(v, 0.f);
                if (Cf) Cf[(size_t)row * N + col] = v;
                else    Cb[(size_t)row * N + col] = f2b(v);
            }
        }
}

// ---------------- Wo GEMM (N=K=128) + residual + LN fused
__global__ __launch_bounds__(256) void gemm_ln(
    const short* __restrict__ A, const short* __restrict__ W,
    const float* __restrict__ bias,
    float* __restrict__ x, const short* __restrict__ base_b,
    const float* __restrict__ g, const float* __restrict__ bta,
    short* __restrict__ xb)
{
    __shared__ short As[128 * 128];
    __shared__ short Ws[128 * 128];
    __shared__ float redbuf[256];
    int tid = threadIdx.x;
    int w = tid >> 6, lane = tid & 63;
    int wr = w >> 1, wc = w & 1;
    int m0 = blockIdx.x * 128;
    int lr = lane & 15;
    int lkq = lane >> 4;
    int srow_in = lane >> 4;
    int jp = lane & 15;
    f32x4 acc[4][4] = {};

#pragma unroll
    for (int inst = 0; inst < 8; ++inst) {
        int c = w * 8 + inst;
        int r = c * 4 + srow_in;
        int j = jp ^ (r & 7);
        gload_lds16(A + (size_t)(m0 + r) * 128 + j * 8, &As[c * 512]);
        gload_lds16(W + (size_t)r * 128 + j * 8, &Ws[c * 512]);
    }
    __syncthreads();
#pragma unroll
    for (int kq = 0; kq < 4; ++kq) {
        int jlog = kq * 4 + lkq;
        short8v a[4], b[4];
#pragma unroll
        for (int i = 0; i < 4; ++i) {
            int ri = wr * 64 + i * 16 + lr;
            a[i] = *reinterpret_cast<const short8v*>(&As[ri * 128 + (jlog ^ (ri & 7)) * 8]);
        }
#pragma unroll
        for (int jj = 0; jj < 4; ++jj) {
            int rj = wc * 64 + jj * 16 + lr;
            b[jj] = *reinterpret_cast<const short8v*>(&Ws[rj * 128 + (jlog ^ (rj & 7)) * 8]);
        }
#pragma unroll
        for (int i = 0; i < 4; ++i)
#pragma unroll
            for (int jj = 0; jj < 4; ++jj)
                acc[i][jj] = __builtin_amdgcn_mfma_f32_16x16x32_bf16(
                    a[i], b[jj], acc[i][jj], 0, 0, 0);
    }
    ln_epi(acc, wr, wc, lane, m0, bias, x, base_b, g, bta, xb, redbuf);
}

// ---------------- fused FFN + residual + LN: ff1 never in HBM, LN in-kernel
__global__ __launch_bounds__(256, 1) void ffn_ln(
    const short* __restrict__ X, const short* __restrict__ W1w,
    const float* __restrict__ bias1,
    const short* __restrict__ W2w, const float* __restrict__ bias2,
    float* __restrict__ x, const float* __restrict__ g,
    const float* __restrict__ bta, short* __restrict__ xb)
{
    __shared__ short Xs[128 * 128];
    __shared__ short Wa[128 * 128];
    __shared__ short Wb[128 * 128];
    __shared__ short Ps[128 * 128];
    __shared__ float redbuf[256];
    int tid = threadIdx.x;
    int w = tid >> 6, lane = tid & 63;
    int wr = w >> 1, wc = w & 1;
    int m0 = blockIdx.x * 128;
    int lr = lane & 15;
    int lkq = lane >> 4;
    int srow_in = lane >> 4;
    int jp = lane & 15;
    int cr0 = (lane >> 4) * 4;
    int cc = lane & 15;

#pragma unroll
    for (int inst = 0; inst < 8; ++inst) {
        int c = w * 8 + inst;
        int r = c * 4 + srow_in;
        int j = jp ^ (r & 7);
        gload_lds16(X + (size_t)(m0 + r) * 128 + j * 8, &Xs[c * 512]);
    }

    f32x4 acc[4][4] = {};
    for (int f = 0; f < 16; ++f) {
#pragma unroll
        for (int inst = 0; inst < 8; ++inst) {
            int c = w * 8 + inst;
            int r = c * 4 + srow_in;
            int j = jp ^ (r & 7);
            gload_lds16(W1w + (size_t)(f * 128 + r) * 128 + j * 8, &Wa[c * 512]);
        }
        __syncthreads();
        float bv[4];
#pragma unroll
        for (int jj = 0; jj < 4; ++jj) bv[jj] = bias1[f * 128 + wc * 64 + jj * 16 + cc];
        f32x4 acc1[4][4] = {};
#pragma unroll
        for (int kq = 0; kq < 4; ++kq) {
            int jlog = kq * 4 + lkq;
            short8v a[4], b[4];
#pragma unroll
            for (int i = 0; i < 4; ++i) {
                int ri = wr * 64 + i * 16 + lr;
                a[i] = *reinterpret_cast<const short8v*>(&Xs[ri * 128 + (jlog ^ (ri & 7)) * 8]);
            }
#pragma unroll
            for (int jj = 0; jj < 4; ++jj) {
                int rj = wc * 64 + jj * 16 + lr;
                b[jj] = *reinterpret_cast<const short8v*>(&Wa[rj * 128 + (jlog ^ (rj & 7)) * 8]);
            }
#pragma unroll
            for (int i = 0; i < 4; ++i)
#pragma unroll
                for (int jj = 0; jj < 4; ++jj)
                    acc1[i][jj] = __builtin_amdgcn_mfma_f32_16x16x32_bf16(
                        a[i], b[jj], acc1[i][jj], 0, 0, 0);
        }
#pragma unroll
        for (int inst = 0; inst < 8; ++inst) {
            int c = w * 8 + inst;
            int r = c * 4 + srow_in;
            int j = jp ^ (r & 7);
            gload_lds16(W2w + (size_t)r * 2048 + f * 128 + j * 8, &Wb[c * 512]);
        }
#pragma unroll
        for (int i = 0; i < 4; ++i)
#pragma unroll
            for (int jj = 0; jj < 4; ++jj) {
                int col = wc * 64 + jj * 16 + cc;
                int jc = col >> 3, ec = col & 7;
#pragma unroll
                for (int r = 0; r < 4; ++r) {
                    int row = wr * 64 + i * 16 + cr0 + r;
                    float v = fmaxf(acc1[i][jj][r] + bv[jj], 0.f);
                    Ps[row * 128 + ((jc ^ (row & 7)) * 8 + ec)] = f2b(v);
                }
            }
        __syncthreads();
#pragma unroll
        for (int kq = 0; kq < 4; ++kq) {
            int jlog = kq * 4 + lkq;
            short8v a[4], b[4];
#pragma unroll
            for (int i = 0; i < 4; ++i) {
                int ri = wr * 64 + i * 16 + lr;
                a[i] = *reinterpret_cast<const short8v*>(&Ps[ri * 128 + (jlog ^ (ri & 7)) * 8]);
            }
#pragma unroll
            for (int jj = 0; jj < 4; ++jj) {
                int rj = wc * 64 + jj * 16 + lr;
                b[jj] = *reinterpret_cast<const short8v*>(&Wb[rj * 128 + (jlog ^ (rj & 7)) * 8]);
            }
#pragma unroll
            for (int i = 0; i < 4; ++i)
#pragma unroll
                for (int jj = 0; jj < 4; ++jj)
                    acc[i][jj] = __builtin_amdgcn_mfma_f32_16x16x32_bf16(
                        a[i], b[jj], acc[i][jj], 0, 0, 0);
        }
    }
    ln_epi(acc, wr, wc, lane, m0, bias2, x, nullptr, g, bta, xb, redbuf);
}

// ---------------------------------------------------------------- LSTM (MFMA matvec v5, frozen)
__global__ __launch_bounds__(256, 1) void lstm_kernel(
    const float* __restrict__ xW, const short* __restrict__ Whh_b,
    short* __restrict__ xb_out)
{
    __shared__ __align__(16) short hb[2][Dm];
    __shared__ __align__(16) float xs[2][8 * 512];
    int b = blockIdx.x;
    int tid = threadIdx.x;
    int w = tid >> 6;
    int lane = tid & 63;
    int lr = lane & 15;
    int lk = (lane >> 4) * 8;
    int cr0 = (lane >> 4) * 4;
    int qs = lr >> 2;
    int qr = lr & 3;
    int d = w * 32 + qs * 16 + cr0 + qr;
    bool owner = (lr < 8);

    short8v a[4][2][4];
#pragma unroll
    for (int g = 0; g < 4; ++g)
#pragma unroll
        for (int s = 0; s < 2; ++s)
#pragma unroll
            for (int k = 0; k < 4; ++k)
                a[g][s][k] = *reinterpret_cast<const short8v*>(
                    &Whh_b[(size_t)(g * 128 + w * 32 + s * 16 + lr) * Dm + k * 32 + lk]);

    const float* xwb = xW + (size_t)b * Lq * 512;
    auto stage = [&](int c, int buf) {
        const float* src = xwb + (size_t)c * 4096 + w * 1024 + lane * 4;
        float* dst = &xs[buf][w * 1024];
#pragma unroll
        for (int i = 0; i < 4; ++i)
            gload_lds16f(src + i * 256, dst + i * 256);
    };

    float cpers = 0.f;
    if (tid < 64) reinterpret_cast<int*>(hb[0])[tid] = 0;
    stage(0, 0);
    stage(1, 1);

    short* xo = xb_out + (size_t)b * Lq * Dm + d;
    short hsv[8];
    asm volatile("s_waitcnt lgkmcnt(0)" ::: "memory");

    for (int c = 0; c < 64; ++c) {
        int buf = c & 1;
        asm volatile("s_waitcnt vmcnt(4)" ::: "memory");
        __builtin_amdgcn_sched_barrier(0);
        __builtin_amdgcn_s_barrier();
#pragma unroll
        for (int s8 = 0; s8 < 8; ++s8) {
            short8v bf[4];
#pragma unroll
            for (int k = 0; k < 4; ++k)
                bf[k] = *reinterpret_cast<const short8v*>(&hb[s8 & 1][k * 32 + lk]);
            f32x4 acc[4][2] = {};
#pragma unroll
            for (int k = 0; k < 4; ++k)
#pragma unroll
                for (int g = 0; g < 4; ++g)
#pragma unroll
                    for (int s = 0; s < 2; ++s)
                        acc[g][s] = __builtin_amdgcn_mfma_f32_16x16x32_bf16(
                            a[g][s][k], bf[k], acc[g][s], 0, 0, 0);
            if (owner) {
                float iraw = 0.f, fraw = 0.f, graw = 0.f, oraw = 0.f;
#pragma unroll
                for (int s = 0; s < 2; ++s)
#pragma unroll
                    for (int r = 0; r < 4; ++r)
                        if (qs == s && qr == r) {
                            iraw = acc[0][s][r]; fraw = acc[1][s][r];
                            graw = acc[2][s][r]; oraw = acc[3][s][r];
                        }
                iraw += xs[buf][s8 * 512 + 0 * 128 + d];
                fraw += xs[buf][s8 * 512 + 1 * 128 + d];
                graw += xs[buf][s8 * 512 + 2 * 128 + d];
                oraw += xs[buf][s8 * 512 + 3 * 128 + d];
                float ig = fsig(iraw);
                float fg = fsig(fraw);
                float gg = fast_tanh(graw);
                float og = fsig(oraw);
                cpers = fg * cpers + ig * gg;
                float h = og * fast_tanh(cpers);
                short hv = f2b(h);
                hsv[s8] = hv;
                hb[(s8 & 1) ^ 1][d] = hv;
            }
            asm volatile("s_waitcnt lgkmcnt(0)" ::: "memory");
            __builtin_amdgcn_s_barrier();
        }
        int cn = (c + 2 < 64) ? c + 2 : 63;
        stage(cn, buf);
        if (owner) {
#pragma unroll
            for (int s8 = 0; s8 < 8; ++s8)
                xo[(size_t)(c * 8 + s8) * Dm] = hsv[s8];
        }
    }
}

// ------------------------------------------------- MFMA flash attention
__global__ __launch_bounds__(256, 1) void attn_kernel(
    const short* __restrict__ qkvb, short* __restrict__ ctxb)
{
    __shared__ __align__(16) short Klds[512 * 16];
    __shared__ __align__(16) short Plds[4][16 * 40];
    __shared__ __align__(16) float Flds[4][16];
    int h = blockIdx.x & (NHh - 1);
    int b = blockIdx.x >> 3;
    int tid = threadIdx.x;
    int w = tid >> 6, lane = tid & 63;
    int cc = lane & 15, kg = lane >> 4;
    const short* base = qkvb + (size_t)b * Lq * 384;
    int hoff = h * 16;

    for (int i = tid; i < 1024; i += 256) {
        int r = i >> 1, half = i & 1;
        *reinterpret_cast<short8v*>(&Klds[r * 16 + half * 8]) =
            *reinterpret_cast<const short8v*>(&base[(size_t)r * 384 + 128 + hoff + half * 8]);
    }

    short8v vf[16];
#pragma unroll
    for (int g = 0; g < 16; ++g) {
        short8v v;
#pragma unroll
        for (int e = 0; e < 8; ++e)
            v[e] = base[(size_t)(g * 32 + kg * 8 + e) * 384 + 256 + hoff + cc];
        vf[g] = v;
    }
    __syncthreads();

    int wq0 = w * 128;
    for (int qt = 0; qt < 8; ++qt) {
        short8v qf = zero8();
        if (kg < 2)
            qf = *reinterpret_cast<const short8v*>(
                &base[(size_t)(wq0 + qt * 16 + cc) * 384 + hoff + kg * 8]);
        f32x4 O = {};
        float m = -1e30f, lsum = 0.f;
#pragma unroll
        for (int g = 0; g < 16; ++g) {
#pragma unroll
            for (int half = 0; half < 2; ++half) {
                int kt = g * 2 + half;
                short8v kf = zero8();
                if (kg < 2)
                    kf = *reinterpret_cast<const short8v*>(&Klds[(kt * 16 + cc) * 16 + kg * 8]);
                f32x4 s4 = __builtin_amdgcn_mfma_f32_16x16x32_bf16(kf, qf, f32x4{}, 0, 0, 0);
                float s0 = s4[0] * 0.25f, s1 = s4[1] * 0.25f;
                float s2 = s4[2] * 0.25f, s3 = s4[3] * 0.25f;
                float rmax = fmaxf(fmaxf(s0, s1), fmaxf(s2, s3));
                rmax = fmaxf(rmax, __shfl_xor(rmax, 16));
                rmax = fmaxf(rmax, __shfl_xor(rmax, 32));
                if (__any(rmax > m + 8.f)) {
                    float newm = fmaxf(m, rmax);
                    float fac = __expf(m - newm);
                    m = newm;
                    lsum *= fac;
                    if (kg == 0) Flds[w][cc] = fac;
                    f32x4 fv = *reinterpret_cast<f32x4*>(&Flds[w][kg * 4]);
                    O[0] *= fv[0]; O[1] *= fv[1]; O[2] *= fv[2]; O[3] *= fv[3];
                }
                float p0 = __expf(s0 - m), p1 = __expf(s1 - m);
                float p2 = __expf(s2 - m), p3 = __expf(s3 - m);
                lsum += (p0 + p1) + (p2 + p3);
                uint2 pk;
                pk.x = (unsigned)(unsigned short)f2b(p0) |
                       ((unsigned)(unsigned short)f2b(p1) << 16);
                pk.y = (unsigned)(unsigned short)f2b(p2) |
                       ((unsigned)(unsigned short)f2b(p3) << 16);
                *reinterpret_cast<uint2*>(&Plds[w][cc * 40 + half * 16 + kg * 4]) = pk;
            }
            short8v pf = *reinterpret_cast<const short8v*>(&Plds[w][cc * 40 + kg * 8]);
            O = __builtin_amdgcn_mfma_f32_16x16x32_bf16(pf, vf[g], O, 0, 0, 0);
        }
        lsum += __shfl_xor(lsum, 16);
        lsum += __shfl_xor(lsum, 32);
        float inv = __builtin_amdgcn_rcpf(lsum);
        if (kg == 0) Flds[w][cc] = inv;
        f32x4 iv = *reinterpret_cast<f32x4*>(&Flds[w][kg * 4]);
        int qrow = wq0 + qt * 16 + kg * 4;
        short* o = ctxb + ((size_t)b * Lq + qrow) * Dm + hoff + cc;
#pragma unroll
        for (int r = 0; r < 4; ++r)
            o[(size_t)r * Dm] = f2b(O[r] * iv[r]);
    }
}

// --------------------------------------------------------------- head
__global__ void head_kernel(const float* __restrict__ x,
                            const float* __restrict__ head_w, const float* __restrict__ head_b,
                            const float* __restrict__ gw1, const float* __restrict__ gb1,
                            const float* __restrict__ gw2, const float* __restrict__ gb2,
                            const float* __restrict__ garch,
                            float* __restrict__ out)
{
    __shared__ float last[Dm];
    __shared__ float t1[Dm / 2];
    int b = blockIdx.x, t = threadIdx.x;
    if (t < Dm) last[t] = x[((size_t)b * Lq + (Lq - 1)) * Dm + t];
    __syncthreads();
    if (t < Dm / 2) {
        float s = gb1[t];
#pragma unroll 8
        for (int d = 0; d < Dm; ++d) s += last[d] * gw1[(size_t)t * Dm + d];
        t1[t] = fmaxf(s, 0.f);
    }
    __syncthreads();
    if (t < PLn) {
        float ai = head_b[t];
#pragma unroll 8
        for (int d = 0; d < Dm; ++d) ai += last[d] * head_w[(size_t)t * Dm + d];
        float gg = gb2[t];
#pragma unroll 8
        for (int j = 0; j < Dm / 2; ++j) gg += t1[j] * gw2[(size_t)t * (Dm / 2) + j];
        float gate = 1.f / (1.f + __expf(-gg));
        out[b * PLn + t] = garch[b * PLn + t] + gate * ai;
    }
}

extern "C" void kernel_launch(void* const* d_in, const int* in_sizes, int n_in,
                              void* d_out, int out_size, void* d_ws, size_t ws_size,
                              hipStream_t stream)
{
    const float* x_enc  = (const float*)d_in[0];
    const float* x_mark = (const float*)d_in[1];
    const float* conv_w = (const float*)d_in[4];
    const float* temp_w = (const float*)d_in[5];
    const float* Wih    = (const float*)d_in[6];
    const float* Whh    = (const float*)d_in[7];
    const float* bih    = (const float*)d_in[8];
    const float* bhh    = (const float*)d_in[9];
    const float* Wqkv   = (const float*)d_in[10];
    const float* bqkv   = (const float*)d_in[11];
    const float* Wo     = (const float*)d_in[12];
    const float* bo     = (const float*)d_in[13];
    const float* ln1g   = (const float*)d_in[14];
    const float* ln1b   = (const float*)d_in[15];
    const float* W1     = (const float*)d_in[16];
    const float* b1     = (const float*)d_in[17];
    const float* W2     = (const float*)d_in[18];
    const float* b2     = (const float*)d_in[19];
    const float* ln2g   = (const float*)d_in[20];
    const float* ln2b   = (const float*)d_in[21];
    const float* head_w = (const float*)d_in[22];
    const float* head_b = (const float*)d_in[23];
    const float* gw1    = (const float*)d_in[24];
    const float* gb1    = (const float*)d_in[25];
    const float* gw2    = (const float*)d_in[26];
    const float* gb2    = (const float*)d_in[27];
    const float* g_omega= (const float*)d_in[28];
    const float* g_alpha= (const float*)d_in[29];
    const float* g_beta = (const float*)d_in[30];
    const float* g_h0   = (const float*)d_in[31];

    const int M = Bn * Lq;                    // 32768
    float* ws    = (float*)d_ws;
    float* garch = ws;                        // 6144 used
    float* biassum = ws + 6144;               // 512 floats (bih+bhh)
    float* regionA = ws + 8192;               // 4,194,304 floats
    short* xb   = (short*)regionA;            //   bf16 x mirror (after lstm)
    short* ctxb = (short*)(regionA + 2097152);//   bf16 ctx
    float* xWr  = regionA + 4194304;          // 16,777,216 floats
    float* xW   = xWr;                        //   fp32 xW (dead after lstm)
    float* x    = xWr + 16777216;             // 4,194,304 floats (live all launch)
    float* qkvr = x + 4194304;                // 12,582,912 floats
    short* encb = (short*)qkvr;               //   bf16 enc (dead after xW gemm)
    short* qkvb = (short*)qkvr;               //   bf16 qkv (dead once ctx built)
    float* ptab = qkvr + 8388608;             //   pos-enc table (65,536 floats, persistent)
    float* wbr  = qkvr + 12582912;            // bf16 weight mirrors
    short* Wqkv_b = (short*)wbr;              // 98,304
    short* Wo_b   = Wqkv_b + 98304;           // 32,768
    short* W1_b   = Wo_b + 32768;             // 524,288
    short* W2_b   = W1_b + 524288;            // 524,288
    short* Whh_bb = W2_b + 524288;            // 65,536
    short* Wih_b  = Whh_bb + 65536;           // 65,536

    prep_kernel<<<5378, 256, 0, stream>>>(Wqkv, Wo, W1, W2, Whh, Wih, bih, bhh,
                                          Wqkv_b, Wo_b, W1_b, W2_b, Whh_bb, Wih_b,
                                          biassum, ptab);
    enc_kernel<<<(Bn * Lq * Dm) / 256, 256, 0, stream>>>(
        x_enc, x_mark, conv_w, temp_w, encb, ptab, g_omega, g_alpha, g_beta, g_h0, garch);
    gemm_stage<<<dim3(M / 128, 512 / 128), 256, 0, stream>>>(
        encb, Wih_b, biassum, xW, nullptr, M, 512, Dm, 0);
    lstm_kernel<<<Bn, 256, 0, stream>>>(xW, Whh_bb, xb);

    for (int li = 0; li < ELn; ++li) {
        gemm_stage<<<dim3(M / 128, 384 / 128), 256, 0, stream>>>(
            xb, Wqkv_b + (size_t)li * 384 * Dm, bqkv + li * 384, nullptr, qkvb, M, 384, Dm, 0);
        attn_kernel<<<Bn * NHh, 256, 0, stream>>>(qkvb, ctxb);
        gemm_ln<<<M / 128, 256, 0, stream>>>(
            ctxb, Wo_b + (size_t)li * Dm * Dm, bo + li * Dm,
            x, (li == 0) ? xb : nullptr, ln1g + li * Dm, ln1b + li * Dm, xb);
        ffn_ln<<<M / 128, 256, 0, stream>>>(
            xb, W1_b + (size_t)li * DFFn * Dm, b1 + li * DFFn,
            W2_b + (size_t)li * Dm * DFFn, b2 + li * Dm,
            x, ln2g + li * Dm, ln2b + li * Dm, xb);
    }
    head_kernel<<<Bn, 128, 0, stream>>>(x, head_w, head_b, gw1, gb1, gw2, gb2, garch,
                                        (float*)d_out);
}